// Round 1
// baseline (4048.205 us; speedup 1.0000x reference)
//
#include <hip/hip_runtime.h>
#include <hip/hip_bf16.h>
#include <math.h>

#define B_   32
#define L_   2048
#define H_   8
#define DMET 16
#define SDIM 27
#define DM   256
#define NL   4
#define DS   64
#define TE   256
#define LT   2055          // L + H - 1
#define LTP  2056          // padded stride
#define NTOT (B_ * LT)     // 65760 samples per channel for BN

__device__ __forceinline__ float sigmoidf_(float x) {
    return 1.0f / (1.0f + expf(-x));
}

__device__ __forceinline__ float gelu_tanh(float x) {
    // jax.nn.gelu default: approximate=True (tanh form)
    const float c0 = 0.7978845608028654f; // sqrt(2/pi)
    float x3 = x * x * x;
    float t = tanhf(c0 * (x + 0.044715f * x3));
    return 0.5f * x * (1.0f + t);
}

// ---------------------------------------------------------------------------
// 1) time MLP: t_b[b][d] = silu(cos(t*f+ph)*sqrt2 @ W1 + b1) @ W2 + b2
// ---------------------------------------------------------------------------
__global__ __launch_bounds__(256) void time_mlp_kernel(
    const float* __restrict__ t, const float* __restrict__ freqs,
    const float* __restrict__ phases,
    const float* __restrict__ W1, const float* __restrict__ b1,
    const float* __restrict__ W2, const float* __restrict__ b2,
    float* __restrict__ tb) {
    int b = blockIdx.x;
    int tid = threadIdx.x;
    __shared__ float f[TE];
    __shared__ float hid[2 * TE];
    float tv = t[b];
    f[tid] = cosf(fmaf(tv, freqs[tid], phases[tid])) * 1.4142135623730951f;
    __syncthreads();
    float a0 = b1[tid], a1 = b1[tid + TE];
    for (int k = 0; k < TE; ++k) {
        float fk = f[k];
        a0 = fmaf(fk, W1[k * 2 * TE + tid], a0);
        a1 = fmaf(fk, W1[k * 2 * TE + tid + TE], a1);
    }
    hid[tid]      = a0 * sigmoidf_(a0);
    hid[tid + TE] = a1 * sigmoidf_(a1);
    __syncthreads();
    float acc = b2[tid];
    for (int j = 0; j < 2 * TE; ++j)
        acc = fmaf(hid[j], W2[j * DM + tid], acc);
    tb[b * DM + tid] = acc;
}

// ---------------------------------------------------------------------------
// 2) input projection -> U[b][d][l]  (transposed layout, stride LTP)
// ---------------------------------------------------------------------------
__global__ __launch_bounds__(256) void input_proj_kernel(
    const float* __restrict__ xp, const float* __restrict__ nf,
    const float* __restrict__ xf, const float* __restrict__ sa,
    const float* __restrict__ inW, const float* __restrict__ inb,
    const float* __restrict__ tb, float* __restrict__ U) {
    int b  = blockIdx.y;
    int l0 = blockIdx.x * 256;
    int tx = threadIdx.x;
    int l  = l0 + tx;

    __shared__ float feats[256][18];   // 17 used (16 met + 1 flow)
    __shared__ float Ws[17][DM];
    __shared__ float sdot[DM];
    __shared__ float tbs[DM];
    __shared__ float sstat[SDIM];

    if (tx < SDIM) sstat[tx] = sa[b * SDIM + tx];
    for (int k = 0; k < 17; ++k) Ws[k][tx] = inW[k * DM + tx];
    tbs[tx] = tb[b * DM + tx];

    bool valid = (l < LT);
    if (valid) {
        const float* src = (l < L_) ? &xp[((size_t)b * L_ + l) * DMET]
                                    : &xf[((size_t)b * (H_ - 1) + (l - L_)) * DMET];
        #pragma unroll
        for (int k = 0; k < DMET; ++k) feats[tx][k] = src[k];
        feats[tx][16] = (l >= L_ - 1) ? nf[b * H_ + (l - (L_ - 1))] : 0.0f;
    }
    __syncthreads();

    // static-feature dot, per output channel (same for all l)
    float sd = 0.0f;
    for (int k = 0; k < SDIM; ++k)
        sd = fmaf(sstat[k], inW[(17 + k) * DM + tx], sd);
    sdot[tx] = sd;
    __syncthreads();

    if (!valid) return;
    bool cond = (l >= L_ - 1);
    size_t base = ((size_t)b * DM) * LTP + l;
    for (int d = 0; d < DM; ++d) {
        float acc = inb[d] + sdot[d] + (cond ? tbs[d] : 0.0f);
        #pragma unroll
        for (int k = 0; k < 17; ++k)
            acc = fmaf(feats[tx][k], Ws[k][d], acc);
        U[base + (size_t)d * LTP] = acc;
    }
}

// ---------------------------------------------------------------------------
// 3) S4D scan:  y = gelu(conv(u,K) + D*u)   exact linear recurrence
//    one wave handles 8 channels; 8 lanes/channel, 8 complex states/lane
// ---------------------------------------------------------------------------
__global__ __launch_bounds__(64) void scan_kernel(
    const float* __restrict__ U, float* __restrict__ Y,
    const float* __restrict__ log_dt,
    const float* __restrict__ A_re, const float* __restrict__ A_im,
    const float* __restrict__ C_re, const float* __restrict__ C_im,
    const float* __restrict__ Dp, int layer) {
    int blk = blockIdx.x;            // b*32 + dgroup
    int b = blk >> 5, dg = blk & 31;
    int lane = threadIdx.x;
    int s = lane >> 3, j = lane & 7;
    int d = dg * 8 + s;

    float dt = expf(log_dt[layer * DM + d]);
    size_t abase = ((size_t)layer * DM + d) * DS;

    float wr[8], wi[8], ckr[8], cki[8], xr[8], xi[8];
    #pragma unroll
    for (int k = 0; k < 8; ++k) {
        int n = j * 8 + k;
        float Ar = A_re[abase + n], Ai = A_im[abase + n];
        float Cr = C_re[abase + n], Ci = C_im[abase + n];
        float dr = dt * Ar, di = dt * Ai;
        float e  = expf(dr);
        float w_r = e * cosf(di);
        float w_i = e * sinf(di);
        wr[k] = w_r; wi[k] = w_i;
        float mr = w_r - 1.0f, mi = w_i;          // expm1(dt*A)
        float den = 1.0f / (Ar * Ar + Ai * Ai);
        float qr = (mr * Ar + mi * Ai) * den;     // expm1(dtA)/A
        float qi = (mi * Ar - mr * Ai) * den;
        ckr[k] = Cr * qr - Ci * qi;
        cki[k] = Cr * qi + Ci * qr;
        xr[k] = 0.0f; xi[k] = 0.0f;
    }
    float Dd = Dp[layer * DM + d];
    const float* u_row = U + ((size_t)b * DM + d) * LTP;
    float*       y_row = Y + ((size_t)b * DM + d) * LTP;

    float yreg = 0.0f;
    for (int l = 0; l < LT; ++l) {
        float u = u_row[l];
        float p = 0.0f;
        #pragma unroll
        for (int k = 0; k < 8; ++k) {
            float nxr = fmaf(wr[k], xr[k], fmaf(-wi[k], xi[k], u));
            float nxi = fmaf(wr[k], xi[k], wi[k] * xr[k]);
            xr[k] = nxr; xi[k] = nxi;
            p = fmaf(ckr[k], nxr, p);
            p = fmaf(-cki[k], nxi, p);
        }
        p += __shfl_xor(p, 1);
        p += __shfl_xor(p, 2);
        p += __shfl_xor(p, 4);
        float yv = fmaf(2.0f, p, Dd * u);
        if ((l & 7) == j) yreg = yv;
        if ((l & 7) == 7) y_row[(l - 7) + j] = gelu_tanh(yreg);
    }
    // tail: LT % 8 == 7 -> lanes j=0..6 hold l = 2048..2054
    if (j < (LT & 7)) y_row[(LT & ~7) + j] = gelu_tanh(yreg);
}

// ---------------------------------------------------------------------------
// 4) z = y @ out_W + out_b ; GLU ; hsum = u + glu (in-place into U) ; BN stats
//    64(l) x 64(col = 32 z1 + 32 z2 pairs) x K256 fp32 tile GEMM
// ---------------------------------------------------------------------------
__global__ __launch_bounds__(256) void gemm_glu_kernel(
    const float* __restrict__ Y, float* __restrict__ U,
    const float* __restrict__ out_W, const float* __restrict__ out_b,
    float* __restrict__ stats, int layer) {
    int lt = blockIdx.x;     // 0..32
    int by = blockIdx.y;     // 0..7  (pair group of 32)
    int b  = blockIdx.z;
    int tid = threadIdx.x;
    int tx = tid & 15, ty = tid >> 4;
    int l0 = lt * 64;

    __shared__ float As[16][68];
    __shared__ float Bs[16][66];

    const float* Wl = out_W + (size_t)layer * DM * 2 * DM;
    const float* bl = out_b + layer * 2 * DM;

    float acc[4][4];
    #pragma unroll
    for (int i = 0; i < 4; ++i)
        #pragma unroll
        for (int jq = 0; jq < 4; ++jq) acc[i][jq] = 0.0f;

    int ak = tid >> 4;          // k-row within tile
    int al = (tid & 15) * 4;    // l-col base

    for (int k0 = 0; k0 < DM; k0 += 16) {
        const float* yrow = Y + ((size_t)b * DM + k0 + ak) * LTP + l0 + al;
        #pragma unroll
        for (int q = 0; q < 4; ++q) {
            int l = l0 + al + q;
            As[ak][al + q] = (l < LT) ? yrow[q] : 0.0f;
        }
        const float* wrow = Wl + (size_t)(k0 + ak) * (2 * DM);
        #pragma unroll
        for (int q = 0; q < 4; ++q) {
            int c = al + q;
            int e = (c < 32) ? (by * 32 + c) : (DM + by * 32 + (c - 32));
            Bs[ak][c] = wrow[e];
        }
        __syncthreads();
        #pragma unroll
        for (int kk = 0; kk < 16; ++kk) {
            float a0 = As[kk][ty * 4 + 0];
            float a1 = As[kk][ty * 4 + 1];
            float a2 = As[kk][ty * 4 + 2];
            float a3 = As[kk][ty * 4 + 3];
            float bv0 = Bs[kk][2 * tx];
            float bv1 = Bs[kk][2 * tx + 1];
            float bv2 = Bs[kk][32 + 2 * tx];
            float bv3 = Bs[kk][33 + 2 * tx];
            acc[0][0] = fmaf(a0, bv0, acc[0][0]); acc[0][1] = fmaf(a0, bv1, acc[0][1]);
            acc[0][2] = fmaf(a0, bv2, acc[0][2]); acc[0][3] = fmaf(a0, bv3, acc[0][3]);
            acc[1][0] = fmaf(a1, bv0, acc[1][0]); acc[1][1] = fmaf(a1, bv1, acc[1][1]);
            acc[1][2] = fmaf(a1, bv2, acc[1][2]); acc[1][3] = fmaf(a1, bv3, acc[1][3]);
            acc[2][0] = fmaf(a2, bv0, acc[2][0]); acc[2][1] = fmaf(a2, bv1, acc[2][1]);
            acc[2][2] = fmaf(a2, bv2, acc[2][2]); acc[2][3] = fmaf(a2, bv3, acc[2][3]);
            acc[3][0] = fmaf(a3, bv0, acc[3][0]); acc[3][1] = fmaf(a3, bv1, acc[3][1]);
            acc[3][2] = fmaf(a3, bv2, acc[3][2]); acc[3][3] = fmaf(a3, bv3, acc[3][3]);
        }
        __syncthreads();
    }

    // epilogue: GLU + residual (in-place) + BN partial stats
    float s_p[2] = {0.0f, 0.0f}, q_p[2] = {0.0f, 0.0f};
    #pragma unroll
    for (int pi = 0; pi < 2; ++pi) {
        int P = by * 32 + 2 * tx + pi;
        float bz1 = bl[P], bz2 = bl[DM + P];
        float* urow = U + ((size_t)b * DM + P) * LTP;
        #pragma unroll
        for (int mi = 0; mi < 4; ++mi) {
            int l = l0 + ty * 4 + mi;
            if (l >= LT) continue;
            float z1 = acc[mi][pi] + bz1;
            float z2 = acc[mi][2 + pi] + bz2;
            float g  = z1 * sigmoidf_(z2);
            float hs = urow[l] + g;
            urow[l] = hs;
            s_p[pi] += hs;
            q_p[pi] += hs * hs;
        }
    }
    __syncthreads();
    float* red = &As[0][0];   // 1088 floats >= 16*32*2
    #pragma unroll
    for (int pi = 0; pi < 2; ++pi) {
        int p = 2 * tx + pi;
        red[(ty * 32 + p) * 2 + 0] = s_p[pi];
        red[(ty * 32 + p) * 2 + 1] = q_p[pi];
    }
    __syncthreads();
    if (tid < 64) {
        int p = tid & 31, which = tid >> 5;
        float v = 0.0f;
        for (int r = 0; r < 16; ++r) v += red[(r * 32 + p) * 2 + which];
        atomicAdd(&stats[which * DM + by * 32 + p], v);
    }
}

// ---------------------------------------------------------------------------
// 5) BatchNorm normalize (in-place on U)
// ---------------------------------------------------------------------------
__global__ __launch_bounds__(256) void bn_kernel(
    float* __restrict__ U, const float* __restrict__ stats,
    const float* __restrict__ gamma, const float* __restrict__ beta, int layer) {
    int l = blockIdx.x * 256 + threadIdx.x;
    int d = blockIdx.y, b = blockIdx.z;
    if (l >= LT) return;
    float s = stats[d], q = stats[DM + d];
    float mean = s * (1.0f / NTOT);
    float var  = q * (1.0f / NTOT) - mean * mean;
    float sc = rsqrtf(var + 1e-5f) * gamma[layer * DM + d];
    float sh = beta[layer * DM + d] - mean * sc;
    size_t idx = ((size_t)b * DM + d) * LTP + l;
    U[idx] = fmaf(U[idx], sc, sh);
}

// ---------------------------------------------------------------------------
// 6) head: out[b,hh] = silu(h[l] @ W1 + b1) @ W2 + b2, l = L-1+hh
// ---------------------------------------------------------------------------
__global__ __launch_bounds__(128) void head_kernel(
    const float* __restrict__ U,
    const float* __restrict__ W1, const float* __restrict__ b1,
    const float* __restrict__ W2, const float* __restrict__ b2,
    float* __restrict__ out) {
    int hh = blockIdx.x;
    int b  = blockIdx.y;
    int j  = threadIdx.x;   // 0..127
    int l  = (L_ - 1) + hh;
    const float* urow = U + ((size_t)b * DM) * LTP + l;
    float a = b1[j];
    for (int k = 0; k < DM; ++k)
        a = fmaf(urow[(size_t)k * LTP], W1[k * 128 + j], a);
    float hs = a * sigmoidf_(a);
    float v = hs * W2[j];
    v += __shfl_xor(v, 1);
    v += __shfl_xor(v, 2);
    v += __shfl_xor(v, 4);
    v += __shfl_xor(v, 8);
    v += __shfl_xor(v, 16);
    v += __shfl_xor(v, 32);
    __shared__ float partial[2];
    if ((j & 63) == 0) partial[j >> 6] = v;
    __syncthreads();
    if (j == 0) out[b * H_ + hh] = partial[0] + partial[1] + b2[0];
}

// ---------------------------------------------------------------------------
extern "C" void kernel_launch(void* const* d_in, const int* in_sizes, int n_in,
                              void* d_out, int out_size, void* d_ws, size_t ws_size,
                              hipStream_t stream) {
    (void)in_sizes; (void)n_in; (void)out_size; (void)ws_size;
    const float* x_past      = (const float*)d_in[0];
    const float* noisy       = (const float*)d_in[1];
    const float* t_in        = (const float*)d_in[2];
    const float* x_future    = (const float*)d_in[3];
    const float* static_attr = (const float*)d_in[4];
    const float* freqs       = (const float*)d_in[5];
    const float* phases      = (const float*)d_in[6];
    const float* in_W        = (const float*)d_in[7];
    const float* in_b        = (const float*)d_in[8];
    const float* tm_W1       = (const float*)d_in[9];
    const float* tm_b1       = (const float*)d_in[10];
    const float* tm_W2       = (const float*)d_in[11];
    const float* tm_b2       = (const float*)d_in[12];
    const float* log_dt      = (const float*)d_in[13];
    const float* A_re        = (const float*)d_in[14];
    const float* A_im        = (const float*)d_in[15];
    const float* C_re        = (const float*)d_in[16];
    const float* C_im        = (const float*)d_in[17];
    const float* Dp          = (const float*)d_in[18];
    const float* out_W       = (const float*)d_in[19];
    const float* out_b       = (const float*)d_in[20];
    const float* bn_gamma    = (const float*)d_in[21];
    const float* bn_beta     = (const float*)d_in[22];
    const float* head_W1     = (const float*)d_in[23];
    const float* head_b1     = (const float*)d_in[24];
    const float* head_W2     = (const float*)d_in[25];
    const float* head_b2     = (const float*)d_in[26];

    char* ws = (char*)d_ws;
    const size_t UBYTES = (size_t)B_ * DM * LTP * 4;   // ~67.4 MB
    float* tb    = (float*)(ws);                        // 32 KB
    float* stats = (float*)(ws + (64 << 10));           // 2 KB
    float* U     = (float*)(ws + (1 << 20));
    float* Yb    = (float*)(ws + (1 << 20) + UBYTES);

    time_mlp_kernel<<<dim3(B_), 256, 0, stream>>>(
        t_in, freqs, phases, tm_W1, tm_b1, tm_W2, tm_b2, tb);

    input_proj_kernel<<<dim3((LT + 255) / 256, B_), 256, 0, stream>>>(
        x_past, noisy, x_future, static_attr, in_W, in_b, tb, U);

    for (int layer = 0; layer < NL; ++layer) {
        scan_kernel<<<dim3(B_ * 32), 64, 0, stream>>>(
            U, Yb, log_dt, A_re, A_im, C_re, C_im, Dp, layer);
        hipMemsetAsync(stats, 0, 2 * DM * sizeof(float), stream);
        gemm_glu_kernel<<<dim3((LT + 63) / 64, 8, B_), 256, 0, stream>>>(
            Yb, U, out_W, out_b, stats, layer);
        bn_kernel<<<dim3((LT + 255) / 256, DM, B_), 256, 0, stream>>>(
            U, stats, bn_gamma, bn_beta, layer);
    }

    head_kernel<<<dim3(H_, B_), 128, 0, stream>>>(
        U, head_W1, head_b1, head_W2, head_b2, (float*)d_out);
}

// Round 2
// 2982.975 us; speedup vs baseline: 1.3571x; 1.3571x over previous
//
#include <hip/hip_runtime.h>
#include <hip/hip_bf16.h>
#include <math.h>

#define B_   32
#define L_   2048
#define H_   8
#define DMET 16
#define SDIM 27
#define DM   256
#define NL   4
#define DS   64
#define TE   256
#define LT   2055          // L + H - 1
#define LTP  2056          // padded stride
#define NTOT (B_ * LT)     // 65760 samples per channel for BN

__device__ __forceinline__ float sigmoidf_(float x) {
    return 1.0f / (1.0f + expf(-x));
}

__device__ __forceinline__ float gelu_tanh(float x) {
    const float c0 = 0.7978845608028654f; // sqrt(2/pi)
    float x3 = x * x * x;
    float t = tanhf(c0 * (x + 0.044715f * x3));
    return 0.5f * x * (1.0f + t);
}

// ---------------------------------------------------------------------------
// 1) time MLP
// ---------------------------------------------------------------------------
__global__ __launch_bounds__(256) void time_mlp_kernel(
    const float* __restrict__ t, const float* __restrict__ freqs,
    const float* __restrict__ phases,
    const float* __restrict__ W1, const float* __restrict__ b1,
    const float* __restrict__ W2, const float* __restrict__ b2,
    float* __restrict__ tb) {
    int b = blockIdx.x;
    int tid = threadIdx.x;
    __shared__ float f[TE];
    __shared__ float hid[2 * TE];
    float tv = t[b];
    f[tid] = cosf(fmaf(tv, freqs[tid], phases[tid])) * 1.4142135623730951f;
    __syncthreads();
    float a0 = b1[tid], a1 = b1[tid + TE];
    for (int k = 0; k < TE; ++k) {
        float fk = f[k];
        a0 = fmaf(fk, W1[k * 2 * TE + tid], a0);
        a1 = fmaf(fk, W1[k * 2 * TE + tid + TE], a1);
    }
    hid[tid]      = a0 * sigmoidf_(a0);
    hid[tid + TE] = a1 * sigmoidf_(a1);
    __syncthreads();
    float acc = b2[tid];
    for (int j = 0; j < 2 * TE; ++j)
        acc = fmaf(hid[j], W2[j * DM + tid], acc);
    tb[b * DM + tid] = acc;
}

// ---------------------------------------------------------------------------
// 2) input projection -> U[b][d][l]  (transposed layout, stride LTP)
// ---------------------------------------------------------------------------
__global__ __launch_bounds__(256) void input_proj_kernel(
    const float* __restrict__ xp, const float* __restrict__ nf,
    const float* __restrict__ xf, const float* __restrict__ sa,
    const float* __restrict__ inW, const float* __restrict__ inb,
    const float* __restrict__ tb, float* __restrict__ U) {
    int b  = blockIdx.y;
    int l0 = blockIdx.x * 256;
    int tx = threadIdx.x;
    int l  = l0 + tx;

    __shared__ float feats[256][18];
    __shared__ float Ws[17][DM];
    __shared__ float sdot[DM];
    __shared__ float tbs[DM];
    __shared__ float sstat[SDIM];

    if (tx < SDIM) sstat[tx] = sa[b * SDIM + tx];
    for (int k = 0; k < 17; ++k) Ws[k][tx] = inW[k * DM + tx];
    tbs[tx] = tb[b * DM + tx];

    bool valid = (l < LT);
    if (valid) {
        const float* src = (l < L_) ? &xp[((size_t)b * L_ + l) * DMET]
                                    : &xf[((size_t)b * (H_ - 1) + (l - L_)) * DMET];
        #pragma unroll
        for (int k = 0; k < DMET; ++k) feats[tx][k] = src[k];
        feats[tx][16] = (l >= L_ - 1) ? nf[b * H_ + (l - (L_ - 1))] : 0.0f;
    }
    __syncthreads();

    float sd = 0.0f;
    for (int k = 0; k < SDIM; ++k)
        sd = fmaf(sstat[k], inW[(17 + k) * DM + tx], sd);
    sdot[tx] = sd;
    __syncthreads();

    if (!valid) return;
    bool cond = (l >= L_ - 1);
    size_t base = ((size_t)b * DM) * LTP + l;
    for (int d = 0; d < DM; ++d) {
        float acc = inb[d] + sdot[d] + (cond ? tbs[d] : 0.0f);
        #pragma unroll
        for (int k = 0; k < 17; ++k)
            acc = fmaf(feats[tx][k], Ws[k][d], acc);
        U[base + (size_t)d * LTP] = acc;
    }
}

// ---------------------------------------------------------------------------
// 3) S4D scan with LDS-staged, double-buffered u prefetch.
//    one wave per (b, 8-channel group); 8 lanes/channel x 8 complex states/lane
//    u staged in 32-col chunks, prefetched 2 chunks ahead.
// ---------------------------------------------------------------------------
__global__ __launch_bounds__(64) void scan_kernel(
    const float* __restrict__ U, float* __restrict__ Y,
    const float* __restrict__ log_dt,
    const float* __restrict__ A_re, const float* __restrict__ A_im,
    const float* __restrict__ C_re, const float* __restrict__ C_im,
    const float* __restrict__ Dp, int layer) {
    int blk = blockIdx.x;            // b*32 + dgroup
    int b = blk >> 5, dg = blk & 31;
    int lane = threadIdx.x;
    int s = lane >> 3, j = lane & 7;
    int d = dg * 8 + s;

    // [buf][row s][col], row stride 36 floats = 144 B (16B-aligned, padded
    // so the 8-way per-step broadcast read hits 8 distinct banks)
    __shared__ float ubuf[2][8][36];

    float dt = expf(log_dt[layer * DM + d]);
    size_t abase = ((size_t)layer * DM + d) * DS;

    float wr[8], wi[8], ckr[8], cki[8], xr[8], xi[8];
    #pragma unroll
    for (int k = 0; k < 8; ++k) {
        int n = j * 8 + k;
        float Ar = A_re[abase + n], Ai = A_im[abase + n];
        float Cr = C_re[abase + n], Ci = C_im[abase + n];
        float dr = dt * Ar, di = dt * Ai;
        float e  = expf(dr);
        float w_r = e * cosf(di);
        float w_i = e * sinf(di);
        wr[k] = w_r; wi[k] = w_i;
        float mr = w_r - 1.0f, mi = w_i;          // expm1(dt*A)
        float den = 1.0f / (Ar * Ar + Ai * Ai);
        float qr = (mr * Ar + mi * Ai) * den;     // expm1(dtA)/A
        float qi = (mi * Ar - mr * Ai) * den;
        ckr[k] = Cr * qr - Ci * qi;
        cki[k] = Cr * qi + Ci * qr;
        xr[k] = 0.0f; xi[k] = 0.0f;
    }
    float Dd = Dp[layer * DM + d];
    const float* u_row = U + ((size_t)b * DM + d) * LTP;
    float*       y_row = Y + ((size_t)b * DM + d) * LTP;

    const int NCH = 65;              // 64 full chunks of 32 + tail of 7
    int colj = j * 4;                // this lane's 4-col slice within a chunk

    float yreg = 0.0f;

    // prologue: chunk0 -> buf0; chunk1 in flight in registers
    float4 r;
    {
        int col = 0 * 32 + colj;
        r = *(const float4*)(u_row + col);
        *(float4*)&ubuf[0][s][colj] = r;
        col = 1 * 32 + colj;
        r = *(const float4*)(u_row + col);
    }

    for (int c = 0; c < NCH; ++c) {
        int buf = c & 1;
        if (c + 1 < NCH) {
            *(float4*)&ubuf[buf ^ 1][s][colj] = r;
        }
        if (c + 2 < NCH) {
            int col = (c + 2) * 32 + colj;
            if (col + 3 < LTP) {
                r = *(const float4*)(u_row + col);
            } else {
                r = make_float4(0.f, 0.f, 0.f, 0.f);
            }
        }
        const float* ub = &ubuf[buf][s][0];
        if (c < NCH - 1) {
            for (int k0 = 0; k0 < 32; k0 += 8) {
                #pragma unroll
                for (int kk = 0; kk < 8; ++kk) {
                    float u = ub[k0 + kk];
                    float p0 = 0.f, p1 = 0.f;
                    #pragma unroll
                    for (int k = 0; k < 8; ++k) {
                        float nxr = fmaf(wr[k], xr[k], fmaf(-wi[k], xi[k], u));
                        float nxi = fmaf(wr[k], xi[k], wi[k] * xr[k]);
                        xr[k] = nxr; xi[k] = nxi;
                        p0 = fmaf(ckr[k], nxr, p0);
                        p1 = fmaf(cki[k], nxi, p1);
                    }
                    float p = p0 - p1;
                    p += __shfl_xor(p, 1);
                    p += __shfl_xor(p, 2);
                    p += __shfl_xor(p, 4);
                    float yv = fmaf(2.0f, p, Dd * u);
                    if (kk == j) yreg = yv;
                    if (kk == 7) y_row[c * 32 + k0 + j] = gelu_tanh(yreg);
                }
            }
        } else {
            // tail: 7 valid steps (l = 2048..2054)
            #pragma unroll
            for (int kk = 0; kk < 7; ++kk) {
                float u = ub[kk];
                float p0 = 0.f, p1 = 0.f;
                #pragma unroll
                for (int k = 0; k < 8; ++k) {
                    float nxr = fmaf(wr[k], xr[k], fmaf(-wi[k], xi[k], u));
                    float nxi = fmaf(wr[k], xi[k], wi[k] * xr[k]);
                    xr[k] = nxr; xi[k] = nxi;
                    p0 = fmaf(ckr[k], nxr, p0);
                    p1 = fmaf(cki[k], nxi, p1);
                }
                float p = p0 - p1;
                p += __shfl_xor(p, 1);
                p += __shfl_xor(p, 2);
                p += __shfl_xor(p, 4);
                float yv = fmaf(2.0f, p, Dd * u);
                if (kk == j) yreg = yv;
            }
            if (j < 7) y_row[2048 + j] = gelu_tanh(yreg);
        }
    }
}

// ---------------------------------------------------------------------------
// 4) z = y @ out_W + out_b ; GLU ; hsum = u + glu (in-place into U) ; BN stats
// ---------------------------------------------------------------------------
__global__ __launch_bounds__(256) void gemm_glu_kernel(
    const float* __restrict__ Y, float* __restrict__ U,
    const float* __restrict__ out_W, const float* __restrict__ out_b,
    float* __restrict__ stats, int layer) {
    int lt = blockIdx.x;     // 0..32
    int by = blockIdx.y;     // 0..7  (pair group of 32)
    int b  = blockIdx.z;
    int tid = threadIdx.x;
    int tx = tid & 15, ty = tid >> 4;
    int l0 = lt * 64;

    __shared__ float As[16][68];
    __shared__ float Bs[16][66];

    const float* Wl = out_W + (size_t)layer * DM * 2 * DM;
    const float* bl = out_b + layer * 2 * DM;

    float acc[4][4];
    #pragma unroll
    for (int i = 0; i < 4; ++i)
        #pragma unroll
        for (int jq = 0; jq < 4; ++jq) acc[i][jq] = 0.0f;

    int ak = tid >> 4;
    int al = (tid & 15) * 4;

    for (int k0 = 0; k0 < DM; k0 += 16) {
        const float* yrow = Y + ((size_t)b * DM + k0 + ak) * LTP + l0 + al;
        #pragma unroll
        for (int q = 0; q < 4; ++q) {
            int l = l0 + al + q;
            As[ak][al + q] = (l < LT) ? yrow[q] : 0.0f;
        }
        const float* wrow = Wl + (size_t)(k0 + ak) * (2 * DM);
        #pragma unroll
        for (int q = 0; q < 4; ++q) {
            int c = al + q;
            int e = (c < 32) ? (by * 32 + c) : (DM + by * 32 + (c - 32));
            Bs[ak][c] = wrow[e];
        }
        __syncthreads();
        #pragma unroll
        for (int kk = 0; kk < 16; ++kk) {
            float a0 = As[kk][ty * 4 + 0];
            float a1 = As[kk][ty * 4 + 1];
            float a2 = As[kk][ty * 4 + 2];
            float a3 = As[kk][ty * 4 + 3];
            float bv0 = Bs[kk][2 * tx];
            float bv1 = Bs[kk][2 * tx + 1];
            float bv2 = Bs[kk][32 + 2 * tx];
            float bv3 = Bs[kk][33 + 2 * tx];
            acc[0][0] = fmaf(a0, bv0, acc[0][0]); acc[0][1] = fmaf(a0, bv1, acc[0][1]);
            acc[0][2] = fmaf(a0, bv2, acc[0][2]); acc[0][3] = fmaf(a0, bv3, acc[0][3]);
            acc[1][0] = fmaf(a1, bv0, acc[1][0]); acc[1][1] = fmaf(a1, bv1, acc[1][1]);
            acc[1][2] = fmaf(a1, bv2, acc[1][2]); acc[1][3] = fmaf(a1, bv3, acc[1][3]);
            acc[2][0] = fmaf(a2, bv0, acc[2][0]); acc[2][1] = fmaf(a2, bv1, acc[2][1]);
            acc[2][2] = fmaf(a2, bv2, acc[2][2]); acc[2][3] = fmaf(a2, bv3, acc[2][3]);
            acc[3][0] = fmaf(a3, bv0, acc[3][0]); acc[3][1] = fmaf(a3, bv1, acc[3][1]);
            acc[3][2] = fmaf(a3, bv2, acc[3][2]); acc[3][3] = fmaf(a3, bv3, acc[3][3]);
        }
        __syncthreads();
    }

    float s_p[2] = {0.0f, 0.0f}, q_p[2] = {0.0f, 0.0f};
    #pragma unroll
    for (int pi = 0; pi < 2; ++pi) {
        int P = by * 32 + 2 * tx + pi;
        float bz1 = bl[P], bz2 = bl[DM + P];
        float* urow = U + ((size_t)b * DM + P) * LTP;
        #pragma unroll
        for (int mi = 0; mi < 4; ++mi) {
            int l = l0 + ty * 4 + mi;
            if (l >= LT) continue;
            float z1 = acc[mi][pi] + bz1;
            float z2 = acc[mi][2 + pi] + bz2;
            float g  = z1 * sigmoidf_(z2);
            float hs = urow[l] + g;
            urow[l] = hs;
            s_p[pi] += hs;
            q_p[pi] += hs * hs;
        }
    }
    __syncthreads();
    float* red = &As[0][0];
    #pragma unroll
    for (int pi = 0; pi < 2; ++pi) {
        int p = 2 * tx + pi;
        red[(ty * 32 + p) * 2 + 0] = s_p[pi];
        red[(ty * 32 + p) * 2 + 1] = q_p[pi];
    }
    __syncthreads();
    if (tid < 64) {
        int p = tid & 31, which = tid >> 5;
        float v = 0.0f;
        for (int r = 0; r < 16; ++r) v += red[(r * 32 + p) * 2 + which];
        atomicAdd(&stats[which * DM + by * 32 + p], v);
    }
}

// ---------------------------------------------------------------------------
// 5) BatchNorm normalize (in-place on U)
// ---------------------------------------------------------------------------
__global__ __launch_bounds__(256) void bn_kernel(
    float* __restrict__ U, const float* __restrict__ stats,
    const float* __restrict__ gamma, const float* __restrict__ beta, int layer) {
    int l = blockIdx.x * 256 + threadIdx.x;
    int d = blockIdx.y, b = blockIdx.z;
    if (l >= LT) return;
    float s = stats[d], q = stats[DM + d];
    float mean = s * (1.0f / NTOT);
    float var  = q * (1.0f / NTOT) - mean * mean;
    float sc = rsqrtf(var + 1e-5f) * gamma[layer * DM + d];
    float sh = beta[layer * DM + d] - mean * sc;
    size_t idx = ((size_t)b * DM + d) * LTP + l;
    U[idx] = fmaf(U[idx], sc, sh);
}

// ---------------------------------------------------------------------------
// 6) head
// ---------------------------------------------------------------------------
__global__ __launch_bounds__(128) void head_kernel(
    const float* __restrict__ U,
    const float* __restrict__ W1, const float* __restrict__ b1,
    const float* __restrict__ W2, const float* __restrict__ b2,
    float* __restrict__ out) {
    int hh = blockIdx.x;
    int b  = blockIdx.y;
    int j  = threadIdx.x;
    int l  = (L_ - 1) + hh;
    const float* urow = U + ((size_t)b * DM) * LTP + l;
    float a = b1[j];
    for (int k = 0; k < DM; ++k)
        a = fmaf(urow[(size_t)k * LTP], W1[k * 128 + j], a);
    float hs = a * sigmoidf_(a);
    float v = hs * W2[j];
    v += __shfl_xor(v, 1);
    v += __shfl_xor(v, 2);
    v += __shfl_xor(v, 4);
    v += __shfl_xor(v, 8);
    v += __shfl_xor(v, 16);
    v += __shfl_xor(v, 32);
    __shared__ float partial[2];
    if ((j & 63) == 0) partial[j >> 6] = v;
    __syncthreads();
    if (j == 0) out[b * H_ + hh] = partial[0] + partial[1] + b2[0];
}

// ---------------------------------------------------------------------------
extern "C" void kernel_launch(void* const* d_in, const int* in_sizes, int n_in,
                              void* d_out, int out_size, void* d_ws, size_t ws_size,
                              hipStream_t stream) {
    (void)in_sizes; (void)n_in; (void)out_size; (void)ws_size;
    const float* x_past      = (const float*)d_in[0];
    const float* noisy       = (const float*)d_in[1];
    const float* t_in        = (const float*)d_in[2];
    const float* x_future    = (const float*)d_in[3];
    const float* static_attr = (const float*)d_in[4];
    const float* freqs       = (const float*)d_in[5];
    const float* phases      = (const float*)d_in[6];
    const float* in_W        = (const float*)d_in[7];
    const float* in_b        = (const float*)d_in[8];
    const float* tm_W1       = (const float*)d_in[9];
    const float* tm_b1       = (const float*)d_in[10];
    const float* tm_W2       = (const float*)d_in[11];
    const float* tm_b2       = (const float*)d_in[12];
    const float* log_dt      = (const float*)d_in[13];
    const float* A_re        = (const float*)d_in[14];
    const float* A_im        = (const float*)d_in[15];
    const float* C_re        = (const float*)d_in[16];
    const float* C_im        = (const float*)d_in[17];
    const float* Dp          = (const float*)d_in[18];
    const float* out_W       = (const float*)d_in[19];
    const float* out_b       = (const float*)d_in[20];
    const float* bn_gamma    = (const float*)d_in[21];
    const float* bn_beta     = (const float*)d_in[22];
    const float* head_W1     = (const float*)d_in[23];
    const float* head_b1     = (const float*)d_in[24];
    const float* head_W2     = (const float*)d_in[25];
    const float* head_b2     = (const float*)d_in[26];

    char* ws = (char*)d_ws;
    const size_t UBYTES = (size_t)B_ * DM * LTP * 4;   // ~67.4 MB
    float* tb    = (float*)(ws);
    float* stats = (float*)(ws + (64 << 10));
    float* U     = (float*)(ws + (1 << 20));
    float* Yb    = (float*)(ws + (1 << 20) + UBYTES);

    time_mlp_kernel<<<dim3(B_), 256, 0, stream>>>(
        t_in, freqs, phases, tm_W1, tm_b1, tm_W2, tm_b2, tb);

    input_proj_kernel<<<dim3((LT + 255) / 256, B_), 256, 0, stream>>>(
        x_past, noisy, x_future, static_attr, in_W, in_b, tb, U);

    for (int layer = 0; layer < NL; ++layer) {
        scan_kernel<<<dim3(B_ * 32), 64, 0, stream>>>(
            U, Yb, log_dt, A_re, A_im, C_re, C_im, Dp, layer);
        hipMemsetAsync(stats, 0, 2 * DM * sizeof(float), stream);
        gemm_glu_kernel<<<dim3((LT + 63) / 64, 8, B_), 256, 0, stream>>>(
            Yb, U, out_W, out_b, stats, layer);
        bn_kernel<<<dim3((LT + 255) / 256, DM, B_), 256, 0, stream>>>(
            U, stats, bn_gamma, bn_beta, layer);
    }

    head_kernel<<<dim3(H_, B_), 128, 0, stream>>>(
        U, head_W1, head_b1, head_W2, head_b2, (float*)d_out);
}

// Round 3
// 2680.713 us; speedup vs baseline: 1.5101x; 1.1128x over previous
//
#include <hip/hip_runtime.h>
#include <hip/hip_bf16.h>
#include <math.h>

#define B_   32
#define L_   2048
#define H_   8
#define DMET 16
#define SDIM 27
#define DM   256
#define NL   4
#define DS   64
#define TE   256
#define LT   2055          // L + H - 1
#define LTP  2056          // padded stride for U (fp32, [b][d][l])
#define LTR  2176          // padded l rows for Yb (17*128), bf16 [b][l][d]
#define NSEG 8             // segments: 7 x 256 + 1 x 263
#define NTOT (B_ * LT)

typedef __attribute__((ext_vector_type(8))) short short8;
typedef __attribute__((ext_vector_type(4))) float floatx4;

__device__ __forceinline__ float sigmoidf_(float x) {
    return 1.0f / (1.0f + expf(-x));
}

__device__ __forceinline__ float gelu_tanh(float x) {
    const float c0 = 0.7978845608028654f; // sqrt(2/pi)
    float x3 = x * x * x;
    float t = tanhf(c0 * (x + 0.044715f * x3));
    return 0.5f * x * (1.0f + t);
}

// shared S4D per-state init: w = exp(dt*A), Ck = (C)*(expm1(dt*A)/A)
__device__ __forceinline__ void s4d_init(
    int layer, int d, int j,
    const float* __restrict__ log_dt,
    const float* __restrict__ A_re, const float* __restrict__ A_im,
    const float* __restrict__ C_re, const float* __restrict__ C_im,
    float* wr, float* wi, float* ckr, float* cki) {
    float dt = expf(log_dt[layer * DM + d]);
    size_t abase = ((size_t)layer * DM + d) * DS;
    #pragma unroll
    for (int k = 0; k < 8; ++k) {
        int n = j * 8 + k;
        float Ar = A_re[abase + n], Ai = A_im[abase + n];
        float Cr = C_re[abase + n], Ci = C_im[abase + n];
        float dr = dt * Ar, di = dt * Ai;
        float e = expf(dr);
        float w_r = e * cosf(di), w_i = e * sinf(di);
        wr[k] = w_r; wi[k] = w_i;
        float mr = w_r - 1.0f, mi = w_i;           // expm1(dt*A)
        float den = 1.0f / (Ar * Ar + Ai * Ai);
        float qr = (mr * Ar + mi * Ai) * den;      // expm1(dtA)/A
        float qi = (mi * Ar - mr * Ai) * den;
        ckr[k] = Cr * qr - Ci * qi;
        cki[k] = Cr * qi + Ci * qr;
    }
}

// ---------------------------------------------------------------------------
// 1) time MLP
// ---------------------------------------------------------------------------
__global__ __launch_bounds__(256) void time_mlp_kernel(
    const float* __restrict__ t, const float* __restrict__ freqs,
    const float* __restrict__ phases,
    const float* __restrict__ W1, const float* __restrict__ b1,
    const float* __restrict__ W2, const float* __restrict__ b2,
    float* __restrict__ tb) {
    int b = blockIdx.x;
    int tid = threadIdx.x;
    __shared__ float f[TE];
    __shared__ float hid[2 * TE];
    float tv = t[b];
    f[tid] = cosf(fmaf(tv, freqs[tid], phases[tid])) * 1.4142135623730951f;
    __syncthreads();
    float a0 = b1[tid], a1 = b1[tid + TE];
    for (int k = 0; k < TE; ++k) {
        float fk = f[k];
        a0 = fmaf(fk, W1[k * 2 * TE + tid], a0);
        a1 = fmaf(fk, W1[k * 2 * TE + tid + TE], a1);
    }
    hid[tid]      = a0 * sigmoidf_(a0);
    hid[tid + TE] = a1 * sigmoidf_(a1);
    __syncthreads();
    float acc = b2[tid];
    for (int j = 0; j < 2 * TE; ++j)
        acc = fmaf(hid[j], W2[j * DM + tid], acc);
    tb[b * DM + tid] = acc;
}

// ---------------------------------------------------------------------------
// 1b) transpose out_W [NL][256][512] fp32 -> Wt bf16 [NL][512][256]
// ---------------------------------------------------------------------------
__global__ __launch_bounds__(256) void wt_prep_kernel(
    const float* __restrict__ out_W, __hip_bfloat16* __restrict__ Wt) {
    int bid = blockIdx.x;            // layer*256 + k
    int layer = bid >> 8, k = bid & 255;
    int e = threadIdx.x;
    const float* src = out_W + ((size_t)layer * 256 + k) * 512;
    #pragma unroll
    for (int q = 0; q < 2; ++q) {
        int ee = e + q * 256;
        Wt[((size_t)layer * 512 + ee) * 256 + k] = __float2bfloat16(src[ee]);
    }
}

// ---------------------------------------------------------------------------
// 2) input projection -> U[b][d][l]
// ---------------------------------------------------------------------------
__global__ __launch_bounds__(256) void input_proj_kernel(
    const float* __restrict__ xp, const float* __restrict__ nf,
    const float* __restrict__ xf, const float* __restrict__ sa,
    const float* __restrict__ inW, const float* __restrict__ inb,
    const float* __restrict__ tb, float* __restrict__ U) {
    int b  = blockIdx.y;
    int l0 = blockIdx.x * 256;
    int tx = threadIdx.x;
    int l  = l0 + tx;

    __shared__ float feats[256][18];
    __shared__ float Ws[17][DM];
    __shared__ float sdot[DM];
    __shared__ float tbs[DM];
    __shared__ float sstat[SDIM];

    if (tx < SDIM) sstat[tx] = sa[b * SDIM + tx];
    for (int k = 0; k < 17; ++k) Ws[k][tx] = inW[k * DM + tx];
    tbs[tx] = tb[b * DM + tx];

    bool valid = (l < LT);
    if (valid) {
        const float* src = (l < L_) ? &xp[((size_t)b * L_ + l) * DMET]
                                    : &xf[((size_t)b * (H_ - 1) + (l - L_)) * DMET];
        #pragma unroll
        for (int k = 0; k < DMET; ++k) feats[tx][k] = src[k];
        feats[tx][16] = (l >= L_ - 1) ? nf[b * H_ + (l - (L_ - 1))] : 0.0f;
    }
    __syncthreads();

    float sd = 0.0f;
    for (int k = 0; k < SDIM; ++k)
        sd = fmaf(sstat[k], inW[(17 + k) * DM + tx], sd);
    sdot[tx] = sd;
    __syncthreads();

    if (!valid) return;
    bool cond = (l >= L_ - 1);
    size_t base = ((size_t)b * DM) * LTP + l;
    for (int d = 0; d < DM; ++d) {
        float acc = inb[d] + sdot[d] + (cond ? tbs[d] : 0.0f);
        #pragma unroll
        for (int k = 0; k < 17; ++k)
            acc = fmaf(feats[tx][k], Ws[k][d], acc);
        U[base + (size_t)d * LTP] = acc;
    }
}

// ---------------------------------------------------------------------------
// 3a) S1: per-segment local recurrence from zero state.
//     y_local = 2*Re(sum Ck x) + D*u  -> bf16 Yb [b][l][d]; final state -> xbuf
// ---------------------------------------------------------------------------
#define SCAN_STEP(UVAL, KK)                                            \
  {                                                                    \
    float u = (UVAL);                                                  \
    float p0 = 0.f, p1 = 0.f;                                          \
    _Pragma("unroll")                                                  \
    for (int k = 0; k < 8; ++k) {                                      \
      float nxr = fmaf(wr[k], xr[k], fmaf(-wi[k], xi[k], u));          \
      float nxi = fmaf(wr[k], xi[k], wi[k] * xr[k]);                   \
      xr[k] = nxr; xi[k] = nxi;                                        \
      p0 = fmaf(ckr[k], nxr, p0);                                      \
      p1 = fmaf(cki[k], nxi, p1);                                      \
    }                                                                  \
    float p = p0 - p1;                                                 \
    p += __shfl_xor(p, 1);                                             \
    p += __shfl_xor(p, 2);                                             \
    p += __shfl_xor(p, 4);                                             \
    float yv = fmaf(2.0f, p, Dd * u);                                  \
    if ((KK) == j) yreg = yv;                                          \
  }

__global__ __launch_bounds__(64) void scan_local_kernel(
    const float* __restrict__ U, __hip_bfloat16* __restrict__ Yb,
    float* __restrict__ xbuf,
    const float* __restrict__ log_dt,
    const float* __restrict__ A_re, const float* __restrict__ A_im,
    const float* __restrict__ C_re, const float* __restrict__ C_im,
    const float* __restrict__ Dp, int layer) {
    int bdg = blockIdx.x;               // b*32 + dg
    int seg = blockIdx.y;
    int b = bdg >> 5, dg = bdg & 31;
    int lane = threadIdx.x;
    int s = lane >> 3, j = lane & 7;
    int d = dg * 8 + s;

    float wr[8], wi[8], ckr[8], cki[8];
    s4d_init(layer, d, j, log_dt, A_re, A_im, C_re, C_im, wr, wi, ckr, cki);
    float Dd = Dp[layer * DM + d];

    int segstart = seg * 256;
    const float* u_row = U + ((size_t)b * DM + d) * LTP + segstart;
    __hip_bfloat16* y_base = Yb + ((size_t)b * LTR + segstart) * DM + d;

    float xr[8], xi[8];
    #pragma unroll
    for (int k = 0; k < 8; ++k) { xr[k] = 0.f; xi[k] = 0.f; }

    float yreg = 0.0f;
    float4 ua = *(const float4*)(u_row);
    float4 ub = *(const float4*)(u_row + 4);

    for (int g = 0; g < 32; ++g) {
        float u0=ua.x,u1=ua.y,u2=ua.z,u3=ua.w,u4=ub.x,u5=ub.y,u6=ub.z,u7=ub.w;
        if (g < 31) {
            const float* np = u_row + (g + 1) * 8;
            ua = *(const float4*)np; ub = *(const float4*)(np + 4);
        } else if (seg == NSEG - 1) {
            const float* np = u_row + 256;
            ua = *(const float4*)np; ub = *(const float4*)(np + 4);
        }
        SCAN_STEP(u0, 0) SCAN_STEP(u1, 1) SCAN_STEP(u2, 2) SCAN_STEP(u3, 3)
        SCAN_STEP(u4, 4) SCAN_STEP(u5, 5) SCAN_STEP(u6, 6) SCAN_STEP(u7, 7)
        y_base[(size_t)(g * 8 + j) * DM] = __float2bfloat16(yreg);
    }
    if (seg == NSEG - 1) {   // tail: 7 more steps (l = 2048..2054)
        float u0=ua.x,u1=ua.y,u2=ua.z,u3=ua.w,u4=ub.x,u5=ub.y,u6=ub.z;
        SCAN_STEP(u0, 0) SCAN_STEP(u1, 1) SCAN_STEP(u2, 2) SCAN_STEP(u3, 3)
        SCAN_STEP(u4, 4) SCAN_STEP(u5, 5) SCAN_STEP(u6, 6)
        if (j < 7) y_base[(size_t)(256 + j) * DM] = __float2bfloat16(yreg);
    }
    // store local end-state
    float* xp_ = xbuf + ((size_t)(bdg * NSEG + seg) * 64 + lane) * 16;
    *(float4*)(xp_ + 0)  = make_float4(xr[0], xr[1], xr[2], xr[3]);
    *(float4*)(xp_ + 4)  = make_float4(xr[4], xr[5], xr[6], xr[7]);
    *(float4*)(xp_ + 8)  = make_float4(xi[0], xi[1], xi[2], xi[3]);
    *(float4*)(xp_ + 12) = make_float4(xi[4], xi[5], xi[6], xi[7]);
}

// ---------------------------------------------------------------------------
// 3b) S2: combine segment states in place: xbuf[seg] <- incoming state x_in
//     carry' = w^256 o carry + x_loc[seg]
// ---------------------------------------------------------------------------
__global__ __launch_bounds__(64) void scan_combine_kernel(
    float* __restrict__ xbuf,
    const float* __restrict__ log_dt,
    const float* __restrict__ A_re, const float* __restrict__ A_im,
    const float* __restrict__ C_re, const float* __restrict__ C_im,
    int layer) {
    int bdg = blockIdx.x;
    int lane = threadIdx.x;
    int s = lane >> 3, j = lane & 7;
    int d = (bdg & 31) * 8 + s;

    float wr[8], wi[8], ckr[8], cki[8];
    s4d_init(layer, d, j, log_dt, A_re, A_im, C_re, C_im, wr, wi, ckr, cki);
    // w^256 by 8 squarings
    #pragma unroll
    for (int t = 0; t < 8; ++t) {
        #pragma unroll
        for (int k = 0; k < 8; ++k) {
            float r = wr[k], i2 = wi[k];
            wr[k] = r * r - i2 * i2;
            wi[k] = 2.0f * r * i2;
        }
    }
    float cr[8], ci[8];
    #pragma unroll
    for (int k = 0; k < 8; ++k) { cr[k] = 0.f; ci[k] = 0.f; }

    for (int sg = 0; sg < NSEG; ++sg) {
        float* p = xbuf + ((size_t)(bdg * NSEG + sg) * 64 + lane) * 16;
        float4 x0 = *(const float4*)(p + 0);
        float4 x1 = *(const float4*)(p + 4);
        float4 x2 = *(const float4*)(p + 8);
        float4 x3 = *(const float4*)(p + 12);
        *(float4*)(p + 0)  = make_float4(cr[0], cr[1], cr[2], cr[3]);
        *(float4*)(p + 4)  = make_float4(cr[4], cr[5], cr[6], cr[7]);
        *(float4*)(p + 8)  = make_float4(ci[0], ci[1], ci[2], ci[3]);
        *(float4*)(p + 12) = make_float4(ci[4], ci[5], ci[6], ci[7]);
        float xsr[8] = {x0.x, x0.y, x0.z, x0.w, x1.x, x1.y, x1.z, x1.w};
        float xsi[8] = {x2.x, x2.y, x2.z, x2.w, x3.x, x3.y, x3.z, x3.w};
        #pragma unroll
        for (int k = 0; k < 8; ++k) {
            float tr = fmaf(wr[k], cr[k], fmaf(-wi[k], ci[k], xsr[k]));
            float ti = fmaf(wr[k], ci[k], fmaf(wi[k], cr[k], xsi[k]));
            cr[k] = tr; ci[k] = ti;
        }
    }
}

// ---------------------------------------------------------------------------
// 3c) S3: add carry correction 2*Re(sum Ck w^{delta+1} x_in), gelu, store bf16
// ---------------------------------------------------------------------------
#define FIX_STEP(KK)                                                   \
  {                                                                    \
    float p0 = 0.f, p1 = 0.f;                                          \
    _Pragma("unroll")                                                  \
    for (int k = 0; k < 8; ++k) {                                      \
      float nvr = vr[k] * wr[k] - vi[k] * wi[k];                       \
      float nvi = vr[k] * wi[k] + vi[k] * wr[k];                       \
      vr[k] = nvr; vi[k] = nvi;                                        \
      p0 = fmaf(ckr[k], nvr, p0);                                      \
      p1 = fmaf(cki[k], nvi, p1);                                      \
    }                                                                  \
    float p = p0 - p1;                                                 \
    p += __shfl_xor(p, 1);                                             \
    p += __shfl_xor(p, 2);                                             \
    p += __shfl_xor(p, 4);                                             \
    if ((KK) == j) creg = p;                                           \
  }

__global__ __launch_bounds__(64) void scan_fix_kernel(
    __hip_bfloat16* __restrict__ Yb, const float* __restrict__ xbuf,
    const float* __restrict__ log_dt,
    const float* __restrict__ A_re, const float* __restrict__ A_im,
    const float* __restrict__ C_re, const float* __restrict__ C_im,
    int layer) {
    int bdg = blockIdx.x;
    int seg = blockIdx.y;
    int b = bdg >> 5, dg = bdg & 31;
    int lane = threadIdx.x;
    int s = lane >> 3, j = lane & 7;
    int d = dg * 8 + s;

    int segstart = seg * 256;
    __hip_bfloat16* y_base = Yb + ((size_t)b * LTR + segstart) * DM + d;

    if (seg == 0) {   // zero incoming state: just gelu
        for (int g = 0; g < 32; ++g) {
            size_t off = (size_t)(g * 8 + j) * DM;
            float yl = __bfloat162float(y_base[off]);
            y_base[off] = __float2bfloat16(gelu_tanh(yl));
        }
        return;
    }

    float wr[8], wi[8], ckr[8], cki[8];
    s4d_init(layer, d, j, log_dt, A_re, A_im, C_re, C_im, wr, wi, ckr, cki);

    const float* xp_ = xbuf + ((size_t)(bdg * NSEG + seg) * 64 + lane) * 16;
    float4 x0 = *(const float4*)(xp_ + 0);
    float4 x1 = *(const float4*)(xp_ + 4);
    float4 x2 = *(const float4*)(xp_ + 8);
    float4 x3 = *(const float4*)(xp_ + 12);
    float vr[8] = {x0.x, x0.y, x0.z, x0.w, x1.x, x1.y, x1.z, x1.w};
    float vi[8] = {x2.x, x2.y, x2.z, x2.w, x3.x, x3.y, x3.z, x3.w};

    int nfull = 32;
    float creg = 0.0f;
    for (int g = 0; g < nfull; ++g) {
        FIX_STEP(0) FIX_STEP(1) FIX_STEP(2) FIX_STEP(3)
        FIX_STEP(4) FIX_STEP(5) FIX_STEP(6) FIX_STEP(7)
        size_t off = (size_t)(g * 8 + j) * DM;
        float yl = __bfloat162float(y_base[off]);
        y_base[off] = __float2bfloat16(gelu_tanh(fmaf(2.0f, creg, yl)));
    }
    if (seg == NSEG - 1) {   // tail 7 steps
        FIX_STEP(0) FIX_STEP(1) FIX_STEP(2) FIX_STEP(3)
        FIX_STEP(4) FIX_STEP(5) FIX_STEP(6)
        if (j < 7) {
            size_t off = (size_t)(256 + j) * DM;
            float yl = __bfloat162float(y_base[off]);
            y_base[off] = __float2bfloat16(gelu_tanh(fmaf(2.0f, creg, yl)));
        }
    }
}

// ---------------------------------------------------------------------------
// 4) MFMA bf16 GEMM + GLU + residual (in-place U) + BN partial stats
//    block: 128 l x 64 pair-channels (both halves). 4 waves, wave = 32 l.
// ---------------------------------------------------------------------------
__global__ __launch_bounds__(256) void gemm_glu_mfma_kernel(
    const __hip_bfloat16* __restrict__ Yb, float* __restrict__ U,
    const __hip_bfloat16* __restrict__ Wt, const float* __restrict__ out_b,
    float* __restrict__ stats, int layer) {
    int bx = blockIdx.x, by = blockIdx.y, b = blockIdx.z;
    int tid = threadIdx.x;
    int wave = tid >> 6, lane = tid & 63;
    int lm = lane & 15, quad = lane >> 4;
    int lbase = bx * 128 + wave * 32;

    const __hip_bfloat16* Yb_b = Yb + (size_t)b * LTR * DM;
    const __hip_bfloat16* ap0 = Yb_b + (size_t)(lbase + lm) * DM + quad * 8;
    const __hip_bfloat16* ap1 = Yb_b + (size_t)(lbase + 16 + lm) * DM + quad * 8;
    const __hip_bfloat16* bp[8];
    #pragma unroll
    for (int nt = 0; nt < 4; ++nt)
        #pragma unroll
        for (int h = 0; h < 2; ++h) {
            int e = by * 64 + nt * 16 + lm + h * 256;
            bp[nt * 2 + h] = Wt + ((size_t)layer * 512 + e) * 256 + quad * 8;
        }

    floatx4 acc[2][4][2];
    floatx4 zf = {0.f, 0.f, 0.f, 0.f};
    #pragma unroll
    for (int mt = 0; mt < 2; ++mt)
        #pragma unroll
        for (int nt = 0; nt < 4; ++nt)
            #pragma unroll
            for (int h = 0; h < 2; ++h) acc[mt][nt][h] = zf;

    for (int k0 = 0; k0 < 256; k0 += 32) {
        short8 a0 = *(const short8*)(ap0 + k0);
        short8 a1 = *(const short8*)(ap1 + k0);
        short8 bv[8];
        #pragma unroll
        for (int i = 0; i < 8; ++i) bv[i] = *(const short8*)(bp[i] + k0);
        #pragma unroll
        for (int nt = 0; nt < 4; ++nt)
            #pragma unroll
            for (int h = 0; h < 2; ++h) {
                acc[0][nt][h] = __builtin_amdgcn_mfma_f32_16x16x32_bf16(
                    a0, bv[nt * 2 + h], acc[0][nt][h], 0, 0, 0);
                acc[1][nt][h] = __builtin_amdgcn_mfma_f32_16x16x32_bf16(
                    a1, bv[nt * 2 + h], acc[1][nt][h], 0, 0, 0);
            }
    }

    // epilogue: GLU + residual + stats.  C layout: n=lane&15, m=quad*4+reg
    const float* bl = out_b + layer * 512;
    float sp[4], sq[4];
    #pragma unroll
    for (int nt = 0; nt < 4; ++nt) { sp[nt] = 0.f; sq[nt] = 0.f; }

    #pragma unroll
    for (int nt = 0; nt < 4; ++nt) {
        int ch = by * 64 + nt * 16 + lm;
        float bz1 = bl[ch], bz2 = bl[256 + ch];
        float* urow = U + ((size_t)b * DM + ch) * LTP;
        #pragma unroll
        for (int mt = 0; mt < 2; ++mt) {
            int l0q = lbase + mt * 16 + quad * 4;
            floatx4 z1v = acc[mt][nt][0];
            floatx4 z2v = acc[mt][nt][1];
            if (l0q + 4 <= LT) {
                float4 uv = *(const float4*)(urow + l0q);
                float h0 = uv.x + (z1v[0] + bz1) * sigmoidf_(z2v[0] + bz2);
                float h1 = uv.y + (z1v[1] + bz1) * sigmoidf_(z2v[1] + bz2);
                float h2 = uv.z + (z1v[2] + bz1) * sigmoidf_(z2v[2] + bz2);
                float h3 = uv.w + (z1v[3] + bz1) * sigmoidf_(z2v[3] + bz2);
                *(float4*)(urow + l0q) = make_float4(h0, h1, h2, h3);
                sp[nt] += (h0 + h1) + (h2 + h3);
                sq[nt] += (h0 * h0 + h1 * h1) + (h2 * h2 + h3 * h3);
            } else {
                #pragma unroll
                for (int r = 0; r < 4; ++r) {
                    int l = l0q + r;
                    if (l < LT) {
                        float uvv = urow[l];
                        float hh = uvv + (z1v[r] + bz1) * sigmoidf_(z2v[r] + bz2);
                        urow[l] = hh;
                        sp[nt] += hh; sq[nt] += hh * hh;
                    }
                }
            }
        }
    }
    #pragma unroll
    for (int nt = 0; nt < 4; ++nt) {
        sp[nt] += __shfl_xor(sp[nt], 16); sp[nt] += __shfl_xor(sp[nt], 32);
        sq[nt] += __shfl_xor(sq[nt], 16); sq[nt] += __shfl_xor(sq[nt], 32);
    }
    __shared__ float sred[2][4][4][16];
    if (quad == 0) {
        #pragma unroll
        for (int nt = 0; nt < 4; ++nt) {
            sred[0][wave][nt][lm] = sp[nt];
            sred[1][wave][nt][lm] = sq[nt];
        }
    }
    __syncthreads();
    if (tid < 128) {
        int which = tid >> 6, idx = tid & 63;
        int nt = idx >> 4, lm2 = idx & 15;
        float v = sred[which][0][nt][lm2] + sred[which][1][nt][lm2]
                + sred[which][2][nt][lm2] + sred[which][3][nt][lm2];
        atomicAdd(&stats[which * DM + by * 64 + nt * 16 + lm2], v);
    }
}

// ---------------------------------------------------------------------------
// 5) BatchNorm normalize (in-place on U)
// ---------------------------------------------------------------------------
__global__ __launch_bounds__(256) void bn_kernel(
    float* __restrict__ U, const float* __restrict__ stats,
    const float* __restrict__ gamma, const float* __restrict__ beta, int layer) {
    int l = blockIdx.x * 256 + threadIdx.x;
    int d = blockIdx.y, b = blockIdx.z;
    if (l >= LT) return;
    float s = stats[d], q = stats[DM + d];
    float mean = s * (1.0f / NTOT);
    float var  = q * (1.0f / NTOT) - mean * mean;
    float sc = rsqrtf(var + 1e-5f) * gamma[layer * DM + d];
    float sh = beta[layer * DM + d] - mean * sc;
    size_t idx = ((size_t)b * DM + d) * LTP + l;
    U[idx] = fmaf(U[idx], sc, sh);
}

// ---------------------------------------------------------------------------
// 6) head
// ---------------------------------------------------------------------------
__global__ __launch_bounds__(128) void head_kernel(
    const float* __restrict__ U,
    const float* __restrict__ W1, const float* __restrict__ b1,
    const float* __restrict__ W2, const float* __restrict__ b2,
    float* __restrict__ out) {
    int hh = blockIdx.x;
    int b  = blockIdx.y;
    int j  = threadIdx.x;
    int l  = (L_ - 1) + hh;
    const float* urow = U + ((size_t)b * DM) * LTP + l;
    float a = b1[j];
    for (int k = 0; k < DM; ++k)
        a = fmaf(urow[(size_t)k * LTP], W1[k * 128 + j], a);
    float hs = a * sigmoidf_(a);
    float v = hs * W2[j];
    v += __shfl_xor(v, 1);
    v += __shfl_xor(v, 2);
    v += __shfl_xor(v, 4);
    v += __shfl_xor(v, 8);
    v += __shfl_xor(v, 16);
    v += __shfl_xor(v, 32);
    __shared__ float partial[2];
    if ((j & 63) == 0) partial[j >> 6] = v;
    __syncthreads();
    if (j == 0) out[b * H_ + hh] = partial[0] + partial[1] + b2[0];
}

// ---------------------------------------------------------------------------
extern "C" void kernel_launch(void* const* d_in, const int* in_sizes, int n_in,
                              void* d_out, int out_size, void* d_ws, size_t ws_size,
                              hipStream_t stream) {
    (void)in_sizes; (void)n_in; (void)out_size; (void)ws_size;
    const float* x_past      = (const float*)d_in[0];
    const float* noisy       = (const float*)d_in[1];
    const float* t_in        = (const float*)d_in[2];
    const float* x_future    = (const float*)d_in[3];
    const float* static_attr = (const float*)d_in[4];
    const float* freqs       = (const float*)d_in[5];
    const float* phases      = (const float*)d_in[6];
    const float* in_W        = (const float*)d_in[7];
    const float* in_b        = (const float*)d_in[8];
    const float* tm_W1       = (const float*)d_in[9];
    const float* tm_b1       = (const float*)d_in[10];
    const float* tm_W2       = (const float*)d_in[11];
    const float* tm_b2       = (const float*)d_in[12];
    const float* log_dt      = (const float*)d_in[13];
    const float* A_re        = (const float*)d_in[14];
    const float* A_im        = (const float*)d_in[15];
    const float* C_re        = (const float*)d_in[16];
    const float* C_im        = (const float*)d_in[17];
    const float* Dp          = (const float*)d_in[18];
    const float* out_W       = (const float*)d_in[19];
    const float* out_b       = (const float*)d_in[20];
    const float* bn_gamma    = (const float*)d_in[21];
    const float* bn_beta     = (const float*)d_in[22];
    const float* head_W1     = (const float*)d_in[23];
    const float* head_b1     = (const float*)d_in[24];
    const float* head_W2     = (const float*)d_in[25];
    const float* head_b2     = (const float*)d_in[26];

    char* ws = (char*)d_ws;
    const size_t U_OFF  = 1u << 20;
    const size_t U_BYT  = (size_t)B_ * DM * LTP * 4;          // 67,371,008
    const size_t Y_OFF  = U_OFF + U_BYT;
    const size_t Y_BYT  = (size_t)B_ * LTR * DM * 2;          // 35,651,584
    const size_t X_OFF  = Y_OFF + Y_BYT;
    const size_t X_BYT  = (size_t)1024 * NSEG * 64 * 16 * 4;  // 33,554,432
    const size_t W_OFF  = X_OFF + X_BYT;

    float*          tb    = (float*)(ws);
    float*          stats = (float*)(ws + (64 << 10));
    float*          U     = (float*)(ws + U_OFF);
    __hip_bfloat16* Yb    = (__hip_bfloat16*)(ws + Y_OFF);
    float*          xbuf  = (float*)(ws + X_OFF);
    __hip_bfloat16* Wt    = (__hip_bfloat16*)(ws + W_OFF);

    time_mlp_kernel<<<dim3(B_), 256, 0, stream>>>(
        t_in, freqs, phases, tm_W1, tm_b1, tm_W2, tm_b2, tb);

    wt_prep_kernel<<<dim3(NL * 256), 256, 0, stream>>>(out_W, Wt);

    input_proj_kernel<<<dim3((LT + 255) / 256, B_), 256, 0, stream>>>(
        x_past, noisy, x_future, static_attr, in_W, in_b, tb, U);

    for (int layer = 0; layer < NL; ++layer) {
        scan_local_kernel<<<dim3(B_ * 32, NSEG), 64, 0, stream>>>(
            U, Yb, xbuf, log_dt, A_re, A_im, C_re, C_im, Dp, layer);
        scan_combine_kernel<<<dim3(B_ * 32), 64, 0, stream>>>(
            xbuf, log_dt, A_re, A_im, C_re, C_im, layer);
        scan_fix_kernel<<<dim3(B_ * 32, NSEG), 64, 0, stream>>>(
            Yb, xbuf, log_dt, A_re, A_im, C_re, C_im, layer);
        hipMemsetAsync(stats, 0, 2 * DM * sizeof(float), stream);
        gemm_glu_mfma_kernel<<<dim3(17, 4, B_), 256, 0, stream>>>(
            Yb, U, Wt, out_b, stats, layer);
        bn_kernel<<<dim3((LT + 255) / 256, DM, B_), 256, 0, stream>>>(
            U, stats, bn_gamma, bn_beta, layer);
    }

    head_kernel<<<dim3(H_, B_), 128, 0, stream>>>(
        U, head_W1, head_b1, head_W2, head_b2, (float*)d_out);
}

// Round 4
// 2102.108 us; speedup vs baseline: 1.9258x; 1.2752x over previous
//
#include <hip/hip_runtime.h>
#include <hip/hip_bf16.h>
#include <math.h>

#define B_   32
#define L_   2048
#define H_   8
#define DMET 16
#define SDIM 27
#define DM   256
#define NL   4
#define DS   64
#define TE   256
#define LT   2055          // L + H - 1
#define LTP  2056          // padded stride for U (fp32, [b][d][l])
#define LTR  2176          // padded l rows for Yb (17*128), bf16 [b][l][d]
#define NSEG 8             // segments: 7 x 256 + 1 x 263
#define NTOT (B_ * LT)

typedef __attribute__((ext_vector_type(8))) short short8;
typedef __attribute__((ext_vector_type(4))) float floatx4;
typedef __attribute__((ext_vector_type(2))) float float2v;

__device__ __forceinline__ float2v pk_fma(float2v a, float2v b, float2v c) {
#if __has_builtin(__builtin_elementwise_fma)
    return __builtin_elementwise_fma(a, b, c);   // -> v_pk_fma_f32
#else
    float2v r; r.x = fmaf(a.x, b.x, c.x); r.y = fmaf(a.y, b.y, c.y); return r;
#endif
}

__device__ __forceinline__ float sigmoidf_(float x) {
    return 1.0f / (1.0f + expf(-x));
}

__device__ __forceinline__ float gelu_tanh(float x) {
    const float c0 = 0.7978845608028654f; // sqrt(2/pi)
    float x3 = x * x * x;
    float t = tanhf(c0 * (x + 0.044715f * x3));
    return 0.5f * x * (1.0f + t);
}

// shared S4D per-state init: w = exp(dt*A), Ck = (C)*(expm1(dt*A)/A)
__device__ __forceinline__ void s4d_init(
    int layer, int d, int j,
    const float* __restrict__ log_dt,
    const float* __restrict__ A_re, const float* __restrict__ A_im,
    const float* __restrict__ C_re, const float* __restrict__ C_im,
    float* wr, float* wi, float* ckr, float* cki) {
    float dt = expf(log_dt[layer * DM + d]);
    size_t abase = ((size_t)layer * DM + d) * DS;
    #pragma unroll
    for (int k = 0; k < 8; ++k) {
        int n = j * 8 + k;
        float Ar = A_re[abase + n], Ai = A_im[abase + n];
        float Cr = C_re[abase + n], Ci = C_im[abase + n];
        float dr = dt * Ar, di = dt * Ai;
        float e = expf(dr);
        float w_r = e * cosf(di), w_i = e * sinf(di);
        wr[k] = w_r; wi[k] = w_i;
        float mr = w_r - 1.0f, mi = w_i;           // expm1(dt*A)
        float den = 1.0f / (Ar * Ar + Ai * Ai);
        float qr = (mr * Ar + mi * Ai) * den;      // expm1(dtA)/A
        float qi = (mi * Ar - mr * Ai) * den;
        ckr[k] = Cr * qr - Ci * qi;
        cki[k] = Cr * qi + Ci * qr;
    }
}

// ---------------------------------------------------------------------------
// 1) time MLP
// ---------------------------------------------------------------------------
__global__ __launch_bounds__(256) void time_mlp_kernel(
    const float* __restrict__ t, const float* __restrict__ freqs,
    const float* __restrict__ phases,
    const float* __restrict__ W1, const float* __restrict__ b1,
    const float* __restrict__ W2, const float* __restrict__ b2,
    float* __restrict__ tb) {
    int b = blockIdx.x;
    int tid = threadIdx.x;
    __shared__ float f[TE];
    __shared__ float hid[2 * TE];
    float tv = t[b];
    f[tid] = cosf(fmaf(tv, freqs[tid], phases[tid])) * 1.4142135623730951f;
    __syncthreads();
    float a0 = b1[tid], a1 = b1[tid + TE];
    for (int k = 0; k < TE; ++k) {
        float fk = f[k];
        a0 = fmaf(fk, W1[k * 2 * TE + tid], a0);
        a1 = fmaf(fk, W1[k * 2 * TE + tid + TE], a1);
    }
    hid[tid]      = a0 * sigmoidf_(a0);
    hid[tid + TE] = a1 * sigmoidf_(a1);
    __syncthreads();
    float acc = b2[tid];
    for (int j = 0; j < 2 * TE; ++j)
        acc = fmaf(hid[j], W2[j * DM + tid], acc);
    tb[b * DM + tid] = acc;
}

// ---------------------------------------------------------------------------
// 1b) transpose out_W [NL][256][512] fp32 -> Wt bf16 [NL][512][256]
// ---------------------------------------------------------------------------
__global__ __launch_bounds__(256) void wt_prep_kernel(
    const float* __restrict__ out_W, __hip_bfloat16* __restrict__ Wt) {
    int bid = blockIdx.x;            // layer*256 + k
    int layer = bid >> 8, k = bid & 255;
    int e = threadIdx.x;
    const float* src = out_W + ((size_t)layer * 256 + k) * 512;
    #pragma unroll
    for (int q = 0; q < 2; ++q) {
        int ee = e + q * 256;
        Wt[((size_t)layer * 512 + ee) * 256 + k] = __float2bfloat16(src[ee]);
    }
}

// ---------------------------------------------------------------------------
// 2) input projection -> U[b][d][l]
// ---------------------------------------------------------------------------
__global__ __launch_bounds__(256) void input_proj_kernel(
    const float* __restrict__ xp, const float* __restrict__ nf,
    const float* __restrict__ xf, const float* __restrict__ sa,
    const float* __restrict__ inW, const float* __restrict__ inb,
    const float* __restrict__ tb, float* __restrict__ U) {
    int b  = blockIdx.y;
    int l0 = blockIdx.x * 256;
    int tx = threadIdx.x;
    int l  = l0 + tx;

    __shared__ float feats[256][18];
    __shared__ float Ws[17][DM];
    __shared__ float sdot[DM];
    __shared__ float tbs[DM];
    __shared__ float sstat[SDIM];

    if (tx < SDIM) sstat[tx] = sa[b * SDIM + tx];
    for (int k = 0; k < 17; ++k) Ws[k][tx] = inW[k * DM + tx];
    tbs[tx] = tb[b * DM + tx];

    bool valid = (l < LT);
    if (valid) {
        const float* src = (l < L_) ? &xp[((size_t)b * L_ + l) * DMET]
                                    : &xf[((size_t)b * (H_ - 1) + (l - L_)) * DMET];
        #pragma unroll
        for (int k = 0; k < DMET; ++k) feats[tx][k] = src[k];
        feats[tx][16] = (l >= L_ - 1) ? nf[b * H_ + (l - (L_ - 1))] : 0.0f;
    }
    __syncthreads();

    float sd = 0.0f;
    for (int k = 0; k < SDIM; ++k)
        sd = fmaf(sstat[k], inW[(17 + k) * DM + tx], sd);
    sdot[tx] = sd;
    __syncthreads();

    if (!valid) return;
    bool cond = (l >= L_ - 1);
    size_t base = ((size_t)b * DM) * LTP + l;
    for (int d = 0; d < DM; ++d) {
        float acc = inb[d] + sdot[d] + (cond ? tbs[d] : 0.0f);
        #pragma unroll
        for (int k = 0; k < 17; ++k)
            acc = fmaf(feats[tx][k], Ws[k][d], acc);
        U[base + (size_t)d * LTP] = acc;
    }
}

// ---------------------------------------------------------------------------
// 3a) S1: per-segment local recurrence from zero state (packed fp32 states).
// ---------------------------------------------------------------------------
#define SCAN_STEP(UVAL, KK)                                            \
  {                                                                    \
    float u = (UVAL);                                                  \
    float2v u2 = {u, u};                                               \
    float2v p0 = {0.f, 0.f}, p1 = {0.f, 0.f};                          \
    _Pragma("unroll")                                                  \
    for (int q = 0; q < 4; ++q) {                                      \
      float2v nr = pk_fma(wr2[q], xr2[q], pk_fma(nwi2[q], xi2[q], u2));\
      float2v ni = pk_fma(wi2[q], xr2[q], wr2[q] * xi2[q]);            \
      xr2[q] = nr; xi2[q] = ni;                                        \
      p0 = pk_fma(ckr2[q], nr, p0);                                    \
      p1 = pk_fma(cki2[q], ni, p1);                                    \
    }                                                                  \
    float2v pd = p0 - p1;                                              \
    float p = pd.x + pd.y;                                             \
    p += __shfl_xor(p, 1);                                             \
    p += __shfl_xor(p, 2);                                             \
    p += __shfl_xor(p, 4);                                             \
    float yv = fmaf(2.0f, p, Dd * u);                                  \
    if ((KK) == j) yreg = yv;                                          \
  }

__global__ __launch_bounds__(64) void scan_local_kernel(
    const float* __restrict__ U, __hip_bfloat16* __restrict__ Yb,
    float* __restrict__ xbuf,
    const float* __restrict__ log_dt,
    const float* __restrict__ A_re, const float* __restrict__ A_im,
    const float* __restrict__ C_re, const float* __restrict__ C_im,
    const float* __restrict__ Dp, int layer) {
    int bdg = blockIdx.x;               // b*32 + dg
    int seg = blockIdx.y;
    int b = bdg >> 5, dg = bdg & 31;
    int lane = threadIdx.x;
    int s = lane >> 3, j = lane & 7;
    int d = dg * 8 + s;

    float wr[8], wi[8], ckr[8], cki[8];
    s4d_init(layer, d, j, log_dt, A_re, A_im, C_re, C_im, wr, wi, ckr, cki);
    float Dd = Dp[layer * DM + d];

    // pack adjacent states into float2 (pairs 2q, 2q+1)
    float2v wr2[4], wi2[4], nwi2[4], ckr2[4], cki2[4], xr2[4], xi2[4];
    #pragma unroll
    for (int q = 0; q < 4; ++q) {
        wr2[q]  = (float2v){wr[2*q], wr[2*q+1]};
        wi2[q]  = (float2v){wi[2*q], wi[2*q+1]};
        nwi2[q] = (float2v){-wi[2*q], -wi[2*q+1]};
        ckr2[q] = (float2v){ckr[2*q], ckr[2*q+1]};
        cki2[q] = (float2v){cki[2*q], cki[2*q+1]};
        xr2[q]  = (float2v){0.f, 0.f};
        xi2[q]  = (float2v){0.f, 0.f};
    }

    int segstart = seg * 256;
    const float* u_row = U + ((size_t)b * DM + d) * LTP + segstart;
    __hip_bfloat16* y_base = Yb + ((size_t)b * LTR + segstart) * DM + d;

    float yreg = 0.0f;
    float4 ua = *(const float4*)(u_row);
    float4 ub = *(const float4*)(u_row + 4);

    for (int g = 0; g < 32; ++g) {
        float u0=ua.x,u1=ua.y,u2=ua.z,u3=ua.w,u4=ub.x,u5=ub.y,u6=ub.z,u7=ub.w;
        if (g < 31) {
            const float* np = u_row + (g + 1) * 8;
            ua = *(const float4*)np; ub = *(const float4*)(np + 4);
        } else if (seg == NSEG - 1) {
            const float* np = u_row + 256;
            ua = *(const float4*)np; ub = *(const float4*)(np + 4);
        }
        SCAN_STEP(u0, 0) SCAN_STEP(u1, 1) SCAN_STEP(u2, 2) SCAN_STEP(u3, 3)
        SCAN_STEP(u4, 4) SCAN_STEP(u5, 5) SCAN_STEP(u6, 6) SCAN_STEP(u7, 7)
        y_base[(size_t)(g * 8 + j) * DM] = __float2bfloat16(yreg);
    }
    if (seg == NSEG - 1) {   // tail: 7 more steps (l = 2048..2054)
        float u0=ua.x,u1=ua.y,u2=ua.z,u3=ua.w,u4=ub.x,u5=ub.y,u6=ub.z;
        SCAN_STEP(u0, 0) SCAN_STEP(u1, 1) SCAN_STEP(u2, 2) SCAN_STEP(u3, 3)
        SCAN_STEP(u4, 4) SCAN_STEP(u5, 5) SCAN_STEP(u6, 6)
        if (j < 7) y_base[(size_t)(256 + j) * DM] = __float2bfloat16(yreg);
    }
    // store local end-state (k order 0..7)
    float* xp_ = xbuf + ((size_t)(bdg * NSEG + seg) * 64 + lane) * 16;
    *(float4*)(xp_ + 0)  = make_float4(xr2[0].x, xr2[0].y, xr2[1].x, xr2[1].y);
    *(float4*)(xp_ + 4)  = make_float4(xr2[2].x, xr2[2].y, xr2[3].x, xr2[3].y);
    *(float4*)(xp_ + 8)  = make_float4(xi2[0].x, xi2[0].y, xi2[1].x, xi2[1].y);
    *(float4*)(xp_ + 12) = make_float4(xi2[2].x, xi2[2].y, xi2[3].x, xi2[3].y);
}

// ---------------------------------------------------------------------------
// 3b) S2: combine segment states in place: xbuf[seg] <- incoming state x_in
// ---------------------------------------------------------------------------
__global__ __launch_bounds__(64) void scan_combine_kernel(
    float* __restrict__ xbuf,
    const float* __restrict__ log_dt,
    const float* __restrict__ A_re, const float* __restrict__ A_im,
    const float* __restrict__ C_re, const float* __restrict__ C_im,
    int layer) {
    int bdg = blockIdx.x;
    int lane = threadIdx.x;
    int s = lane >> 3, j = lane & 7;
    int d = (bdg & 31) * 8 + s;

    float wr[8], wi[8], ckr[8], cki[8];
    s4d_init(layer, d, j, log_dt, A_re, A_im, C_re, C_im, wr, wi, ckr, cki);
    // w^256 by 8 squarings
    #pragma unroll
    for (int t = 0; t < 8; ++t) {
        #pragma unroll
        for (int k = 0; k < 8; ++k) {
            float r = wr[k], i2 = wi[k];
            wr[k] = r * r - i2 * i2;
            wi[k] = 2.0f * r * i2;
        }
    }
    float cr[8], ci[8];
    #pragma unroll
    for (int k = 0; k < 8; ++k) { cr[k] = 0.f; ci[k] = 0.f; }

    for (int sg = 0; sg < NSEG; ++sg) {
        float* p = xbuf + ((size_t)(bdg * NSEG + sg) * 64 + lane) * 16;
        float4 x0 = *(const float4*)(p + 0);
        float4 x1 = *(const float4*)(p + 4);
        float4 x2 = *(const float4*)(p + 8);
        float4 x3 = *(const float4*)(p + 12);
        *(float4*)(p + 0)  = make_float4(cr[0], cr[1], cr[2], cr[3]);
        *(float4*)(p + 4)  = make_float4(cr[4], cr[5], cr[6], cr[7]);
        *(float4*)(p + 8)  = make_float4(ci[0], ci[1], ci[2], ci[3]);
        *(float4*)(p + 12) = make_float4(ci[4], ci[5], ci[6], ci[7]);
        float xsr[8] = {x0.x, x0.y, x0.z, x0.w, x1.x, x1.y, x1.z, x1.w};
        float xsi[8] = {x2.x, x2.y, x2.z, x2.w, x3.x, x3.y, x3.z, x3.w};
        #pragma unroll
        for (int k = 0; k < 8; ++k) {
            float tr = fmaf(wr[k], cr[k], fmaf(-wi[k], ci[k], xsr[k]));
            float ti = fmaf(wr[k], ci[k], fmaf(wi[k], cr[k], xsi[k]));
            cr[k] = tr; ci[k] = ti;
        }
    }
}

// ---------------------------------------------------------------------------
// 3c) S3: carry correction via premultiplied rotor a = Ck o (w o x_in);
//     per step: c = Re(sum a), then rotate a by w. Packed fp32.
// ---------------------------------------------------------------------------
#define FIX_STEP(KK)                                                   \
  {                                                                    \
    float2v p2 = (ar2[0] + ar2[1]) + (ar2[2] + ar2[3]);                \
    float p = p2.x + p2.y;                                             \
    p += __shfl_xor(p, 1);                                             \
    p += __shfl_xor(p, 2);                                             \
    p += __shfl_xor(p, 4);                                             \
    if ((KK) == j) creg = p;                                           \
    _Pragma("unroll")                                                  \
    for (int q = 0; q < 4; ++q) {                                      \
      float2v nr = pk_fma(nwi2[q], ai2[q], wr2[q] * ar2[q]);           \
      float2v ni = pk_fma(wi2[q], ar2[q], wr2[q] * ai2[q]);            \
      ar2[q] = nr; ai2[q] = ni;                                        \
    }                                                                  \
  }

__global__ __launch_bounds__(64) void scan_fix_kernel(
    __hip_bfloat16* __restrict__ Yb, const float* __restrict__ xbuf,
    const float* __restrict__ log_dt,
    const float* __restrict__ A_re, const float* __restrict__ A_im,
    const float* __restrict__ C_re, const float* __restrict__ C_im,
    int layer) {
    int bdg = blockIdx.x;
    int seg = blockIdx.y;
    int b = bdg >> 5, dg = bdg & 31;
    int lane = threadIdx.x;
    int s = lane >> 3, j = lane & 7;
    int d = dg * 8 + s;

    int segstart = seg * 256;
    __hip_bfloat16* y_base = Yb + ((size_t)b * LTR + segstart) * DM + d;

    if (seg == 0) {   // zero incoming state: just gelu
        for (int g = 0; g < 32; ++g) {
            size_t off = (size_t)(g * 8 + j) * DM;
            float yl = __bfloat162float(y_base[off]);
            y_base[off] = __float2bfloat16(gelu_tanh(yl));
        }
        return;
    }

    float wr[8], wi[8], ckr[8], cki[8];
    s4d_init(layer, d, j, log_dt, A_re, A_im, C_re, C_im, wr, wi, ckr, cki);

    const float* xp_ = xbuf + ((size_t)(bdg * NSEG + seg) * 64 + lane) * 16;
    float4 x0 = *(const float4*)(xp_ + 0);
    float4 x1 = *(const float4*)(xp_ + 4);
    float4 x2 = *(const float4*)(xp_ + 8);
    float4 x3 = *(const float4*)(xp_ + 12);
    float vr0[8] = {x0.x, x0.y, x0.z, x0.w, x1.x, x1.y, x1.z, x1.w};
    float vi0[8] = {x2.x, x2.y, x2.z, x2.w, x3.x, x3.y, x3.z, x3.w};

    // a = Ck o (w o x_in): correction at local step 0 is Re(sum a)
    float2v wr2[4], wi2[4], nwi2[4], ar2[4], ai2[4];
    #pragma unroll
    for (int q = 0; q < 4; ++q) {
        float ar_[2], ai_[2];
        #pragma unroll
        for (int h = 0; h < 2; ++h) {
            int k = 2 * q + h;
            float tr = wr[k] * vr0[k] - wi[k] * vi0[k];
            float ti = wr[k] * vi0[k] + wi[k] * vr0[k];
            ar_[h] = ckr[k] * tr - cki[k] * ti;
            ai_[h] = ckr[k] * ti + cki[k] * tr;
        }
        wr2[q]  = (float2v){wr[2*q], wr[2*q+1]};
        wi2[q]  = (float2v){wi[2*q], wi[2*q+1]};
        nwi2[q] = (float2v){-wi[2*q], -wi[2*q+1]};
        ar2[q]  = (float2v){ar_[0], ar_[1]};
        ai2[q]  = (float2v){ai_[0], ai_[1]};
    }

    float creg = 0.0f;
    for (int g = 0; g < 32; ++g) {
        FIX_STEP(0) FIX_STEP(1) FIX_STEP(2) FIX_STEP(3)
        FIX_STEP(4) FIX_STEP(5) FIX_STEP(6) FIX_STEP(7)
        size_t off = (size_t)(g * 8 + j) * DM;
        float yl = __bfloat162float(y_base[off]);
        y_base[off] = __float2bfloat16(gelu_tanh(fmaf(2.0f, creg, yl)));
    }
    if (seg == NSEG - 1) {   // tail 7 steps
        FIX_STEP(0) FIX_STEP(1) FIX_STEP(2) FIX_STEP(3)
        FIX_STEP(4) FIX_STEP(5) FIX_STEP(6)
        if (j < 7) {
            size_t off = (size_t)(256 + j) * DM;
            float yl = __bfloat162float(y_base[off]);
            y_base[off] = __float2bfloat16(gelu_tanh(fmaf(2.0f, creg, yl)));
        }
    }
}

// ---------------------------------------------------------------------------
// 4) MFMA bf16 GEMM + GLU + residual (in-place U) + BN partial stats
// ---------------------------------------------------------------------------
__global__ __launch_bounds__(256) void gemm_glu_mfma_kernel(
    const __hip_bfloat16* __restrict__ Yb, float* __restrict__ U,
    const __hip_bfloat16* __restrict__ Wt, const float* __restrict__ out_b,
    float* __restrict__ stats, int layer) {
    int bx = blockIdx.x, by = blockIdx.y, b = blockIdx.z;
    int tid = threadIdx.x;
    int wave = tid >> 6, lane = tid & 63;
    int lm = lane & 15, quad = lane >> 4;
    int lbase = bx * 128 + wave * 32;

    const __hip_bfloat16* Yb_b = Yb + (size_t)b * LTR * DM;
    const __hip_bfloat16* ap0 = Yb_b + (size_t)(lbase + lm) * DM + quad * 8;
    const __hip_bfloat16* ap1 = Yb_b + (size_t)(lbase + 16 + lm) * DM + quad * 8;
    const __hip_bfloat16* bp[8];
    #pragma unroll
    for (int nt = 0; nt < 4; ++nt)
        #pragma unroll
        for (int h = 0; h < 2; ++h) {
            int e = by * 64 + nt * 16 + lm + h * 256;
            bp[nt * 2 + h] = Wt + ((size_t)layer * 512 + e) * 256 + quad * 8;
        }

    floatx4 acc[2][4][2];
    floatx4 zf = {0.f, 0.f, 0.f, 0.f};
    #pragma unroll
    for (int mt = 0; mt < 2; ++mt)
        #pragma unroll
        for (int nt = 0; nt < 4; ++nt)
            #pragma unroll
            for (int h = 0; h < 2; ++h) acc[mt][nt][h] = zf;

    for (int k0 = 0; k0 < 256; k0 += 32) {
        short8 a0 = *(const short8*)(ap0 + k0);
        short8 a1 = *(const short8*)(ap1 + k0);
        short8 bv[8];
        #pragma unroll
        for (int i = 0; i < 8; ++i) bv[i] = *(const short8*)(bp[i] + k0);
        #pragma unroll
        for (int nt = 0; nt < 4; ++nt)
            #pragma unroll
            for (int h = 0; h < 2; ++h) {
                acc[0][nt][h] = __builtin_amdgcn_mfma_f32_16x16x32_bf16(
                    a0, bv[nt * 2 + h], acc[0][nt][h], 0, 0, 0);
                acc[1][nt][h] = __builtin_amdgcn_mfma_f32_16x16x32_bf16(
                    a1, bv[nt * 2 + h], acc[1][nt][h], 0, 0, 0);
            }
    }

    const float* bl = out_b + layer * 512;
    float sp[4], sq[4];
    #pragma unroll
    for (int nt = 0; nt < 4; ++nt) { sp[nt] = 0.f; sq[nt] = 0.f; }

    #pragma unroll
    for (int nt = 0; nt < 4; ++nt) {
        int ch = by * 64 + nt * 16 + lm;
        float bz1 = bl[ch], bz2 = bl[256 + ch];
        float* urow = U + ((size_t)b * DM + ch) * LTP;
        #pragma unroll
        for (int mt = 0; mt < 2; ++mt) {
            int l0q = lbase + mt * 16 + quad * 4;
            floatx4 z1v = acc[mt][nt][0];
            floatx4 z2v = acc[mt][nt][1];
            if (l0q + 4 <= LT) {
                float4 uv = *(const float4*)(urow + l0q);
                float h0 = uv.x + (z1v[0] + bz1) * sigmoidf_(z2v[0] + bz2);
                float h1 = uv.y + (z1v[1] + bz1) * sigmoidf_(z2v[1] + bz2);
                float h2 = uv.z + (z1v[2] + bz1) * sigmoidf_(z2v[2] + bz2);
                float h3 = uv.w + (z1v[3] + bz1) * sigmoidf_(z2v[3] + bz2);
                *(float4*)(urow + l0q) = make_float4(h0, h1, h2, h3);
                sp[nt] += (h0 + h1) + (h2 + h3);
                sq[nt] += (h0 * h0 + h1 * h1) + (h2 * h2 + h3 * h3);
            } else {
                #pragma unroll
                for (int r = 0; r < 4; ++r) {
                    int l = l0q + r;
                    if (l < LT) {
                        float uvv = urow[l];
                        float hh = uvv + (z1v[r] + bz1) * sigmoidf_(z2v[r] + bz2);
                        urow[l] = hh;
                        sp[nt] += hh; sq[nt] += hh * hh;
                    }
                }
            }
        }
    }
    #pragma unroll
    for (int nt = 0; nt < 4; ++nt) {
        sp[nt] += __shfl_xor(sp[nt], 16); sp[nt] += __shfl_xor(sp[nt], 32);
        sq[nt] += __shfl_xor(sq[nt], 16); sq[nt] += __shfl_xor(sq[nt], 32);
    }
    __shared__ float sred[2][4][4][16];
    if (quad == 0) {
        #pragma unroll
        for (int nt = 0; nt < 4; ++nt) {
            sred[0][wave][nt][lm] = sp[nt];
            sred[1][wave][nt][lm] = sq[nt];
        }
    }
    __syncthreads();
    if (tid < 128) {
        int which = tid >> 6, idx = tid & 63;
        int nt = idx >> 4, lm2 = idx & 15;
        float v = sred[which][0][nt][lm2] + sred[which][1][nt][lm2]
                + sred[which][2][nt][lm2] + sred[which][3][nt][lm2];
        atomicAdd(&stats[which * DM + by * 64 + nt * 16 + lm2], v);
    }
}

// ---------------------------------------------------------------------------
// 5) BatchNorm normalize (in-place on U)
// ---------------------------------------------------------------------------
__global__ __launch_bounds__(256) void bn_kernel(
    float* __restrict__ U, const float* __restrict__ stats,
    const float* __restrict__ gamma, const float* __restrict__ beta, int layer) {
    int l = blockIdx.x * 256 + threadIdx.x;
    int d = blockIdx.y, b = blockIdx.z;
    if (l >= LT) return;
    float s = stats[d], q = stats[DM + d];
    float mean = s * (1.0f / NTOT);
    float var  = q * (1.0f / NTOT) - mean * mean;
    float sc = rsqrtf(var + 1e-5f) * gamma[layer * DM + d];
    float sh = beta[layer * DM + d] - mean * sc;
    size_t idx = ((size_t)b * DM + d) * LTP + l;
    U[idx] = fmaf(U[idx], sc, sh);
}

// ---------------------------------------------------------------------------
// 6) head
// ---------------------------------------------------------------------------
__global__ __launch_bounds__(128) void head_kernel(
    const float* __restrict__ U,
    const float* __restrict__ W1, const float* __restrict__ b1,
    const float* __restrict__ W2, const float* __restrict__ b2,
    float* __restrict__ out) {
    int hh = blockIdx.x;
    int b  = blockIdx.y;
    int j  = threadIdx.x;
    int l  = (L_ - 1) + hh;
    const float* urow = U + ((size_t)b * DM) * LTP + l;
    float a = b1[j];
    for (int k = 0; k < DM; ++k)
        a = fmaf(urow[(size_t)k * LTP], W1[k * 128 + j], a);
    float hs = a * sigmoidf_(a);
    float v = hs * W2[j];
    v += __shfl_xor(v, 1);
    v += __shfl_xor(v, 2);
    v += __shfl_xor(v, 4);
    v += __shfl_xor(v, 8);
    v += __shfl_xor(v, 16);
    v += __shfl_xor(v, 32);
    __shared__ float partial[2];
    if ((j & 63) == 0) partial[j >> 6] = v;
    __syncthreads();
    if (j == 0) out[b * H_ + hh] = partial[0] + partial[1] + b2[0];
}

// ---------------------------------------------------------------------------
extern "C" void kernel_launch(void* const* d_in, const int* in_sizes, int n_in,
                              void* d_out, int out_size, void* d_ws, size_t ws_size,
                              hipStream_t stream) {
    (void)in_sizes; (void)n_in; (void)out_size; (void)ws_size;
    const float* x_past      = (const float*)d_in[0];
    const float* noisy       = (const float*)d_in[1];
    const float* t_in        = (const float*)d_in[2];
    const float* x_future    = (const float*)d_in[3];
    const float* static_attr = (const float*)d_in[4];
    const float* freqs       = (const float*)d_in[5];
    const float* phases      = (const float*)d_in[6];
    const float* in_W        = (const float*)d_in[7];
    const float* in_b        = (const float*)d_in[8];
    const float* tm_W1       = (const float*)d_in[9];
    const float* tm_b1       = (const float*)d_in[10];
    const float* tm_W2       = (const float*)d_in[11];
    const float* tm_b2       = (const float*)d_in[12];
    const float* log_dt      = (const float*)d_in[13];
    const float* A_re        = (const float*)d_in[14];
    const float* A_im        = (const float*)d_in[15];
    const float* C_re        = (const float*)d_in[16];
    const float* C_im        = (const float*)d_in[17];
    const float* Dp          = (const float*)d_in[18];
    const float* out_W       = (const float*)d_in[19];
    const float* out_b       = (const float*)d_in[20];
    const float* bn_gamma    = (const float*)d_in[21];
    const float* bn_beta     = (const float*)d_in[22];
    const float* head_W1     = (const float*)d_in[23];
    const float* head_b1     = (const float*)d_in[24];
    const float* head_W2     = (const float*)d_in[25];
    const float* head_b2     = (const float*)d_in[26];

    char* ws = (char*)d_ws;
    const size_t U_OFF  = 1u << 20;
    const size_t U_BYT  = (size_t)B_ * DM * LTP * 4;
    const size_t Y_OFF  = U_OFF + U_BYT;
    const size_t Y_BYT  = (size_t)B_ * LTR * DM * 2;
    const size_t X_OFF  = Y_OFF + Y_BYT;
    const size_t X_BYT  = (size_t)1024 * NSEG * 64 * 16 * 4;
    const size_t W_OFF  = X_OFF + X_BYT;

    float*          tb    = (float*)(ws);
    float*          stats = (float*)(ws + (64 << 10));
    float*          U     = (float*)(ws + U_OFF);
    __hip_bfloat16* Yb    = (__hip_bfloat16*)(ws + Y_OFF);
    float*          xbuf  = (float*)(ws + X_OFF);
    __hip_bfloat16* Wt    = (__hip_bfloat16*)(ws + W_OFF);

    time_mlp_kernel<<<dim3(B_), 256, 0, stream>>>(
        t_in, freqs, phases, tm_W1, tm_b1, tm_W2, tm_b2, tb);

    wt_prep_kernel<<<dim3(NL * 256), 256, 0, stream>>>(out_W, Wt);

    input_proj_kernel<<<dim3((LT + 255) / 256, B_), 256, 0, stream>>>(
        x_past, noisy, x_future, static_attr, in_W, in_b, tb, U);

    for (int layer = 0; layer < NL; ++layer) {
        scan_local_kernel<<<dim3(B_ * 32, NSEG), 64, 0, stream>>>(
            U, Yb, xbuf, log_dt, A_re, A_im, C_re, C_im, Dp, layer);
        scan_combine_kernel<<<dim3(B_ * 32), 64, 0, stream>>>(
            xbuf, log_dt, A_re, A_im, C_re, C_im, layer);
        scan_fix_kernel<<<dim3(B_ * 32, NSEG), 64, 0, stream>>>(
            Yb, xbuf, log_dt, A_re, A_im, C_re, C_im, layer);
        hipMemsetAsync(stats, 0, 2 * DM * sizeof(float), stream);
        gemm_glu_mfma_kernel<<<dim3(17, 4, B_), 256, 0, stream>>>(
            Yb, U, Wt, out_b, stats, layer);
        bn_kernel<<<dim3((LT + 255) / 256, DM, B_), 256, 0, stream>>>(
            U, stats, bn_gamma, bn_beta, layer);
    }

    head_kernel<<<dim3(H_, B_), 128, 0, stream>>>(
        U, head_W1, head_b1, head_W2, head_b2, (float*)d_out);
}

// Round 5
// 1510.026 us; speedup vs baseline: 2.6809x; 1.3921x over previous
//
#include <hip/hip_runtime.h>
#include <hip/hip_bf16.h>
#include <math.h>

#define B_   32
#define L_   2048
#define H_   8
#define DMET 16
#define SDIM 27
#define DM   256
#define NL   4
#define DS   64
#define TE   256
#define LT   2055          // L + H - 1
#define LTP  2056          // padded stride for U (fp32, [b][d][l])
#define LTR  2176          // 17*128: padded l for Ub/Ybt/Yb
#define TCH  128           // chunk length
#define NC   17            // chunks per sequence
#define COLS 544           // B_ * NC
#define NTOT (B_ * LT)

typedef __attribute__((ext_vector_type(8))) short short8;
typedef __attribute__((ext_vector_type(4))) short short4v;
typedef __attribute__((ext_vector_type(4))) float floatx4;

__device__ __forceinline__ float sigmoidf_(float x) {
    return 1.0f / (1.0f + expf(-x));
}

__device__ __forceinline__ float gelu_tanh(float x) {
    const float c0 = 0.7978845608028654f; // sqrt(2/pi)
    float x3 = x * x * x;
    float t = tanhf(c0 * (x + 0.044715f * x3));
    return 0.5f * x * (1.0f + t);
}

__device__ __forceinline__ short bfs(float x) {
    __hip_bfloat16 h = __float2bfloat16(x);
    return *(short*)&h;
}

// ---------------------------------------------------------------------------
// 1) time MLP
// ---------------------------------------------------------------------------
__global__ __launch_bounds__(256) void time_mlp_kernel(
    const float* __restrict__ t, const float* __restrict__ freqs,
    const float* __restrict__ phases,
    const float* __restrict__ W1, const float* __restrict__ b1,
    const float* __restrict__ W2, const float* __restrict__ b2,
    float* __restrict__ tb) {
    int b = blockIdx.x;
    int tid = threadIdx.x;
    __shared__ float f[TE];
    __shared__ float hid[2 * TE];
    float tv = t[b];
    f[tid] = cosf(fmaf(tv, freqs[tid], phases[tid])) * 1.4142135623730951f;
    __syncthreads();
    float a0 = b1[tid], a1 = b1[tid + TE];
    for (int k = 0; k < TE; ++k) {
        float fk = f[k];
        a0 = fmaf(fk, W1[k * 2 * TE + tid], a0);
        a1 = fmaf(fk, W1[k * 2 * TE + tid + TE], a1);
    }
    hid[tid]      = a0 * sigmoidf_(a0);
    hid[tid + TE] = a1 * sigmoidf_(a1);
    __syncthreads();
    float acc = b2[tid];
    for (int j = 0; j < 2 * TE; ++j)
        acc = fmaf(hid[j], W2[j * DM + tid], acc);
    tb[b * DM + tid] = acc;
}

// ---------------------------------------------------------------------------
// 1b) transpose out_W [NL][256][512] fp32 -> Wt bf16 [NL][512][256]
// ---------------------------------------------------------------------------
__global__ __launch_bounds__(256) void wt_prep_kernel(
    const float* __restrict__ out_W, __hip_bfloat16* __restrict__ Wt) {
    int bid = blockIdx.x;
    int layer = bid >> 8, k = bid & 255;
    int e = threadIdx.x;
    const float* src = out_W + ((size_t)layer * 256 + k) * 512;
    #pragma unroll
    for (int q = 0; q < 2; ++q) {
        int ee = e + q * 256;
        Wt[((size_t)layer * 512 + ee) * 256 + k] = __float2bfloat16(src[ee]);
    }
}

// ---------------------------------------------------------------------------
// 2) input projection -> U[b][d][l] fp32 and Ub[b][d][l] bf16
// ---------------------------------------------------------------------------
__global__ __launch_bounds__(256) void input_proj_kernel(
    const float* __restrict__ xp, const float* __restrict__ nf,
    const float* __restrict__ xf, const float* __restrict__ sa,
    const float* __restrict__ inW, const float* __restrict__ inb,
    const float* __restrict__ tb, float* __restrict__ U,
    __hip_bfloat16* __restrict__ Ub) {
    int b  = blockIdx.y;
    int l0 = blockIdx.x * 256;
    int tx = threadIdx.x;
    int l  = l0 + tx;

    __shared__ float feats[256][18];
    __shared__ float Ws[17][DM];
    __shared__ float sdot[DM];
    __shared__ float tbs[DM];
    __shared__ float sstat[SDIM];

    if (tx < SDIM) sstat[tx] = sa[b * SDIM + tx];
    for (int k = 0; k < 17; ++k) Ws[k][tx] = inW[k * DM + tx];
    tbs[tx] = tb[b * DM + tx];

    bool valid = (l < LT);
    if (valid) {
        const float* src = (l < L_) ? &xp[((size_t)b * L_ + l) * DMET]
                                    : &xf[((size_t)b * (H_ - 1) + (l - L_)) * DMET];
        #pragma unroll
        for (int k = 0; k < DMET; ++k) feats[tx][k] = src[k];
        feats[tx][16] = (l >= L_ - 1) ? nf[b * H_ + (l - (L_ - 1))] : 0.0f;
    }
    __syncthreads();

    float sd = 0.0f;
    for (int k = 0; k < SDIM; ++k)
        sd = fmaf(sstat[k], inW[(17 + k) * DM + tx], sd);
    sdot[tx] = sd;
    __syncthreads();

    if (!valid) return;
    bool cond = (l >= L_ - 1);
    size_t base  = ((size_t)b * DM) * LTP + l;
    size_t baseb = ((size_t)b * DM) * LTR + l;
    for (int d = 0; d < DM; ++d) {
        float acc = inb[d] + sdot[d] + (cond ? tbs[d] : 0.0f);
        #pragma unroll
        for (int k = 0; k < 17; ++k)
            acc = fmaf(feats[tx][k], Ws[k][d], acc);
        U[base + (size_t)d * LTP] = acc;
        Ub[baseb + (size_t)d * LTR] = __float2bfloat16(acc);
    }
}

// ---------------------------------------------------------------------------
// 2b) zero the l >= LT pad of Ub (poisoned each launch)
// ---------------------------------------------------------------------------
__global__ __launch_bounds__(128) void padzero_kernel(__hip_bfloat16* __restrict__ Ub) {
    int bd = blockIdx.x;
    int t = threadIdx.x;
    if (t < LTR - LT)
        Ub[(size_t)bd * LTR + LT + t] = __float2bfloat16(0.0f);
}

// ---------------------------------------------------------------------------
// 3a) per-layer, per-channel matrix prep:
//     Abig[d][i 128][k 256] = [ Toeplitz kappa | Vout(2Re, -2Im of Ck w^{i+1}) ]
//     SA  [d][k 128][m 128] = Vin: rows 0..63 Re(w^{127-m}), 64..127 Im(...)
// ---------------------------------------------------------------------------
__global__ __launch_bounds__(64) void prep_kernel(
    const float* __restrict__ log_dt,
    const float* __restrict__ A_re, const float* __restrict__ A_im,
    const float* __restrict__ C_re, const float* __restrict__ C_im,
    const float* __restrict__ Dp,
    __hip_bfloat16* __restrict__ Abig, __hip_bfloat16* __restrict__ SA,
    int layer) {
    int d = blockIdx.x;
    int n = threadIdx.x;
    __shared__ float kap[TCH];
    __shared__ __hip_bfloat16 Lv[128][132];

    float dt = expf(log_dt[layer * DM + d]);
    size_t ab = ((size_t)layer * DM + d) * DS + n;
    float Ar = A_re[ab], Ai = A_im[ab], Cr = C_re[ab], Ci = C_im[ab];
    float e = expf(dt * Ar);
    float wre = e * cosf(dt * Ai), wim = e * sinf(dt * Ai);
    float mr = wre - 1.0f, mi = wim;
    float den = 1.0f / (Ar * Ar + Ai * Ai);
    float qr = (mr * Ar + mi * Ai) * den, qi = (mi * Ar - mr * Ai) * den;
    float ckr = Cr * qr - Ci * qi, cki = Cr * qi + Ci * qr;
    float Dd = Dp[layer * DM + d];

    // kappa[delta] = 2 Re(sum_n Ck w^delta); kappa[0] += D
    float rr = ckr, ri = cki;
    for (int dlt = 0; dlt < TCH; ++dlt) {
        float p = 2.0f * rr;
        p += __shfl_xor(p, 1);  p += __shfl_xor(p, 2);  p += __shfl_xor(p, 4);
        p += __shfl_xor(p, 8);  p += __shfl_xor(p, 16); p += __shfl_xor(p, 32);
        if (n == 0) kap[dlt] = p + (dlt == 0 ? Dd : 0.0f);
        float tmp = rr * wre - ri * wim;
        ri = rr * wim + ri * wre; rr = tmp;
    }
    __syncthreads();

    __hip_bfloat16* Ad = Abig + (size_t)d * TCH * 256;
    for (int idx = n; idx < TCH * TCH; idx += 64) {
        int i = idx >> 7, m = idx & 127;
        float v = (m <= i) ? kap[i - m] : 0.0f;
        Ad[(size_t)i * 256 + m] = __float2bfloat16(v);
    }
    // Vout: rot = Ck * w^{i+1}
    float vr = ckr * wre - cki * wim, vi = ckr * wim + cki * wre;
    for (int i = 0; i < TCH; ++i) {
        Ad[(size_t)i * 256 + 128 + n] = __float2bfloat16(2.0f * vr);
        Ad[(size_t)i * 256 + 192 + n] = __float2bfloat16(-2.0f * vi);
        float tmp = vr * wre - vi * wim;
        vi = vr * wim + vi * wre; vr = tmp;
    }
    // Vin into LDS, then coalesced copy-out
    float pr = 1.0f, pi = 0.0f;
    for (int mp = 0; mp < TCH; ++mp) {
        int m = 127 - mp;
        Lv[n][m]      = __float2bfloat16(pr);
        Lv[64 + n][m] = __float2bfloat16(pi);
        float tmp = pr * wre - pi * wim;
        pi = pr * wim + pi * wre; pr = tmp;
    }
    __syncthreads();
    __hip_bfloat16* Sd = SA + (size_t)d * TCH * TCH;
    for (int idx = n; idx < TCH * TCH; idx += 64)
        Sd[idx] = Lv[idx >> 7][idx & 127];
}

// ---------------------------------------------------------------------------
// 3b) S-GEMM: S[d][col][k 128] = Vin_d x u_chunk  (bf16 out, fp32 accum)
//     col = b*17 + c
// ---------------------------------------------------------------------------
__global__ __launch_bounds__(256) void sgemm_kernel(
    const __hip_bfloat16* __restrict__ Ub, const __hip_bfloat16* __restrict__ SA,
    __hip_bfloat16* __restrict__ S) {
    int cb = blockIdx.x, d = blockIdx.y;
    int tid = threadIdx.x, wave = tid >> 6, lane = tid & 63;
    int lm = lane & 15, quad = lane >> 4;
    const __hip_bfloat16* SAd = SA + (size_t)d * TCH * TCH;

    size_t ubase[4];
    int colv[4];
    #pragma unroll
    for (int nt = 0; nt < 4; ++nt) {
        int col = cb * 64 + nt * 16 + lm;
        colv[nt] = col;
        int colc = col < COLS ? col : COLS - 1;
        int bh = (colc * 241) >> 12;
        int c = colc - bh * 17;
        ubase[nt] = ((size_t)bh * DM + d) * LTR + (size_t)c * TCH;
    }

    floatx4 acc[2][4];
    floatx4 zf = {0.f, 0.f, 0.f, 0.f};
    #pragma unroll
    for (int mi = 0; mi < 2; ++mi)
        #pragma unroll
        for (int nt = 0; nt < 4; ++nt) acc[mi][nt] = zf;

    for (int kk = 0; kk < 4; ++kk) {
        short8 a0 = *(const short8*)(SAd + (size_t)(wave * 32 + lm) * TCH + kk * 32 + quad * 8);
        short8 a1 = *(const short8*)(SAd + (size_t)(wave * 32 + 16 + lm) * TCH + kk * 32 + quad * 8);
        #pragma unroll
        for (int nt = 0; nt < 4; ++nt) {
            short8 bv = *(const short8*)(Ub + ubase[nt] + kk * 32 + quad * 8);
            acc[0][nt] = __builtin_amdgcn_mfma_f32_16x16x32_bf16(a0, bv, acc[0][nt], 0, 0, 0);
            acc[1][nt] = __builtin_amdgcn_mfma_f32_16x16x32_bf16(a1, bv, acc[1][nt], 0, 0, 0);
        }
    }
    #pragma unroll
    for (int mi = 0; mi < 2; ++mi)
        #pragma unroll
        for (int nt = 0; nt < 4; ++nt) {
            if (colv[nt] >= COLS) continue;
            int row = wave * 32 + mi * 16 + quad * 4;
            short4v o;
            o[0] = bfs(acc[mi][nt][0]); o[1] = bfs(acc[mi][nt][1]);
            o[2] = bfs(acc[mi][nt][2]); o[3] = bfs(acc[mi][nt][3]);
            *(short4v*)(S + ((size_t)d * COLS + colv[nt]) * TCH + row) = o;
        }
}

// ---------------------------------------------------------------------------
// 3c) carry scan over chunks, in place: SX[col] <- state BEFORE chunk c
// ---------------------------------------------------------------------------
__global__ __launch_bounds__(64) void carry_kernel(
    __hip_bfloat16* __restrict__ SX,
    const float* __restrict__ log_dt,
    const float* __restrict__ A_re, const float* __restrict__ A_im,
    int layer) {
    int d = blockIdx.x, b = blockIdx.y;
    int n = threadIdx.x;
    float dt = expf(log_dt[layer * DM + d]);
    size_t ab = ((size_t)layer * DM + d) * DS + n;
    float Ar = A_re[ab], Ai = A_im[ab];
    float e = expf(dt * Ar);
    float wre = e * cosf(dt * Ai), wim = e * sinf(dt * Ai);
    #pragma unroll
    for (int t = 0; t < 7; ++t) {   // w^128
        float r = wre * wre - wim * wim;
        wim = 2.0f * wre * wim; wre = r;
    }
    float xr = 0.0f, xi = 0.0f;
    for (int c = 0; c < NC; ++c) {
        size_t addr = ((size_t)d * COLS + b * NC + c) * TCH;
        float sre = __bfloat162float(SX[addr + n]);
        float sim = __bfloat162float(SX[addr + 64 + n]);
        SX[addr + n]      = __float2bfloat16(xr);
        SX[addr + 64 + n] = __float2bfloat16(xi);
        float nr = wre * xr - wim * xi + sre;
        xi = wre * xi + wim * xr + sim;
        xr = nr;
    }
}

// ---------------------------------------------------------------------------
// 3d) main chunk GEMM: y = [Toep | Vout] x [u ; x], gelu, -> Ybt[b][d][l] bf16
// ---------------------------------------------------------------------------
__global__ __launch_bounds__(256) void mainscan_kernel(
    const __hip_bfloat16* __restrict__ Ub, const __hip_bfloat16* __restrict__ X,
    const __hip_bfloat16* __restrict__ Abig, __hip_bfloat16* __restrict__ Ybt) {
    int cb = blockIdx.x, d = blockIdx.y;
    int tid = threadIdx.x, wave = tid >> 6, lane = tid & 63;
    int lm = lane & 15, quad = lane >> 4;
    const __hip_bfloat16* Ad = Abig + (size_t)d * TCH * 256;

    size_t ubase[4], xbase[4];
    int colv[4], ccv[4], bhv[4];
    #pragma unroll
    for (int nt = 0; nt < 4; ++nt) {
        int col = cb * 64 + nt * 16 + lm;
        colv[nt] = col;
        int colc = col < COLS ? col : COLS - 1;
        int bh = (colc * 241) >> 12;
        int c = colc - bh * 17;
        bhv[nt] = bh; ccv[nt] = c;
        ubase[nt] = ((size_t)bh * DM + d) * LTR + (size_t)c * TCH;
        xbase[nt] = ((size_t)d * COLS + colc) * TCH;
    }

    floatx4 acc[2][4];
    floatx4 zf = {0.f, 0.f, 0.f, 0.f};
    #pragma unroll
    for (int mi = 0; mi < 2; ++mi)
        #pragma unroll
        for (int nt = 0; nt < 4; ++nt) acc[mi][nt] = zf;

    #pragma unroll
    for (int kk = 0; kk < 8; ++kk) {
        short8 a0 = *(const short8*)(Ad + (size_t)(wave * 32 + lm) * 256 + kk * 32 + quad * 8);
        short8 a1 = *(const short8*)(Ad + (size_t)(wave * 32 + 16 + lm) * 256 + kk * 32 + quad * 8);
        #pragma unroll
        for (int nt = 0; nt < 4; ++nt) {
            short8 bv = (kk < 4)
                ? *(const short8*)(Ub + ubase[nt] + kk * 32 + quad * 8)
                : *(const short8*)(X + xbase[nt] + (kk - 4) * 32 + quad * 8);
            acc[0][nt] = __builtin_amdgcn_mfma_f32_16x16x32_bf16(a0, bv, acc[0][nt], 0, 0, 0);
            acc[1][nt] = __builtin_amdgcn_mfma_f32_16x16x32_bf16(a1, bv, acc[1][nt], 0, 0, 0);
        }
    }
    #pragma unroll
    for (int mi = 0; mi < 2; ++mi)
        #pragma unroll
        for (int nt = 0; nt < 4; ++nt) {
            if (colv[nt] >= COLS) continue;
            int row0 = wave * 32 + mi * 16 + quad * 4;
            int l0 = ccv[nt] * TCH + row0;
            float g0 = gelu_tanh(acc[mi][nt][0]);
            float g1 = gelu_tanh(acc[mi][nt][1]);
            float g2 = gelu_tanh(acc[mi][nt][2]);
            float g3 = gelu_tanh(acc[mi][nt][3]);
            __hip_bfloat16* dst = Ybt + ((size_t)bhv[nt] * DM + d) * LTR + l0;
            if (l0 + 3 < LT) {
                short4v o;
                o[0] = bfs(g0); o[1] = bfs(g1); o[2] = bfs(g2); o[3] = bfs(g3);
                *(short4v*)dst = o;
            } else {
                if (l0 + 0 < LT) dst[0] = __float2bfloat16(g0);
                if (l0 + 1 < LT) dst[1] = __float2bfloat16(g1);
                if (l0 + 2 < LT) dst[2] = __float2bfloat16(g2);
                if (l0 + 3 < LT) dst[3] = __float2bfloat16(g3);
            }
        }
}

// ---------------------------------------------------------------------------
// 3e) transpose Ybt[b][d][l] -> Yb[b][l][d] (64x64 LDS tiles)
// ---------------------------------------------------------------------------
__global__ __launch_bounds__(256) void transpose_kernel(
    const __hip_bfloat16* __restrict__ Ybt, __hip_bfloat16* __restrict__ Yb) {
    int lt = blockIdx.x, dti = blockIdx.y, b = blockIdx.z;
    int t = threadIdx.x;
    __shared__ __hip_bfloat16 tile[64][66];
    int l0 = lt * 64, d0 = dti * 64;
    #pragma unroll
    for (int rep = 0; rep < 16; ++rep) {
        int idx = rep * 256 + t;
        int dd = idx >> 6, ll = idx & 63;
        tile[dd][ll] = Ybt[((size_t)b * DM + d0 + dd) * LTR + l0 + ll];
    }
    __syncthreads();
    #pragma unroll
    for (int rep = 0; rep < 16; ++rep) {
        int idx = rep * 256 + t;
        int ll = idx >> 6, dd = idx & 63;
        Yb[((size_t)b * LTR + l0 + ll) * DM + d0 + dd] = tile[dd][ll];
    }
}

// ---------------------------------------------------------------------------
// 4) MFMA bf16 GEMM + GLU + residual (in-place U) + BN partial stats
// ---------------------------------------------------------------------------
__global__ __launch_bounds__(256) void gemm_glu_mfma_kernel(
    const __hip_bfloat16* __restrict__ Yb, float* __restrict__ U,
    const __hip_bfloat16* __restrict__ Wt, const float* __restrict__ out_b,
    float* __restrict__ stats, int layer) {
    int bx = blockIdx.x, by = blockIdx.y, b = blockIdx.z;
    int tid = threadIdx.x;
    int wave = tid >> 6, lane = tid & 63;
    int lm = lane & 15, quad = lane >> 4;
    int lbase = bx * 128 + wave * 32;

    const __hip_bfloat16* Yb_b = Yb + (size_t)b * LTR * DM;
    const __hip_bfloat16* ap0 = Yb_b + (size_t)(lbase + lm) * DM + quad * 8;
    const __hip_bfloat16* ap1 = Yb_b + (size_t)(lbase + 16 + lm) * DM + quad * 8;
    const __hip_bfloat16* bp[8];
    #pragma unroll
    for (int nt = 0; nt < 4; ++nt)
        #pragma unroll
        for (int h = 0; h < 2; ++h) {
            int e = by * 64 + nt * 16 + lm + h * 256;
            bp[nt * 2 + h] = Wt + ((size_t)layer * 512 + e) * 256 + quad * 8;
        }

    floatx4 acc[2][4][2];
    floatx4 zf = {0.f, 0.f, 0.f, 0.f};
    #pragma unroll
    for (int mt = 0; mt < 2; ++mt)
        #pragma unroll
        for (int nt = 0; nt < 4; ++nt)
            #pragma unroll
            for (int h = 0; h < 2; ++h) acc[mt][nt][h] = zf;

    for (int k0 = 0; k0 < 256; k0 += 32) {
        short8 a0 = *(const short8*)(ap0 + k0);
        short8 a1 = *(const short8*)(ap1 + k0);
        short8 bv[8];
        #pragma unroll
        for (int i = 0; i < 8; ++i) bv[i] = *(const short8*)(bp[i] + k0);
        #pragma unroll
        for (int nt = 0; nt < 4; ++nt)
            #pragma unroll
            for (int h = 0; h < 2; ++h) {
                acc[0][nt][h] = __builtin_amdgcn_mfma_f32_16x16x32_bf16(
                    a0, bv[nt * 2 + h], acc[0][nt][h], 0, 0, 0);
                acc[1][nt][h] = __builtin_amdgcn_mfma_f32_16x16x32_bf16(
                    a1, bv[nt * 2 + h], acc[1][nt][h], 0, 0, 0);
            }
    }

    const float* bl = out_b + layer * 512;
    float sp[4], sq[4];
    #pragma unroll
    for (int nt = 0; nt < 4; ++nt) { sp[nt] = 0.f; sq[nt] = 0.f; }

    #pragma unroll
    for (int nt = 0; nt < 4; ++nt) {
        int ch = by * 64 + nt * 16 + lm;
        float bz1 = bl[ch], bz2 = bl[256 + ch];
        float* urow = U + ((size_t)b * DM + ch) * LTP;
        #pragma unroll
        for (int mt = 0; mt < 2; ++mt) {
            int l0q = lbase + mt * 16 + quad * 4;
            floatx4 z1v = acc[mt][nt][0];
            floatx4 z2v = acc[mt][nt][1];
            if (l0q + 4 <= LT) {
                float4 uv = *(const float4*)(urow + l0q);
                float h0 = uv.x + (z1v[0] + bz1) * sigmoidf_(z2v[0] + bz2);
                float h1 = uv.y + (z1v[1] + bz1) * sigmoidf_(z2v[1] + bz2);
                float h2 = uv.z + (z1v[2] + bz1) * sigmoidf_(z2v[2] + bz2);
                float h3 = uv.w + (z1v[3] + bz1) * sigmoidf_(z2v[3] + bz2);
                *(float4*)(urow + l0q) = make_float4(h0, h1, h2, h3);
                sp[nt] += (h0 + h1) + (h2 + h3);
                sq[nt] += (h0 * h0 + h1 * h1) + (h2 * h2 + h3 * h3);
            } else {
                #pragma unroll
                for (int r = 0; r < 4; ++r) {
                    int l = l0q + r;
                    if (l < LT) {
                        float uvv = urow[l];
                        float hh = uvv + (z1v[r] + bz1) * sigmoidf_(z2v[r] + bz2);
                        urow[l] = hh;
                        sp[nt] += hh; sq[nt] += hh * hh;
                    }
                }
            }
        }
    }
    #pragma unroll
    for (int nt = 0; nt < 4; ++nt) {
        sp[nt] += __shfl_xor(sp[nt], 16); sp[nt] += __shfl_xor(sp[nt], 32);
        sq[nt] += __shfl_xor(sq[nt], 16); sq[nt] += __shfl_xor(sq[nt], 32);
    }
    __shared__ float sred[2][4][4][16];
    if (quad == 0) {
        #pragma unroll
        for (int nt = 0; nt < 4; ++nt) {
            sred[0][wave][nt][lm] = sp[nt];
            sred[1][wave][nt][lm] = sq[nt];
        }
    }
    __syncthreads();
    if (tid < 128) {
        int which = tid >> 6, idx = tid & 63;
        int nt = idx >> 4, lm2 = idx & 15;
        float v = sred[which][0][nt][lm2] + sred[which][1][nt][lm2]
                + sred[which][2][nt][lm2] + sred[which][3][nt][lm2];
        atomicAdd(&stats[which * DM + by * 64 + nt * 16 + lm2], v);
    }
}

// ---------------------------------------------------------------------------
// 5) BatchNorm normalize (in-place on U) + write Ub bf16 for next layer
// ---------------------------------------------------------------------------
__global__ __launch_bounds__(256) void bn_kernel(
    float* __restrict__ U, __hip_bfloat16* __restrict__ Ub,
    const float* __restrict__ stats,
    const float* __restrict__ gamma, const float* __restrict__ beta, int layer) {
    int l = blockIdx.x * 256 + threadIdx.x;
    int d = blockIdx.y, b = blockIdx.z;
    if (l >= LT) return;
    float s = stats[d], q = stats[DM + d];
    float mean = s * (1.0f / NTOT);
    float var  = q * (1.0f / NTOT) - mean * mean;
    float sc = rsqrtf(var + 1e-5f) * gamma[layer * DM + d];
    float sh = beta[layer * DM + d] - mean * sc;
    size_t idx = ((size_t)b * DM + d) * LTP + l;
    float v = fmaf(U[idx], sc, sh);
    U[idx] = v;
    Ub[((size_t)b * DM + d) * LTR + l] = __float2bfloat16(v);
}

// ---------------------------------------------------------------------------
// 6) head
// ---------------------------------------------------------------------------
__global__ __launch_bounds__(128) void head_kernel(
    const float* __restrict__ U,
    const float* __restrict__ W1, const float* __restrict__ b1,
    const float* __restrict__ W2, const float* __restrict__ b2,
    float* __restrict__ out) {
    int hh = blockIdx.x;
    int b  = blockIdx.y;
    int j  = threadIdx.x;
    int l  = (L_ - 1) + hh;
    const float* urow = U + ((size_t)b * DM) * LTP + l;
    float a = b1[j];
    for (int k = 0; k < DM; ++k)
        a = fmaf(urow[(size_t)k * LTP], W1[k * 128 + j], a);
    float hs = a * sigmoidf_(a);
    float v = hs * W2[j];
    v += __shfl_xor(v, 1);
    v += __shfl_xor(v, 2);
    v += __shfl_xor(v, 4);
    v += __shfl_xor(v, 8);
    v += __shfl_xor(v, 16);
    v += __shfl_xor(v, 32);
    __shared__ float partial[2];
    if ((j & 63) == 0) partial[j >> 6] = v;
    __syncthreads();
    if (j == 0) out[b * H_ + hh] = partial[0] + partial[1] + b2[0];
}

// ---------------------------------------------------------------------------
extern "C" void kernel_launch(void* const* d_in, const int* in_sizes, int n_in,
                              void* d_out, int out_size, void* d_ws, size_t ws_size,
                              hipStream_t stream) {
    (void)in_sizes; (void)n_in; (void)out_size; (void)ws_size;
    const float* x_past      = (const float*)d_in[0];
    const float* noisy       = (const float*)d_in[1];
    const float* t_in        = (const float*)d_in[2];
    const float* x_future    = (const float*)d_in[3];
    const float* static_attr = (const float*)d_in[4];
    const float* freqs       = (const float*)d_in[5];
    const float* phases      = (const float*)d_in[6];
    const float* in_W        = (const float*)d_in[7];
    const float* in_b        = (const float*)d_in[8];
    const float* tm_W1       = (const float*)d_in[9];
    const float* tm_b1       = (const float*)d_in[10];
    const float* tm_W2       = (const float*)d_in[11];
    const float* tm_b2       = (const float*)d_in[12];
    const float* log_dt      = (const float*)d_in[13];
    const float* A_re        = (const float*)d_in[14];
    const float* A_im        = (const float*)d_in[15];
    const float* C_re        = (const float*)d_in[16];
    const float* C_im        = (const float*)d_in[17];
    const float* Dp          = (const float*)d_in[18];
    const float* out_W       = (const float*)d_in[19];
    const float* out_b       = (const float*)d_in[20];
    const float* bn_gamma    = (const float*)d_in[21];
    const float* bn_beta     = (const float*)d_in[22];
    const float* head_W1     = (const float*)d_in[23];
    const float* head_b1     = (const float*)d_in[24];
    const float* head_W2     = (const float*)d_in[25];
    const float* head_b2     = (const float*)d_in[26];

    char* ws = (char*)d_ws;
    const size_t U_OFF  = 1u << 20;
    const size_t U_BYT  = (size_t)B_ * DM * LTP * 4;         // 67,371,008
    const size_t UB_OFF = U_OFF + U_BYT;
    const size_t UB_BYT = (size_t)B_ * DM * LTR * 2;         // 35,651,584
    const size_t R1_OFF = UB_OFF + UB_BYT;                   // S/X then Yb
    const size_t RB     = (size_t)256 * COLS * TCH * 2;      // 35,651,584
    const size_t R2_OFF = R1_OFF + RB;                       // Ybt
    const size_t AB_OFF = R2_OFF + RB;
    const size_t AB_BYT = (size_t)256 * TCH * 256 * 2;       // 16,777,216
    const size_t SA_OFF = AB_OFF + AB_BYT;
    const size_t SA_BYT = (size_t)256 * TCH * TCH * 2;       // 8,388,608
    const size_t WT_OFF = SA_OFF + SA_BYT;

    float*          tb    = (float*)(ws);
    float*          stats = (float*)(ws + (64 << 10));
    float*          U     = (float*)(ws + U_OFF);
    __hip_bfloat16* Ub    = (__hip_bfloat16*)(ws + UB_OFF);
    __hip_bfloat16* R1    = (__hip_bfloat16*)(ws + R1_OFF);  // S/X, later Yb
    __hip_bfloat16* Ybt   = (__hip_bfloat16*)(ws + R2_OFF);
    __hip_bfloat16* Abig  = (__hip_bfloat16*)(ws + AB_OFF);
    __hip_bfloat16* SA    = (__hip_bfloat16*)(ws + SA_OFF);
    __hip_bfloat16* Wt    = (__hip_bfloat16*)(ws + WT_OFF);

    time_mlp_kernel<<<dim3(B_), 256, 0, stream>>>(
        t_in, freqs, phases, tm_W1, tm_b1, tm_W2, tm_b2, tb);

    wt_prep_kernel<<<dim3(NL * 256), 256, 0, stream>>>(out_W, Wt);

    input_proj_kernel<<<dim3((LT + 255) / 256, B_), 256, 0, stream>>>(
        x_past, noisy, x_future, static_attr, in_W, in_b, tb, U, Ub);

    padzero_kernel<<<dim3(B_ * DM), 128, 0, stream>>>(Ub);

    for (int layer = 0; layer < NL; ++layer) {
        prep_kernel<<<dim3(256), 64, 0, stream>>>(
            log_dt, A_re, A_im, C_re, C_im, Dp, Abig, SA, layer);
        sgemm_kernel<<<dim3(9, 256), 256, 0, stream>>>(Ub, SA, R1);
        carry_kernel<<<dim3(256, B_), 64, 0, stream>>>(
            R1, log_dt, A_re, A_im, layer);
        mainscan_kernel<<<dim3(9, 256), 256, 0, stream>>>(Ub, R1, Abig, Ybt);
        transpose_kernel<<<dim3(LTR / 64, DM / 64, B_), 256, 0, stream>>>(Ybt, R1);
        hipMemsetAsync(stats, 0, 2 * DM * sizeof(float), stream);
        gemm_glu_mfma_kernel<<<dim3(17, 4, B_), 256, 0, stream>>>(
            R1, U, Wt, out_b, stats, layer);
        bn_kernel<<<dim3((LT + 255) / 256, DM, B_), 256, 0, stream>>>(
            U, Ub, stats, bn_gamma, bn_beta, layer);
    }

    head_kernel<<<dim3(H_, B_), 128, 0, stream>>>(
        U, head_W1, head_b1, head_W2, head_b2, (float*)d_out);
}

// Round 6
// 1324.698 us; speedup vs baseline: 3.0559x; 1.1399x over previous
//
#include <hip/hip_runtime.h>
#include <hip/hip_bf16.h>
#include <math.h>

#define B_   32
#define L_   2048
#define H_   8
#define DMET 16
#define SDIM 27
#define DM   256
#define NL   4
#define DS   64
#define TE   256
#define LT   2055          // L + H - 1
#define LTP  2056          // padded stride for U (fp32, [b][d][l])
#define LTR  2176          // 17*128: padded l for Ub/Ybt/Yb
#define TCH  128           // chunk length
#define NC   17            // chunks per sequence
#define COLS 544           // B_ * NC
#define NTOT (B_ * LT)

typedef __attribute__((ext_vector_type(8))) short short8;
typedef __attribute__((ext_vector_type(4))) short short4v;
typedef __attribute__((ext_vector_type(4))) float floatx4;

__device__ __forceinline__ float sigmoidf_(float x) {
    return 1.0f / (1.0f + expf(-x));
}

__device__ __forceinline__ float gelu_tanh(float x) {
    const float c0 = 0.7978845608028654f; // sqrt(2/pi)
    float x3 = x * x * x;
    float t = tanhf(c0 * (x + 0.044715f * x3));
    return 0.5f * x * (1.0f + t);
}

__device__ __forceinline__ short bfs(float x) {
    __hip_bfloat16 h = __float2bfloat16(x);
    return *(short*)&h;
}

__device__ __forceinline__ void glds16(const void* g, void* l) {
    __builtin_amdgcn_global_load_lds(
        (const __attribute__((address_space(1))) unsigned*)g,
        (__attribute__((address_space(3))) unsigned*)l, 16, 0, 0);
}

// ---------------------------------------------------------------------------
// 1) time MLP
// ---------------------------------------------------------------------------
__global__ __launch_bounds__(256) void time_mlp_kernel(
    const float* __restrict__ t, const float* __restrict__ freqs,
    const float* __restrict__ phases,
    const float* __restrict__ W1, const float* __restrict__ b1,
    const float* __restrict__ W2, const float* __restrict__ b2,
    float* __restrict__ tb) {
    int b = blockIdx.x;
    int tid = threadIdx.x;
    __shared__ float f[TE];
    __shared__ float hid[2 * TE];
    float tv = t[b];
    f[tid] = cosf(fmaf(tv, freqs[tid], phases[tid])) * 1.4142135623730951f;
    __syncthreads();
    float a0 = b1[tid], a1 = b1[tid + TE];
    for (int k = 0; k < TE; ++k) {
        float fk = f[k];
        a0 = fmaf(fk, W1[k * 2 * TE + tid], a0);
        a1 = fmaf(fk, W1[k * 2 * TE + tid + TE], a1);
    }
    hid[tid]      = a0 * sigmoidf_(a0);
    hid[tid + TE] = a1 * sigmoidf_(a1);
    __syncthreads();
    float acc = b2[tid];
    for (int j = 0; j < 2 * TE; ++j)
        acc = fmaf(hid[j], W2[j * DM + tid], acc);
    tb[b * DM + tid] = acc;
}

// ---------------------------------------------------------------------------
// 1b) out_W [NL][256][512] fp32 -> Wtp bf16 [NL][512 permuted cols][256 k]
//     col permutation groups z1/z2 of a channel into the same wave's N-range:
//     e=(half*256+P) -> c = (P>>6)*128 + (P&63 segmented): by-block of 128 =
//     [32 z1 | 32 z2 | 32 z1 | 32 z2]
// ---------------------------------------------------------------------------
__global__ __launch_bounds__(256) void wt_prep_kernel(
    const float* __restrict__ out_W, __hip_bfloat16* __restrict__ Wtp) {
    int bid = blockIdx.x;
    int layer = bid >> 8, k = bid & 255;
    int e = threadIdx.x;
    const float* src = out_W + ((size_t)layer * 256 + k) * 512;
    #pragma unroll
    for (int q = 0; q < 2; ++q) {
        int ee = e + q * 256;
        int P = ee & 255, half = ee >> 8;
        int by = P >> 6, pp = P & 63;
        int g = pp >> 5;
        int tcol = (pp & 31) + half * 32;
        int c = by * 128 + g * 64 + tcol;
        Wtp[((size_t)layer * 512 + c) * 256 + k] = __float2bfloat16(src[ee]);
    }
}

// ---------------------------------------------------------------------------
// 2) input projection -> U[b][d][l] fp32 and Ub[b][d][l] bf16
// ---------------------------------------------------------------------------
__global__ __launch_bounds__(256) void input_proj_kernel(
    const float* __restrict__ xp, const float* __restrict__ nf,
    const float* __restrict__ xf, const float* __restrict__ sa,
    const float* __restrict__ inW, const float* __restrict__ inb,
    const float* __restrict__ tb, float* __restrict__ U,
    __hip_bfloat16* __restrict__ Ub) {
    int b  = blockIdx.y;
    int l0 = blockIdx.x * 256;
    int tx = threadIdx.x;
    int l  = l0 + tx;

    __shared__ float feats[256][18];
    __shared__ float Ws[17][DM];
    __shared__ float sdot[DM];
    __shared__ float tbs[DM];
    __shared__ float sstat[SDIM];

    if (tx < SDIM) sstat[tx] = sa[b * SDIM + tx];
    for (int k = 0; k < 17; ++k) Ws[k][tx] = inW[k * DM + tx];
    tbs[tx] = tb[b * DM + tx];

    bool valid = (l < LT);
    if (valid) {
        const float* src = (l < L_) ? &xp[((size_t)b * L_ + l) * DMET]
                                    : &xf[((size_t)b * (H_ - 1) + (l - L_)) * DMET];
        #pragma unroll
        for (int k = 0; k < DMET; ++k) feats[tx][k] = src[k];
        feats[tx][16] = (l >= L_ - 1) ? nf[b * H_ + (l - (L_ - 1))] : 0.0f;
    }
    __syncthreads();

    float sd = 0.0f;
    for (int k = 0; k < SDIM; ++k)
        sd = fmaf(sstat[k], inW[(17 + k) * DM + tx], sd);
    sdot[tx] = sd;
    __syncthreads();

    if (!valid) return;
    bool cond = (l >= L_ - 1);
    size_t base  = ((size_t)b * DM) * LTP + l;
    size_t baseb = ((size_t)b * DM) * LTR + l;
    for (int d = 0; d < DM; ++d) {
        float acc = inb[d] + sdot[d] + (cond ? tbs[d] : 0.0f);
        #pragma unroll
        for (int k = 0; k < 17; ++k)
            acc = fmaf(feats[tx][k], Ws[k][d], acc);
        U[base + (size_t)d * LTP] = acc;
        Ub[baseb + (size_t)d * LTR] = __float2bfloat16(acc);
    }
}

// ---------------------------------------------------------------------------
// 2b) zero the l >= LT pad of Ub (poisoned each launch)
// ---------------------------------------------------------------------------
__global__ __launch_bounds__(128) void padzero_kernel(__hip_bfloat16* __restrict__ Ub) {
    int bd = blockIdx.x;
    int t = threadIdx.x;
    if (t < LTR - LT)
        Ub[(size_t)bd * LTR + LT + t] = __float2bfloat16(0.0f);
}

// ---------------------------------------------------------------------------
// 3a) per-layer per-channel matrix prep (Toeplitz kappa | Vout) and Vin
// ---------------------------------------------------------------------------
__global__ __launch_bounds__(64) void prep_kernel(
    const float* __restrict__ log_dt,
    const float* __restrict__ A_re, const float* __restrict__ A_im,
    const float* __restrict__ C_re, const float* __restrict__ C_im,
    const float* __restrict__ Dp,
    __hip_bfloat16* __restrict__ Abig, __hip_bfloat16* __restrict__ SA,
    int layer) {
    int d = blockIdx.x;
    int n = threadIdx.x;
    __shared__ float kap[TCH];
    __shared__ __hip_bfloat16 Lv[128][132];

    float dt = expf(log_dt[layer * DM + d]);
    size_t ab = ((size_t)layer * DM + d) * DS + n;
    float Ar = A_re[ab], Ai = A_im[ab], Cr = C_re[ab], Ci = C_im[ab];
    float e = expf(dt * Ar);
    float wre = e * cosf(dt * Ai), wim = e * sinf(dt * Ai);
    float mr = wre - 1.0f, mi = wim;
    float den = 1.0f / (Ar * Ar + Ai * Ai);
    float qr = (mr * Ar + mi * Ai) * den, qi = (mi * Ar - mr * Ai) * den;
    float ckr = Cr * qr - Ci * qi, cki = Cr * qi + Ci * qr;
    float Dd = Dp[layer * DM + d];

    float rr = ckr, ri = cki;
    for (int dlt = 0; dlt < TCH; ++dlt) {
        float p = 2.0f * rr;
        p += __shfl_xor(p, 1);  p += __shfl_xor(p, 2);  p += __shfl_xor(p, 4);
        p += __shfl_xor(p, 8);  p += __shfl_xor(p, 16); p += __shfl_xor(p, 32);
        if (n == 0) kap[dlt] = p + (dlt == 0 ? Dd : 0.0f);
        float tmp = rr * wre - ri * wim;
        ri = rr * wim + ri * wre; rr = tmp;
    }
    __syncthreads();

    __hip_bfloat16* Ad = Abig + (size_t)d * TCH * 256;
    for (int idx = n; idx < TCH * TCH; idx += 64) {
        int i = idx >> 7, m = idx & 127;
        float v = (m <= i) ? kap[i - m] : 0.0f;
        Ad[(size_t)i * 256 + m] = __float2bfloat16(v);
    }
    float vr = ckr * wre - cki * wim, vi = ckr * wim + cki * wre;
    for (int i = 0; i < TCH; ++i) {
        Ad[(size_t)i * 256 + 128 + n] = __float2bfloat16(2.0f * vr);
        Ad[(size_t)i * 256 + 192 + n] = __float2bfloat16(-2.0f * vi);
        float tmp = vr * wre - vi * wim;
        vi = vr * wim + vi * wre; vr = tmp;
    }
    float pr = 1.0f, pi = 0.0f;
    for (int mp = 0; mp < TCH; ++mp) {
        int m = 127 - mp;
        Lv[n][m]      = __float2bfloat16(pr);
        Lv[64 + n][m] = __float2bfloat16(pi);
        float tmp = pr * wre - pi * wim;
        pi = pr * wim + pi * wre; pr = tmp;
    }
    __syncthreads();
    __hip_bfloat16* Sd = SA + (size_t)d * TCH * TCH;
    for (int idx = n; idx < TCH * TCH; idx += 64)
        Sd[idx] = Lv[idx >> 7][idx & 127];
}

// ---------------------------------------------------------------------------
// 3b) S-GEMM: S[d][col][k 128] = Vin_d x u_chunk
// ---------------------------------------------------------------------------
__global__ __launch_bounds__(256) void sgemm_kernel(
    const __hip_bfloat16* __restrict__ Ub, const __hip_bfloat16* __restrict__ SA,
    __hip_bfloat16* __restrict__ S) {
    int cb = blockIdx.x, d = blockIdx.y;
    int tid = threadIdx.x, wave = tid >> 6, lane = tid & 63;
    int lm = lane & 15, quad = lane >> 4;
    const __hip_bfloat16* SAd = SA + (size_t)d * TCH * TCH;

    size_t ubase[4];
    int colv[4];
    #pragma unroll
    for (int nt = 0; nt < 4; ++nt) {
        int col = cb * 64 + nt * 16 + lm;
        colv[nt] = col;
        int colc = col < COLS ? col : COLS - 1;
        int bh = (colc * 241) >> 12;
        int c = colc - bh * 17;
        ubase[nt] = ((size_t)bh * DM + d) * LTR + (size_t)c * TCH;
    }

    floatx4 acc[2][4];
    floatx4 zf = {0.f, 0.f, 0.f, 0.f};
    #pragma unroll
    for (int mi = 0; mi < 2; ++mi)
        #pragma unroll
        for (int nt = 0; nt < 4; ++nt) acc[mi][nt] = zf;

    for (int kk = 0; kk < 4; ++kk) {
        short8 a0 = *(const short8*)(SAd + (size_t)(wave * 32 + lm) * TCH + kk * 32 + quad * 8);
        short8 a1 = *(const short8*)(SAd + (size_t)(wave * 32 + 16 + lm) * TCH + kk * 32 + quad * 8);
        #pragma unroll
        for (int nt = 0; nt < 4; ++nt) {
            short8 bv = *(const short8*)(Ub + ubase[nt] + kk * 32 + quad * 8);
            acc[0][nt] = __builtin_amdgcn_mfma_f32_16x16x32_bf16(a0, bv, acc[0][nt], 0, 0, 0);
            acc[1][nt] = __builtin_amdgcn_mfma_f32_16x16x32_bf16(a1, bv, acc[1][nt], 0, 0, 0);
        }
    }
    #pragma unroll
    for (int mi = 0; mi < 2; ++mi)
        #pragma unroll
        for (int nt = 0; nt < 4; ++nt) {
            if (colv[nt] >= COLS) continue;
            int row = wave * 32 + mi * 16 + quad * 4;
            short4v o;
            o[0] = bfs(acc[mi][nt][0]); o[1] = bfs(acc[mi][nt][1]);
            o[2] = bfs(acc[mi][nt][2]); o[3] = bfs(acc[mi][nt][3]);
            *(short4v*)(S + ((size_t)d * COLS + colv[nt]) * TCH + row) = o;
        }
}

// ---------------------------------------------------------------------------
// 3c) carry scan over chunks (in place)
// ---------------------------------------------------------------------------
__global__ __launch_bounds__(64) void carry_kernel(
    __hip_bfloat16* __restrict__ SX,
    const float* __restrict__ log_dt,
    const float* __restrict__ A_re, const float* __restrict__ A_im,
    int layer) {
    int d = blockIdx.x, b = blockIdx.y;
    int n = threadIdx.x;
    float dt = expf(log_dt[layer * DM + d]);
    size_t ab = ((size_t)layer * DM + d) * DS + n;
    float Ar = A_re[ab], Ai = A_im[ab];
    float e = expf(dt * Ar);
    float wre = e * cosf(dt * Ai), wim = e * sinf(dt * Ai);
    #pragma unroll
    for (int t = 0; t < 7; ++t) {
        float r = wre * wre - wim * wim;
        wim = 2.0f * wre * wim; wre = r;
    }
    float xr = 0.0f, xi = 0.0f;
    for (int c = 0; c < NC; ++c) {
        size_t addr = ((size_t)d * COLS + b * NC + c) * TCH;
        float sre = __bfloat162float(SX[addr + n]);
        float sim = __bfloat162float(SX[addr + 64 + n]);
        SX[addr + n]      = __float2bfloat16(xr);
        SX[addr + 64 + n] = __float2bfloat16(xi);
        float nr = wre * xr - wim * xi + sre;
        xi = wre * xi + wim * xr + sim;
        xr = nr;
    }
}

// ---------------------------------------------------------------------------
// 3d) main chunk GEMM: y = [Toep | Vout] x [u ; x], gelu -> Ybt[b][d][l]
// ---------------------------------------------------------------------------
__global__ __launch_bounds__(256) void mainscan_kernel(
    const __hip_bfloat16* __restrict__ Ub, const __hip_bfloat16* __restrict__ X,
    const __hip_bfloat16* __restrict__ Abig, __hip_bfloat16* __restrict__ Ybt) {
    int cb = blockIdx.x, d = blockIdx.y;
    int tid = threadIdx.x, wave = tid >> 6, lane = tid & 63;
    int lm = lane & 15, quad = lane >> 4;
    const __hip_bfloat16* Ad = Abig + (size_t)d * TCH * 256;

    size_t ubase[4], xbase[4];
    int colv[4], ccv[4], bhv[4];
    #pragma unroll
    for (int nt = 0; nt < 4; ++nt) {
        int col = cb * 64 + nt * 16 + lm;
        colv[nt] = col;
        int colc = col < COLS ? col : COLS - 1;
        int bh = (colc * 241) >> 12;
        int c = colc - bh * 17;
        bhv[nt] = bh; ccv[nt] = c;
        ubase[nt] = ((size_t)bh * DM + d) * LTR + (size_t)c * TCH;
        xbase[nt] = ((size_t)d * COLS + colc) * TCH;
    }

    floatx4 acc[2][4];
    floatx4 zf = {0.f, 0.f, 0.f, 0.f};
    #pragma unroll
    for (int mi = 0; mi < 2; ++mi)
        #pragma unroll
        for (int nt = 0; nt < 4; ++nt) acc[mi][nt] = zf;

    #pragma unroll
    for (int kk = 0; kk < 8; ++kk) {
        short8 a0 = *(const short8*)(Ad + (size_t)(wave * 32 + lm) * 256 + kk * 32 + quad * 8);
        short8 a1 = *(const short8*)(Ad + (size_t)(wave * 32 + 16 + lm) * 256 + kk * 32 + quad * 8);
        #pragma unroll
        for (int nt = 0; nt < 4; ++nt) {
            short8 bv = (kk < 4)
                ? *(const short8*)(Ub + ubase[nt] + kk * 32 + quad * 8)
                : *(const short8*)(X + xbase[nt] + (kk - 4) * 32 + quad * 8);
            acc[0][nt] = __builtin_amdgcn_mfma_f32_16x16x32_bf16(a0, bv, acc[0][nt], 0, 0, 0);
            acc[1][nt] = __builtin_amdgcn_mfma_f32_16x16x32_bf16(a1, bv, acc[1][nt], 0, 0, 0);
        }
    }
    #pragma unroll
    for (int mi = 0; mi < 2; ++mi)
        #pragma unroll
        for (int nt = 0; nt < 4; ++nt) {
            if (colv[nt] >= COLS) continue;
            int row0 = wave * 32 + mi * 16 + quad * 4;
            int l0 = ccv[nt] * TCH + row0;
            float g0 = gelu_tanh(acc[mi][nt][0]);
            float g1 = gelu_tanh(acc[mi][nt][1]);
            float g2 = gelu_tanh(acc[mi][nt][2]);
            float g3 = gelu_tanh(acc[mi][nt][3]);
            __hip_bfloat16* dst = Ybt + ((size_t)bhv[nt] * DM + d) * LTR + l0;
            if (l0 + 3 < LT) {
                short4v o;
                o[0] = bfs(g0); o[1] = bfs(g1); o[2] = bfs(g2); o[3] = bfs(g3);
                *(short4v*)dst = o;
            } else {
                if (l0 + 0 < LT) dst[0] = __float2bfloat16(g0);
                if (l0 + 1 < LT) dst[1] = __float2bfloat16(g1);
                if (l0 + 2 < LT) dst[2] = __float2bfloat16(g2);
                if (l0 + 3 < LT) dst[3] = __float2bfloat16(g3);
            }
        }
}

// ---------------------------------------------------------------------------
// 3e) transpose Ybt[b][d][l] -> Yb[b][l][d]
// ---------------------------------------------------------------------------
__global__ __launch_bounds__(256) void transpose_kernel(
    const __hip_bfloat16* __restrict__ Ybt, __hip_bfloat16* __restrict__ Yb) {
    int lt = blockIdx.x, dti = blockIdx.y, b = blockIdx.z;
    int t = threadIdx.x;
    __shared__ __hip_bfloat16 tile[64][66];
    int l0 = lt * 64, d0 = dti * 64;
    #pragma unroll
    for (int rep = 0; rep < 16; ++rep) {
        int idx = rep * 256 + t;
        int dd = idx >> 6, ll = idx & 63;
        tile[dd][ll] = Ybt[((size_t)b * DM + d0 + dd) * LTR + l0 + ll];
    }
    __syncthreads();
    #pragma unroll
    for (int rep = 0; rep < 16; ++rep) {
        int idx = rep * 256 + t;
        int ll = idx >> 6, dd = idx & 63;
        Yb[((size_t)b * LTR + l0 + ll) * DM + d0 + dd] = tile[dd][ll];
    }
}

// ---------------------------------------------------------------------------
// 4) m97-style LDS-staged MFMA GEMM + GLU + residual + BN stats.
//    Block: 128 l x 128 permuted cols, 4 waves (2x2 of 64x64), BK=32.
//    LDS chunks XOR-swizzled so frag ds_read_b128 is 2-way (free).
// ---------------------------------------------------------------------------
__global__ __launch_bounds__(256) void gemm_glu_mfma_kernel(
    const __hip_bfloat16* __restrict__ Yb, float* __restrict__ U,
    const __hip_bfloat16* __restrict__ Wtp, const float* __restrict__ out_b,
    float* __restrict__ stats, int layer) {
    int bx = blockIdx.x, by = blockIdx.y, b = blockIdx.z;
    int tid = threadIdx.x;
    int wave = tid >> 6, lane = tid & 63;
    int lm = lane & 15, quad = lane >> 4;
    int l0 = bx * 128;

    __shared__ short lds[8192];           // A: [0,4096) shorts, B: [4096,8192)
    short* Asb = lds;
    short* Bsb = lds + 4096;

    const __hip_bfloat16* Yb_b = Yb + (size_t)b * LTR * DM;
    const __hip_bfloat16* Wl = Wtp + (size_t)layer * 512 * 256 + (size_t)by * 128 * 256;

    floatx4 acc[4][4];
    floatx4 zf = {0.f, 0.f, 0.f, 0.f};
    #pragma unroll
    for (int mi = 0; mi < 4; ++mi)
        #pragma unroll
        for (int ni = 0; ni < 4; ++ni) acc[mi][ni] = zf;

    // staging chunk indices for this thread (i = 0,1): P = i*256 + tid
    // row = P>>2, sw = P&3, q = (sw - (row>>1)) & 3
    int rowA[2], qA[2];
    #pragma unroll
    for (int i = 0; i < 2; ++i) {
        int P = i * 256 + tid;
        rowA[i] = P >> 2;
        qA[i] = ((P & 3) - (rowA[i] >> 1)) & 3;
    }
    // frag read offsets (shorts): chunk = r*4 + ((quad + (r>>1)) & 3)
    int aoff[4], boff[4];
    #pragma unroll
    for (int mi = 0; mi < 4; ++mi) {
        int r = (wave >> 1) * 64 + mi * 16 + lm;
        aoff[mi] = (r * 4 + ((quad + (r >> 1)) & 3)) * 8;
    }
    #pragma unroll
    for (int ni = 0; ni < 4; ++ni) {
        int r = (wave & 1) * 64 + ni * 16 + lm;
        boff[ni] = (r * 4 + ((quad + (r >> 1)) & 3)) * 8;
    }

    for (int ks = 0; ks < 8; ++ks) {
        int k0 = ks * 32;
        __syncthreads();
        #pragma unroll
        for (int i = 0; i < 2; ++i) {
            const __hip_bfloat16* ga = Yb_b + (size_t)(l0 + rowA[i]) * DM + k0 + qA[i] * 8;
            glds16(ga, (char*)Asb + i * 4096 + wave * 1024 + (lane & 63) * 16);
            const __hip_bfloat16* gb = Wl + (size_t)rowA[i] * 256 + k0 + qA[i] * 8;
            glds16(gb, (char*)Bsb + i * 4096 + wave * 1024 + (lane & 63) * 16);
        }
        asm volatile("s_waitcnt vmcnt(0)" ::: "memory");
        __syncthreads();

        short8 af[4], bf[4];
        #pragma unroll
        for (int mi = 0; mi < 4; ++mi) af[mi] = *(const short8*)(Asb + aoff[mi]);
        #pragma unroll
        for (int ni = 0; ni < 4; ++ni) bf[ni] = *(const short8*)(Bsb + boff[ni]);
        #pragma unroll
        for (int mi = 0; mi < 4; ++mi)
            #pragma unroll
            for (int ni = 0; ni < 4; ++ni)
                acc[mi][ni] = __builtin_amdgcn_mfma_f32_16x16x32_bf16(
                    af[mi], bf[ni], acc[mi][ni], 0, 0, 0);
    }

    // epilogue: cols of this wave = [32 z1 of P | 32 z2 of same P]
    // ni in {0,1}: z1 of P = Pbase + ni*16 + lm ; z2 = acc[mi][ni+2]
    const float* bl = out_b + layer * 512;
    int Pbase = by * 64 + (wave & 1) * 32;
    int lw = l0 + (wave >> 1) * 64;
    #pragma unroll
    for (int ni = 0; ni < 2; ++ni) {
        int P = Pbase + ni * 16 + lm;
        float bz1 = bl[P], bz2 = bl[256 + P];
        float* urow = U + ((size_t)b * DM + P) * LTP;
        float sp = 0.f, sq = 0.f;
        #pragma unroll
        for (int mi = 0; mi < 4; ++mi) {
            int l0q = lw + mi * 16 + quad * 4;
            if (l0q >= LT) continue;
            floatx4 z1 = acc[mi][ni];
            floatx4 z2 = acc[mi][ni + 2];
            if (l0q + 4 <= LT) {
                float4 uv = *(const float4*)(urow + l0q);
                float h0 = uv.x + (z1[0] + bz1) * sigmoidf_(z2[0] + bz2);
                float h1 = uv.y + (z1[1] + bz1) * sigmoidf_(z2[1] + bz2);
                float h2 = uv.z + (z1[2] + bz1) * sigmoidf_(z2[2] + bz2);
                float h3 = uv.w + (z1[3] + bz1) * sigmoidf_(z2[3] + bz2);
                *(float4*)(urow + l0q) = make_float4(h0, h1, h2, h3);
                sp += (h0 + h1) + (h2 + h3);
                sq += (h0 * h0 + h1 * h1) + (h2 * h2 + h3 * h3);
            } else {
                #pragma unroll
                for (int r = 0; r < 4; ++r) {
                    int l = l0q + r;
                    if (l < LT) {
                        float uvv = urow[l];
                        float hh = uvv + (z1[r] + bz1) * sigmoidf_(z2[r] + bz2);
                        urow[l] = hh;
                        sp += hh; sq += hh * hh;
                    }
                }
            }
        }
        sp += __shfl_xor(sp, 16); sp += __shfl_xor(sp, 32);
        sq += __shfl_xor(sq, 16); sq += __shfl_xor(sq, 32);
        if (quad == 0) {
            atomicAdd(&stats[P], sp);
            atomicAdd(&stats[DM + P], sq);
        }
    }
}

// ---------------------------------------------------------------------------
// 5) BatchNorm normalize (in-place on U) + write Ub bf16 for next layer
// ---------------------------------------------------------------------------
__global__ __launch_bounds__(256) void bn_kernel(
    float* __restrict__ U, __hip_bfloat16* __restrict__ Ub,
    const float* __restrict__ stats,
    const float* __restrict__ gamma, const float* __restrict__ beta, int layer) {
    int l = blockIdx.x * 256 + threadIdx.x;
    int d = blockIdx.y, b = blockIdx.z;
    if (l >= LT) return;
    float s = stats[d], q = stats[DM + d];
    float mean = s * (1.0f / NTOT);
    float var  = q * (1.0f / NTOT) - mean * mean;
    float sc = rsqrtf(var + 1e-5f) * gamma[layer * DM + d];
    float sh = beta[layer * DM + d] - mean * sc;
    size_t idx = ((size_t)b * DM + d) * LTP + l;
    float v = fmaf(U[idx], sc, sh);
    U[idx] = v;
    Ub[((size_t)b * DM + d) * LTR + l] = __float2bfloat16(v);
}

// ---------------------------------------------------------------------------
// 6) head
// ---------------------------------------------------------------------------
__global__ __launch_bounds__(128) void head_kernel(
    const float* __restrict__ U,
    const float* __restrict__ W1, const float* __restrict__ b1,
    const float* __restrict__ W2, const float* __restrict__ b2,
    float* __restrict__ out) {
    int hh = blockIdx.x;
    int b  = blockIdx.y;
    int j  = threadIdx.x;
    int l  = (L_ - 1) + hh;
    const float* urow = U + ((size_t)b * DM) * LTP + l;
    float a = b1[j];
    for (int k = 0; k < DM; ++k)
        a = fmaf(urow[(size_t)k * LTP], W1[k * 128 + j], a);
    float hs = a * sigmoidf_(a);
    float v = hs * W2[j];
    v += __shfl_xor(v, 1);
    v += __shfl_xor(v, 2);
    v += __shfl_xor(v, 4);
    v += __shfl_xor(v, 8);
    v += __shfl_xor(v, 16);
    v += __shfl_xor(v, 32);
    __shared__ float partial[2];
    if ((j & 63) == 0) partial[j >> 6] = v;
    __syncthreads();
    if (j == 0) out[b * H_ + hh] = partial[0] + partial[1] + b2[0];
}

// ---------------------------------------------------------------------------
extern "C" void kernel_launch(void* const* d_in, const int* in_sizes, int n_in,
                              void* d_out, int out_size, void* d_ws, size_t ws_size,
                              hipStream_t stream) {
    (void)in_sizes; (void)n_in; (void)out_size; (void)ws_size;
    const float* x_past      = (const float*)d_in[0];
    const float* noisy       = (const float*)d_in[1];
    const float* t_in        = (const float*)d_in[2];
    const float* x_future    = (const float*)d_in[3];
    const float* static_attr = (const float*)d_in[4];
    const float* freqs       = (const float*)d_in[5];
    const float* phases      = (const float*)d_in[6];
    const float* in_W        = (const float*)d_in[7];
    const float* in_b        = (const float*)d_in[8];
    const float* tm_W1       = (const float*)d_in[9];
    const float* tm_b1       = (const float*)d_in[10];
    const float* tm_W2       = (const float*)d_in[11];
    const float* tm_b2       = (const float*)d_in[12];
    const float* log_dt      = (const float*)d_in[13];
    const float* A_re        = (const float*)d_in[14];
    const float* A_im        = (const float*)d_in[15];
    const float* C_re        = (const float*)d_in[16];
    const float* C_im        = (const float*)d_in[17];
    const float* Dp          = (const float*)d_in[18];
    const float* out_W       = (const float*)d_in[19];
    const float* out_b       = (const float*)d_in[20];
    const float* bn_gamma    = (const float*)d_in[21];
    const float* bn_beta     = (const float*)d_in[22];
    const float* head_W1     = (const float*)d_in[23];
    const float* head_b1     = (const float*)d_in[24];
    const float* head_W2     = (const float*)d_in[25];
    const float* head_b2     = (const float*)d_in[26];

    char* ws = (char*)d_ws;
    const size_t U_OFF  = 1u << 20;
    const size_t U_BYT  = (size_t)B_ * DM * LTP * 4;
    const size_t UB_OFF = U_OFF + U_BYT;
    const size_t UB_BYT = (size_t)B_ * DM * LTR * 2;
    const size_t R1_OFF = UB_OFF + UB_BYT;
    const size_t RB     = (size_t)256 * COLS * TCH * 2;
    const size_t R2_OFF = R1_OFF + RB;
    const size_t AB_OFF = R2_OFF + RB;
    const size_t AB_BYT = (size_t)256 * TCH * 256 * 2;
    const size_t SA_OFF = AB_OFF + AB_BYT;
    const size_t SA_BYT = (size_t)256 * TCH * TCH * 2;
    const size_t WT_OFF = SA_OFF + SA_BYT;

    float*          tb    = (float*)(ws);
    float*          stats = (float*)(ws + (64 << 10));
    float*          U     = (float*)(ws + U_OFF);
    __hip_bfloat16* Ub    = (__hip_bfloat16*)(ws + UB_OFF);
    __hip_bfloat16* R1    = (__hip_bfloat16*)(ws + R1_OFF);  // S/X, later Yb
    __hip_bfloat16* Ybt   = (__hip_bfloat16*)(ws + R2_OFF);
    __hip_bfloat16* Abig  = (__hip_bfloat16*)(ws + AB_OFF);
    __hip_bfloat16* SA    = (__hip_bfloat16*)(ws + SA_OFF);
    __hip_bfloat16* Wtp   = (__hip_bfloat16*)(ws + WT_OFF);

    time_mlp_kernel<<<dim3(B_), 256, 0, stream>>>(
        t_in, freqs, phases, tm_W1, tm_b1, tm_W2, tm_b2, tb);

    wt_prep_kernel<<<dim3(NL * 256), 256, 0, stream>>>(out_W, Wtp);

    input_proj_kernel<<<dim3((LT + 255) / 256, B_), 256, 0, stream>>>(
        x_past, noisy, x_future, static_attr, in_W, in_b, tb, U, Ub);

    padzero_kernel<<<dim3(B_ * DM), 128, 0, stream>>>(Ub);

    for (int layer = 0; layer < NL; ++layer) {
        prep_kernel<<<dim3(256), 64, 0, stream>>>(
            log_dt, A_re, A_im, C_re, C_im, Dp, Abig, SA, layer);
        sgemm_kernel<<<dim3(9, 256), 256, 0, stream>>>(Ub, SA, R1);
        carry_kernel<<<dim3(256, B_), 64, 0, stream>>>(
            R1, log_dt, A_re, A_im, layer);
        mainscan_kernel<<<dim3(9, 256), 256, 0, stream>>>(Ub, R1, Abig, Ybt);
        transpose_kernel<<<dim3(LTR / 64, DM / 64, B_), 256, 0, stream>>>(Ybt, R1);
        hipMemsetAsync(stats, 0, 2 * DM * sizeof(float), stream);
        gemm_glu_mfma_kernel<<<dim3(17, 4, B_), 256, 0, stream>>>(
            R1, U, Wtp, out_b, stats, layer);
        bn_kernel<<<dim3((LT + 255) / 256, DM, B_), 256, 0, stream>>>(
            U, Ub, stats, bn_gamma, bn_beta, layer);
    }

    head_kernel<<<dim3(H_, B_), 128, 0, stream>>>(
        U, head_W1, head_b1, head_W2, head_b2, (float*)d_out);
}

// Round 7
// 1225.441 us; speedup vs baseline: 3.3035x; 1.0810x over previous
//
#include <hip/hip_runtime.h>
#include <hip/hip_bf16.h>
#include <math.h>

#define B_   32
#define L_   2048
#define H_   8
#define DMET 16
#define SDIM 27
#define DM   256
#define NL   4
#define DS   64
#define TE   256
#define LT   2055          // L + H - 1
#define LTP  2056          // padded stride for U (fp32, [b][d][l])
#define LTR  2176          // 17*128: padded l for Ub/Ybt/Yb
#define TCH  128           // chunk length
#define NC   17            // chunks per sequence
#define COLS 544           // B_ * NC
#define NTOT (B_ * LT)

typedef __attribute__((ext_vector_type(8))) short short8;
typedef __attribute__((ext_vector_type(4))) short short4v;
typedef __attribute__((ext_vector_type(4))) float floatx4;

__device__ __forceinline__ float sigmoidf_(float x) {
    return 1.0f / (1.0f + expf(-x));
}

__device__ __forceinline__ float gelu_tanh(float x) {
    const float c0 = 0.7978845608028654f; // sqrt(2/pi)
    float x3 = x * x * x;
    float t = tanhf(c0 * (x + 0.044715f * x3));
    return 0.5f * x * (1.0f + t);
}

__device__ __forceinline__ short bfs(float x) {
    __hip_bfloat16 h = __float2bfloat16(x);
    return *(short*)&h;
}

__device__ __forceinline__ void glds16(const void* g, void* l) {
    __builtin_amdgcn_global_load_lds(
        (const __attribute__((address_space(1))) unsigned*)g,
        (__attribute__((address_space(3))) unsigned*)l, 16, 0, 0);
}

// ---------------------------------------------------------------------------
// 1) time MLP
// ---------------------------------------------------------------------------
__global__ __launch_bounds__(256) void time_mlp_kernel(
    const float* __restrict__ t, const float* __restrict__ freqs,
    const float* __restrict__ phases,
    const float* __restrict__ W1, const float* __restrict__ b1,
    const float* __restrict__ W2, const float* __restrict__ b2,
    float* __restrict__ tb) {
    int b = blockIdx.x;
    int tid = threadIdx.x;
    __shared__ float f[TE];
    __shared__ float hid[2 * TE];
    float tv = t[b];
    f[tid] = cosf(fmaf(tv, freqs[tid], phases[tid])) * 1.4142135623730951f;
    __syncthreads();
    float a0 = b1[tid], a1 = b1[tid + TE];
    for (int k = 0; k < TE; ++k) {
        float fk = f[k];
        a0 = fmaf(fk, W1[k * 2 * TE + tid], a0);
        a1 = fmaf(fk, W1[k * 2 * TE + tid + TE], a1);
    }
    hid[tid]      = a0 * sigmoidf_(a0);
    hid[tid + TE] = a1 * sigmoidf_(a1);
    __syncthreads();
    float acc = b2[tid];
    for (int j = 0; j < 2 * TE; ++j)
        acc = fmaf(hid[j], W2[j * DM + tid], acc);
    tb[b * DM + tid] = acc;
}

// ---------------------------------------------------------------------------
// 1b) out_W [NL][256][512] fp32 -> Wtp bf16 [NL][512 permuted cols][256 k]
// ---------------------------------------------------------------------------
__global__ __launch_bounds__(256) void wt_prep_kernel(
    const float* __restrict__ out_W, __hip_bfloat16* __restrict__ Wtp) {
    int bid = blockIdx.x;
    int layer = bid >> 8, k = bid & 255;
    int e = threadIdx.x;
    const float* src = out_W + ((size_t)layer * 256 + k) * 512;
    #pragma unroll
    for (int q = 0; q < 2; ++q) {
        int ee = e + q * 256;
        int P = ee & 255, half = ee >> 8;
        int by = P >> 6, pp = P & 63;
        int g = pp >> 5;
        int tcol = (pp & 31) + half * 32;
        int c = by * 128 + g * 64 + tcol;
        Wtp[((size_t)layer * 512 + c) * 256 + k] = __float2bfloat16(src[ee]);
    }
}

// ---------------------------------------------------------------------------
// 2) input projection -> U[b][d][l] fp32 and Ub[b][d][l] bf16
// ---------------------------------------------------------------------------
__global__ __launch_bounds__(256) void input_proj_kernel(
    const float* __restrict__ xp, const float* __restrict__ nf,
    const float* __restrict__ xf, const float* __restrict__ sa,
    const float* __restrict__ inW, const float* __restrict__ inb,
    const float* __restrict__ tb, float* __restrict__ U,
    __hip_bfloat16* __restrict__ Ub) {
    int b  = blockIdx.y;
    int l0 = blockIdx.x * 256;
    int tx = threadIdx.x;
    int l  = l0 + tx;

    __shared__ float feats[256][18];
    __shared__ float Ws[17][DM];
    __shared__ float sdot[DM];
    __shared__ float tbs[DM];
    __shared__ float sstat[SDIM];

    if (tx < SDIM) sstat[tx] = sa[b * SDIM + tx];
    for (int k = 0; k < 17; ++k) Ws[k][tx] = inW[k * DM + tx];
    tbs[tx] = tb[b * DM + tx];

    bool valid = (l < LT);
    if (valid) {
        const float* src = (l < L_) ? &xp[((size_t)b * L_ + l) * DMET]
                                    : &xf[((size_t)b * (H_ - 1) + (l - L_)) * DMET];
        #pragma unroll
        for (int k = 0; k < DMET; ++k) feats[tx][k] = src[k];
        feats[tx][16] = (l >= L_ - 1) ? nf[b * H_ + (l - (L_ - 1))] : 0.0f;
    }
    __syncthreads();

    float sd = 0.0f;
    for (int k = 0; k < SDIM; ++k)
        sd = fmaf(sstat[k], inW[(17 + k) * DM + tx], sd);
    sdot[tx] = sd;
    __syncthreads();

    if (!valid) return;
    bool cond = (l >= L_ - 1);
    size_t base  = ((size_t)b * DM) * LTP + l;
    size_t baseb = ((size_t)b * DM) * LTR + l;
    for (int d = 0; d < DM; ++d) {
        float acc = inb[d] + sdot[d] + (cond ? tbs[d] : 0.0f);
        #pragma unroll
        for (int k = 0; k < 17; ++k)
            acc = fmaf(feats[tx][k], Ws[k][d], acc);
        U[base + (size_t)d * LTP] = acc;
        Ub[baseb + (size_t)d * LTR] = __float2bfloat16(acc);
    }
}

// ---------------------------------------------------------------------------
// 2b) zero the l >= LT pad of Ub (poisoned each launch)
// ---------------------------------------------------------------------------
__global__ __launch_bounds__(128) void padzero_kernel(__hip_bfloat16* __restrict__ Ub) {
    int bd = blockIdx.x;
    int t = threadIdx.x;
    if (t < LTR - LT)
        Ub[(size_t)bd * LTR + LT + t] = __float2bfloat16(0.0f);
}

// ---------------------------------------------------------------------------
// 3a) per-layer per-channel matrix prep (Toeplitz kappa | Vout) and Vin
// ---------------------------------------------------------------------------
__global__ __launch_bounds__(64) void prep_kernel(
    const float* __restrict__ log_dt,
    const float* __restrict__ A_re, const float* __restrict__ A_im,
    const float* __restrict__ C_re, const float* __restrict__ C_im,
    const float* __restrict__ Dp,
    __hip_bfloat16* __restrict__ Abig, __hip_bfloat16* __restrict__ SA,
    int layer) {
    int d = blockIdx.x;
    int n = threadIdx.x;
    __shared__ float kap[TCH];
    __shared__ __hip_bfloat16 Lv[128][132];

    float dt = expf(log_dt[layer * DM + d]);
    size_t ab = ((size_t)layer * DM + d) * DS + n;
    float Ar = A_re[ab], Ai = A_im[ab], Cr = C_re[ab], Ci = C_im[ab];
    float e = expf(dt * Ar);
    float wre = e * cosf(dt * Ai), wim = e * sinf(dt * Ai);
    float mr = wre - 1.0f, mi = wim;
    float den = 1.0f / (Ar * Ar + Ai * Ai);
    float qr = (mr * Ar + mi * Ai) * den, qi = (mi * Ar - mr * Ai) * den;
    float ckr = Cr * qr - Ci * qi, cki = Cr * qi + Ci * qr;
    float Dd = Dp[layer * DM + d];

    float rr = ckr, ri = cki;
    for (int dlt = 0; dlt < TCH; ++dlt) {
        float p = 2.0f * rr;
        p += __shfl_xor(p, 1);  p += __shfl_xor(p, 2);  p += __shfl_xor(p, 4);
        p += __shfl_xor(p, 8);  p += __shfl_xor(p, 16); p += __shfl_xor(p, 32);
        if (n == 0) kap[dlt] = p + (dlt == 0 ? Dd : 0.0f);
        float tmp = rr * wre - ri * wim;
        ri = rr * wim + ri * wre; rr = tmp;
    }
    __syncthreads();

    __hip_bfloat16* Ad = Abig + (size_t)d * TCH * 256;
    for (int idx = n; idx < TCH * TCH; idx += 64) {
        int i = idx >> 7, m = idx & 127;
        float v = (m <= i) ? kap[i - m] : 0.0f;
        Ad[(size_t)i * 256 + m] = __float2bfloat16(v);
    }
    float vr = ckr * wre - cki * wim, vi = ckr * wim + cki * wre;
    for (int i = 0; i < TCH; ++i) {
        Ad[(size_t)i * 256 + 128 + n] = __float2bfloat16(2.0f * vr);
        Ad[(size_t)i * 256 + 192 + n] = __float2bfloat16(-2.0f * vi);
        float tmp = vr * wre - vi * wim;
        vi = vr * wim + vi * wre; vr = tmp;
    }
    float pr = 1.0f, pi = 0.0f;
    for (int mp = 0; mp < TCH; ++mp) {
        int m = 127 - mp;
        Lv[n][m]      = __float2bfloat16(pr);
        Lv[64 + n][m] = __float2bfloat16(pi);
        float tmp = pr * wre - pi * wim;
        pi = pr * wim + pi * wre; pr = tmp;
    }
    __syncthreads();
    __hip_bfloat16* Sd = SA + (size_t)d * TCH * TCH;
    for (int idx = n; idx < TCH * TCH; idx += 64)
        Sd[idx] = Lv[idx >> 7][idx & 127];
}

// ---------------------------------------------------------------------------
// 3b) S-GEMM: S[d][col][k 128] = Vin_d x u_chunk.  B staged in LDS once.
// ---------------------------------------------------------------------------
__global__ __launch_bounds__(256) void sgemm_kernel(
    const __hip_bfloat16* __restrict__ Ub, const __hip_bfloat16* __restrict__ SA,
    __hip_bfloat16* __restrict__ S) {
    int cb = blockIdx.x, d = blockIdx.y;
    int tid = threadIdx.x, wave = tid >> 6, lane = tid & 63;
    int lm = lane & 15, quad = lane >> 4;
    const __hip_bfloat16* SAd = SA + (size_t)d * TCH * TCH;

    __shared__ short Bs[8192];   // 4 sections x 64 cols x 32 shorts = 16 KB

    // stage: idx = it*256+tid -> kk=idx>>8, col=(idx>>2)&63, part=idx&3
    #pragma unroll
    for (int it = 0; it < 4; ++it) {
        int idx = it * 256 + tid;
        int kk = idx >> 8;
        int colloc = (idx >> 2) & 63;
        int part = idx & 3;
        int col = cb * 64 + colloc;
        int colc = col < COLS ? col : COLS - 1;
        int bh = (colc * 241) >> 12;
        int c = colc - bh * 17;
        const __hip_bfloat16* src =
            Ub + ((size_t)bh * DM + d) * LTR + (size_t)c * TCH + kk * 32 + part * 8;
        glds16(src, (char*)Bs + idx * 16);
    }
    asm volatile("s_waitcnt vmcnt(0)" ::: "memory");
    __syncthreads();

    floatx4 acc[2][4];
    floatx4 zf = {0.f, 0.f, 0.f, 0.f};
    #pragma unroll
    for (int mi = 0; mi < 2; ++mi)
        #pragma unroll
        for (int nt = 0; nt < 4; ++nt) acc[mi][nt] = zf;

    #pragma unroll
    for (int kk = 0; kk < 4; ++kk) {
        short8 a0 = *(const short8*)(SAd + (size_t)(wave * 32 + lm) * TCH + kk * 32 + quad * 8);
        short8 a1 = *(const short8*)(SAd + (size_t)(wave * 32 + 16 + lm) * TCH + kk * 32 + quad * 8);
        #pragma unroll
        for (int nt = 0; nt < 4; ++nt) {
            short8 bv = *(const short8*)(Bs + kk * 2048 + (nt * 16 + lm) * 32 + quad * 8);
            acc[0][nt] = __builtin_amdgcn_mfma_f32_16x16x32_bf16(a0, bv, acc[0][nt], 0, 0, 0);
            acc[1][nt] = __builtin_amdgcn_mfma_f32_16x16x32_bf16(a1, bv, acc[1][nt], 0, 0, 0);
        }
    }
    #pragma unroll
    for (int mi = 0; mi < 2; ++mi)
        #pragma unroll
        for (int nt = 0; nt < 4; ++nt) {
            int col = cb * 64 + nt * 16 + lm;
            if (col >= COLS) continue;
            int row = wave * 32 + mi * 16 + quad * 4;
            short4v o;
            o[0] = bfs(acc[mi][nt][0]); o[1] = bfs(acc[mi][nt][1]);
            o[2] = bfs(acc[mi][nt][2]); o[3] = bfs(acc[mi][nt][3]);
            *(short4v*)(S + ((size_t)d * COLS + col) * TCH + row) = o;
        }
}

// ---------------------------------------------------------------------------
// 3c) carry scan over chunks (in place)
// ---------------------------------------------------------------------------
__global__ __launch_bounds__(64) void carry_kernel(
    __hip_bfloat16* __restrict__ SX,
    const float* __restrict__ log_dt,
    const float* __restrict__ A_re, const float* __restrict__ A_im,
    int layer) {
    int d = blockIdx.x, b = blockIdx.y;
    int n = threadIdx.x;
    float dt = expf(log_dt[layer * DM + d]);
    size_t ab = ((size_t)layer * DM + d) * DS + n;
    float Ar = A_re[ab], Ai = A_im[ab];
    float e = expf(dt * Ar);
    float wre = e * cosf(dt * Ai), wim = e * sinf(dt * Ai);
    #pragma unroll
    for (int t = 0; t < 7; ++t) {
        float r = wre * wre - wim * wim;
        wim = 2.0f * wre * wim; wre = r;
    }
    float xr = 0.0f, xi = 0.0f;
    for (int c = 0; c < NC; ++c) {
        size_t addr = ((size_t)d * COLS + b * NC + c) * TCH;
        float sre = __bfloat162float(SX[addr + n]);
        float sim = __bfloat162float(SX[addr + 64 + n]);
        SX[addr + n]      = __float2bfloat16(xr);
        SX[addr + 64 + n] = __float2bfloat16(xi);
        float nr = wre * xr - wim * xi + sre;
        xi = wre * xi + wim * xr + sim;
        xr = nr;
    }
}

// ---------------------------------------------------------------------------
// 3d) main chunk GEMM: y = [Toep | Vout] x [u ; x], gelu -> Ybt[b][d][l].
//     Full K=256 B-operand staged in LDS once (shared by all 4 waves).
// ---------------------------------------------------------------------------
__global__ __launch_bounds__(256) void mainscan_kernel(
    const __hip_bfloat16* __restrict__ Ub, const __hip_bfloat16* __restrict__ X,
    const __hip_bfloat16* __restrict__ Abig, __hip_bfloat16* __restrict__ Ybt) {
    int cb = blockIdx.x, d = blockIdx.y;
    int tid = threadIdx.x, wave = tid >> 6, lane = tid & 63;
    int lm = lane & 15, quad = lane >> 4;
    const __hip_bfloat16* Ad = Abig + (size_t)d * TCH * 256;

    __shared__ short Bs[16384];  // 8 sections x 64 cols x 32 shorts = 32 KB

    #pragma unroll
    for (int it = 0; it < 8; ++it) {
        int idx = it * 256 + tid;
        int kk = idx >> 8;
        int colloc = (idx >> 2) & 63;
        int part = idx & 3;
        int col = cb * 64 + colloc;
        int colc = col < COLS ? col : COLS - 1;
        int bh = (colc * 241) >> 12;
        int c = colc - bh * 17;
        const __hip_bfloat16* src;
        if (kk < 4)
            src = Ub + ((size_t)bh * DM + d) * LTR + (size_t)c * TCH + kk * 32 + part * 8;
        else
            src = X + ((size_t)d * COLS + colc) * TCH + (kk - 4) * 32 + part * 8;
        glds16(src, (char*)Bs + idx * 16);
    }
    asm volatile("s_waitcnt vmcnt(0)" ::: "memory");
    __syncthreads();

    floatx4 acc[2][4];
    floatx4 zf = {0.f, 0.f, 0.f, 0.f};
    #pragma unroll
    for (int mi = 0; mi < 2; ++mi)
        #pragma unroll
        for (int nt = 0; nt < 4; ++nt) acc[mi][nt] = zf;

    #pragma unroll
    for (int kk = 0; kk < 8; ++kk) {
        short8 a0 = *(const short8*)(Ad + (size_t)(wave * 32 + lm) * 256 + kk * 32 + quad * 8);
        short8 a1 = *(const short8*)(Ad + (size_t)(wave * 32 + 16 + lm) * 256 + kk * 32 + quad * 8);
        #pragma unroll
        for (int nt = 0; nt < 4; ++nt) {
            short8 bv = *(const short8*)(Bs + kk * 2048 + (nt * 16 + lm) * 32 + quad * 8);
            acc[0][nt] = __builtin_amdgcn_mfma_f32_16x16x32_bf16(a0, bv, acc[0][nt], 0, 0, 0);
            acc[1][nt] = __builtin_amdgcn_mfma_f32_16x16x32_bf16(a1, bv, acc[1][nt], 0, 0, 0);
        }
    }

    #pragma unroll
    for (int mi = 0; mi < 2; ++mi)
        #pragma unroll
        for (int nt = 0; nt < 4; ++nt) {
            int col = cb * 64 + nt * 16 + lm;
            if (col >= COLS) continue;
            int bh = (col * 241) >> 12;
            int c = col - bh * 17;
            int row0 = wave * 32 + mi * 16 + quad * 4;
            int l0 = c * TCH + row0;
            float g0 = gelu_tanh(acc[mi][nt][0]);
            float g1 = gelu_tanh(acc[mi][nt][1]);
            float g2 = gelu_tanh(acc[mi][nt][2]);
            float g3 = gelu_tanh(acc[mi][nt][3]);
            __hip_bfloat16* dst = Ybt + ((size_t)bh * DM + d) * LTR + l0;
            if (l0 + 3 < LT) {
                short4v o;
                o[0] = bfs(g0); o[1] = bfs(g1); o[2] = bfs(g2); o[3] = bfs(g3);
                *(short4v*)dst = o;
            } else {
                if (l0 + 0 < LT) dst[0] = __float2bfloat16(g0);
                if (l0 + 1 < LT) dst[1] = __float2bfloat16(g1);
                if (l0 + 2 < LT) dst[2] = __float2bfloat16(g2);
                if (l0 + 3 < LT) dst[3] = __float2bfloat16(g3);
            }
        }
}

// ---------------------------------------------------------------------------
// 3e) transpose Ybt[b][d][l] -> Yb[b][l][d].  16B global I/O both sides,
//     scalar LDS through stride-66 tile (4-way / ~2-way aliasing only).
// ---------------------------------------------------------------------------
__global__ __launch_bounds__(256) void transpose_kernel(
    const __hip_bfloat16* __restrict__ Ybt, __hip_bfloat16* __restrict__ Yb) {
    int lt = blockIdx.x, dti = blockIdx.y, b = blockIdx.z;
    int t = threadIdx.x;
    __shared__ short tileT[64 * 66];   // [l][d], stride 66
    int l0 = lt * 64, d0 = dti * 64;
    #pragma unroll
    for (int r = 0; r < 2; ++r) {
        int idx = r * 256 + t;
        int dd = idx >> 3, lseg = idx & 7;
        short8 v = *(const short8*)(Ybt + ((size_t)b * DM + d0 + dd) * LTR + l0 + lseg * 8);
        #pragma unroll
        for (int i = 0; i < 8; ++i)
            tileT[(lseg * 8 + i) * 66 + dd] = v[i];
    }
    __syncthreads();
    #pragma unroll
    for (int r = 0; r < 2; ++r) {
        int idx = r * 256 + t;
        int ll = idx >> 3, dseg = idx & 7;
        short8 v;
        #pragma unroll
        for (int i = 0; i < 8; ++i)
            v[i] = tileT[ll * 66 + dseg * 8 + i];
        *(short8*)(Yb + ((size_t)b * LTR + l0 + ll) * DM + d0 + dseg * 8) = v;
    }
}

// ---------------------------------------------------------------------------
// 4) m97-style LDS-staged MFMA GEMM + GLU + residual + BN stats.
// ---------------------------------------------------------------------------
__global__ __launch_bounds__(256) void gemm_glu_mfma_kernel(
    const __hip_bfloat16* __restrict__ Yb, float* __restrict__ U,
    const __hip_bfloat16* __restrict__ Wtp, const float* __restrict__ out_b,
    float* __restrict__ stats, int layer) {
    int bx = blockIdx.x, by = blockIdx.y, b = blockIdx.z;
    int tid = threadIdx.x;
    int wave = tid >> 6, lane = tid & 63;
    int lm = lane & 15, quad = lane >> 4;
    int l0 = bx * 128;

    __shared__ short lds[8192];           // A: [0,4096) shorts, B: [4096,8192)
    short* Asb = lds;
    short* Bsb = lds + 4096;

    const __hip_bfloat16* Yb_b = Yb + (size_t)b * LTR * DM;
    const __hip_bfloat16* Wl = Wtp + (size_t)layer * 512 * 256 + (size_t)by * 128 * 256;

    floatx4 acc[4][4];
    floatx4 zf = {0.f, 0.f, 0.f, 0.f};
    #pragma unroll
    for (int mi = 0; mi < 4; ++mi)
        #pragma unroll
        for (int ni = 0; ni < 4; ++ni) acc[mi][ni] = zf;

    int rowA[2], qA[2];
    #pragma unroll
    for (int i = 0; i < 2; ++i) {
        int P = i * 256 + tid;
        rowA[i] = P >> 2;
        qA[i] = ((P & 3) - (rowA[i] >> 1)) & 3;
    }
    int aoff[4], boff[4];
    #pragma unroll
    for (int mi = 0; mi < 4; ++mi) {
        int r = (wave >> 1) * 64 + mi * 16 + lm;
        aoff[mi] = (r * 4 + ((quad + (r >> 1)) & 3)) * 8;
    }
    #pragma unroll
    for (int ni = 0; ni < 4; ++ni) {
        int r = (wave & 1) * 64 + ni * 16 + lm;
        boff[ni] = (r * 4 + ((quad + (r >> 1)) & 3)) * 8;
    }

    for (int ks = 0; ks < 8; ++ks) {
        int k0 = ks * 32;
        __syncthreads();
        #pragma unroll
        for (int i = 0; i < 2; ++i) {
            const __hip_bfloat16* ga = Yb_b + (size_t)(l0 + rowA[i]) * DM + k0 + qA[i] * 8;
            glds16(ga, (char*)Asb + i * 4096 + wave * 1024 + (lane & 63) * 16);
            const __hip_bfloat16* gb = Wl + (size_t)rowA[i] * 256 + k0 + qA[i] * 8;
            glds16(gb, (char*)Bsb + i * 4096 + wave * 1024 + (lane & 63) * 16);
        }
        asm volatile("s_waitcnt vmcnt(0)" ::: "memory");
        __syncthreads();

        short8 af[4], bf[4];
        #pragma unroll
        for (int mi = 0; mi < 4; ++mi) af[mi] = *(const short8*)(Asb + aoff[mi]);
        #pragma unroll
        for (int ni = 0; ni < 4; ++ni) bf[ni] = *(const short8*)(Bsb + boff[ni]);
        #pragma unroll
        for (int mi = 0; mi < 4; ++mi)
            #pragma unroll
            for (int ni = 0; ni < 4; ++ni)
                acc[mi][ni] = __builtin_amdgcn_mfma_f32_16x16x32_bf16(
                    af[mi], bf[ni], acc[mi][ni], 0, 0, 0);
    }

    const float* bl = out_b + layer * 512;
    int Pbase = by * 64 + (wave & 1) * 32;
    int lw = l0 + (wave >> 1) * 64;
    #pragma unroll
    for (int ni = 0; ni < 2; ++ni) {
        int P = Pbase + ni * 16 + lm;
        float bz1 = bl[P], bz2 = bl[256 + P];
        float* urow = U + ((size_t)b * DM + P) * LTP;
        float sp = 0.f, sq = 0.f;
        #pragma unroll
        for (int mi = 0; mi < 4; ++mi) {
            int l0q = lw + mi * 16 + quad * 4;
            if (l0q >= LT) continue;
            floatx4 z1 = acc[mi][ni];
            floatx4 z2 = acc[mi][ni + 2];
            if (l0q + 4 <= LT) {
                float4 uv = *(const float4*)(urow + l0q);
                float h0 = uv.x + (z1[0] + bz1) * sigmoidf_(z2[0] + bz2);
                float h1 = uv.y + (z1[1] + bz1) * sigmoidf_(z2[1] + bz2);
                float h2 = uv.z + (z1[2] + bz1) * sigmoidf_(z2[2] + bz2);
                float h3 = uv.w + (z1[3] + bz1) * sigmoidf_(z2[3] + bz2);
                *(float4*)(urow + l0q) = make_float4(h0, h1, h2, h3);
                sp += (h0 + h1) + (h2 + h3);
                sq += (h0 * h0 + h1 * h1) + (h2 * h2 + h3 * h3);
            } else {
                #pragma unroll
                for (int r = 0; r < 4; ++r) {
                    int l = l0q + r;
                    if (l < LT) {
                        float uvv = urow[l];
                        float hh = uvv + (z1[r] + bz1) * sigmoidf_(z2[r] + bz2);
                        urow[l] = hh;
                        sp += hh; sq += hh * hh;
                    }
                }
            }
        }
        sp += __shfl_xor(sp, 16); sp += __shfl_xor(sp, 32);
        sq += __shfl_xor(sq, 16); sq += __shfl_xor(sq, 32);
        if (quad == 0) {
            atomicAdd(&stats[P], sp);
            atomicAdd(&stats[DM + P], sq);
        }
    }
}

// ---------------------------------------------------------------------------
// 5) BatchNorm normalize (in-place on U) + write Ub bf16 for next layer
// ---------------------------------------------------------------------------
__global__ __launch_bounds__(256) void bn_kernel(
    float* __restrict__ U, __hip_bfloat16* __restrict__ Ub,
    const float* __restrict__ stats,
    const float* __restrict__ gamma, const float* __restrict__ beta, int layer) {
    int l = blockIdx.x * 256 + threadIdx.x;
    int d = blockIdx.y, b = blockIdx.z;
    if (l >= LT) return;
    float s = stats[d], q = stats[DM + d];
    float mean = s * (1.0f / NTOT);
    float var  = q * (1.0f / NTOT) - mean * mean;
    float sc = rsqrtf(var + 1e-5f) * gamma[layer * DM + d];
    float sh = beta[layer * DM + d] - mean * sc;
    size_t idx = ((size_t)b * DM + d) * LTP + l;
    float v = fmaf(U[idx], sc, sh);
    U[idx] = v;
    Ub[((size_t)b * DM + d) * LTR + l] = __float2bfloat16(v);
}

// ---------------------------------------------------------------------------
// 6) head
// ---------------------------------------------------------------------------
__global__ __launch_bounds__(128) void head_kernel(
    const float* __restrict__ U,
    const float* __restrict__ W1, const float* __restrict__ b1,
    const float* __restrict__ W2, const float* __restrict__ b2,
    float* __restrict__ out) {
    int hh = blockIdx.x;
    int b  = blockIdx.y;
    int j  = threadIdx.x;
    int l  = (L_ - 1) + hh;
    const float* urow = U + ((size_t)b * DM) * LTP + l;
    float a = b1[j];
    for (int k = 0; k < DM; ++k)
        a = fmaf(urow[(size_t)k * LTP], W1[k * 128 + j], a);
    float hs = a * sigmoidf_(a);
    float v = hs * W2[j];
    v += __shfl_xor(v, 1);
    v += __shfl_xor(v, 2);
    v += __shfl_xor(v, 4);
    v += __shfl_xor(v, 8);
    v += __shfl_xor(v, 16);
    v += __shfl_xor(v, 32);
    __shared__ float partial[2];
    if ((j & 63) == 0) partial[j >> 6] = v;
    __syncthreads();
    if (j == 0) out[b * H_ + hh] = partial[0] + partial[1] + b2[0];
}

// ---------------------------------------------------------------------------
extern "C" void kernel_launch(void* const* d_in, const int* in_sizes, int n_in,
                              void* d_out, int out_size, void* d_ws, size_t ws_size,
                              hipStream_t stream) {
    (void)in_sizes; (void)n_in; (void)out_size; (void)ws_size;
    const float* x_past      = (const float*)d_in[0];
    const float* noisy       = (const float*)d_in[1];
    const float* t_in        = (const float*)d_in[2];
    const float* x_future    = (const float*)d_in[3];
    const float* static_attr = (const float*)d_in[4];
    const float* freqs       = (const float*)d_in[5];
    const float* phases      = (const float*)d_in[6];
    const float* in_W        = (const float*)d_in[7];
    const float* in_b        = (const float*)d_in[8];
    const float* tm_W1       = (const float*)d_in[9];
    const float* tm_b1       = (const float*)d_in[10];
    const float* tm_W2       = (const float*)d_in[11];
    const float* tm_b2       = (const float*)d_in[12];
    const float* log_dt      = (const float*)d_in[13];
    const float* A_re        = (const float*)d_in[14];
    const float* A_im        = (const float*)d_in[15];
    const float* C_re        = (const float*)d_in[16];
    const float* C_im        = (const float*)d_in[17];
    const float* Dp          = (const float*)d_in[18];
    const float* out_W       = (const float*)d_in[19];
    const float* out_b       = (const float*)d_in[20];
    const float* bn_gamma    = (const float*)d_in[21];
    const float* bn_beta     = (const float*)d_in[22];
    const float* head_W1     = (const float*)d_in[23];
    const float* head_b1     = (const float*)d_in[24];
    const float* head_W2     = (const float*)d_in[25];
    const float* head_b2     = (const float*)d_in[26];

    char* ws = (char*)d_ws;
    const size_t U_OFF  = 1u << 20;
    const size_t U_BYT  = (size_t)B_ * DM * LTP * 4;
    const size_t UB_OFF = U_OFF + U_BYT;
    const size_t UB_BYT = (size_t)B_ * DM * LTR * 2;
    const size_t R1_OFF = UB_OFF + UB_BYT;
    const size_t RB     = (size_t)256 * COLS * TCH * 2;
    const size_t R2_OFF = R1_OFF + RB;
    const size_t AB_OFF = R2_OFF + RB;
    const size_t AB_BYT = (size_t)256 * TCH * 256 * 2;
    const size_t SA_OFF = AB_OFF + AB_BYT;
    const size_t SA_BYT = (size_t)256 * TCH * TCH * 2;
    const size_t WT_OFF = SA_OFF + SA_BYT;

    float*          tb    = (float*)(ws);
    float*          stats = (float*)(ws + (64 << 10));
    float*          U     = (float*)(ws + U_OFF);
    __hip_bfloat16* Ub    = (__hip_bfloat16*)(ws + UB_OFF);
    __hip_bfloat16* R1    = (__hip_bfloat16*)(ws + R1_OFF);  // S/X, later Yb
    __hip_bfloat16* Ybt   = (__hip_bfloat16*)(ws + R2_OFF);
    __hip_bfloat16* Abig  = (__hip_bfloat16*)(ws + AB_OFF);
    __hip_bfloat16* SA    = (__hip_bfloat16*)(ws + SA_OFF);
    __hip_bfloat16* Wtp   = (__hip_bfloat16*)(ws + WT_OFF);

    time_mlp_kernel<<<dim3(B_), 256, 0, stream>>>(
        t_in, freqs, phases, tm_W1, tm_b1, tm_W2, tm_b2, tb);

    wt_prep_kernel<<<dim3(NL * 256), 256, 0, stream>>>(out_W, Wtp);

    input_proj_kernel<<<dim3((LT + 255) / 256, B_), 256, 0, stream>>>(
        x_past, noisy, x_future, static_attr, in_W, in_b, tb, U, Ub);

    padzero_kernel<<<dim3(B_ * DM), 128, 0, stream>>>(Ub);

    for (int layer = 0; layer < NL; ++layer) {
        prep_kernel<<<dim3(256), 64, 0, stream>>>(
            log_dt, A_re, A_im, C_re, C_im, Dp, Abig, SA, layer);
        sgemm_kernel<<<dim3(9, 256), 256, 0, stream>>>(Ub, SA, R1);
        carry_kernel<<<dim3(256, B_), 64, 0, stream>>>(
            R1, log_dt, A_re, A_im, layer);
        mainscan_kernel<<<dim3(9, 256), 256, 0, stream>>>(Ub, R1, Abig, Ybt);
        transpose_kernel<<<dim3(LTR / 64, DM / 64, B_), 256, 0, stream>>>(Ybt, R1);
        hipMemsetAsync(stats, 0, 2 * DM * sizeof(float), stream);
        gemm_glu_mfma_kernel<<<dim3(17, 4, B_), 256, 0, stream>>>(
            R1, U, Wtp, out_b, stats, layer);
        bn_kernel<<<dim3((LT + 255) / 256, DM, B_), 256, 0, stream>>>(
            U, Ub, stats, bn_gamma, bn_beta, layer);
    }

    head_kernel<<<dim3(H_, B_), 128, 0, stream>>>(
        U, head_W1, head_b1, head_W2, head_b2, (float*)d_out);
}

// Round 8
// 1082.674 us; speedup vs baseline: 3.7391x; 1.1319x over previous
//
#include <hip/hip_runtime.h>
#include <hip/hip_bf16.h>
#include <math.h>

#define B_   32
#define L_   2048
#define H_   8
#define DMET 16
#define SDIM 27
#define DM   256
#define NL   4
#define DS   64
#define TE   256
#define LT   2055          // L + H - 1
#define LTP  2056          // padded stride for U (fp32, [b][d][l])
#define LTR  2176          // 17*128: padded l for Ub/Ybt/Yb
#define TCH  128           // chunk length
#define NC   17            // chunks per sequence
#define COLS 544           // B_ * NC
#define NTOT (B_ * LT)

typedef __attribute__((ext_vector_type(8))) short short8;
typedef __attribute__((ext_vector_type(4))) short short4v;
typedef __attribute__((ext_vector_type(4))) float floatx4;

__device__ __forceinline__ float sigmoidf_(float x) {
    return 1.0f / (1.0f + expf(-x));
}

__device__ __forceinline__ float gelu_tanh(float x) {
    const float c0 = 0.7978845608028654f; // sqrt(2/pi)
    float x3 = x * x * x;
    float t = tanhf(c0 * (x + 0.044715f * x3));
    return 0.5f * x * (1.0f + t);
}

__device__ __forceinline__ short bfs(float x) {
    __hip_bfloat16 h = __float2bfloat16(x);
    return *(short*)&h;
}

__device__ __forceinline__ void glds16(const void* g, void* l) {
    __builtin_amdgcn_global_load_lds(
        (const __attribute__((address_space(1))) unsigned*)g,
        (__attribute__((address_space(3))) unsigned*)l, 16, 0, 0);
}

// ---------------------------------------------------------------------------
// 1) time MLP
// ---------------------------------------------------------------------------
__global__ __launch_bounds__(256) void time_mlp_kernel(
    const float* __restrict__ t, const float* __restrict__ freqs,
    const float* __restrict__ phases,
    const float* __restrict__ W1, const float* __restrict__ b1,
    const float* __restrict__ W2, const float* __restrict__ b2,
    float* __restrict__ tb) {
    int b = blockIdx.x;
    int tid = threadIdx.x;
    __shared__ float f[TE];
    __shared__ float hid[2 * TE];
    float tv = t[b];
    f[tid] = cosf(fmaf(tv, freqs[tid], phases[tid])) * 1.4142135623730951f;
    __syncthreads();
    float a0 = b1[tid], a1 = b1[tid + TE];
    for (int k = 0; k < TE; ++k) {
        float fk = f[k];
        a0 = fmaf(fk, W1[k * 2 * TE + tid], a0);
        a1 = fmaf(fk, W1[k * 2 * TE + tid + TE], a1);
    }
    hid[tid]      = a0 * sigmoidf_(a0);
    hid[tid + TE] = a1 * sigmoidf_(a1);
    __syncthreads();
    float acc = b2[tid];
    for (int j = 0; j < 2 * TE; ++j)
        acc = fmaf(hid[j], W2[j * DM + tid], acc);
    tb[b * DM + tid] = acc;
}

// ---------------------------------------------------------------------------
// 1b) out_W [NL][256][512] fp32 -> Wtp bf16 [NL][512 permuted cols][256 k]
// ---------------------------------------------------------------------------
__global__ __launch_bounds__(256) void wt_prep_kernel(
    const float* __restrict__ out_W, __hip_bfloat16* __restrict__ Wtp) {
    int bid = blockIdx.x;
    int layer = bid >> 8, k = bid & 255;
    int e = threadIdx.x;
    const float* src = out_W + ((size_t)layer * 256 + k) * 512;
    #pragma unroll
    for (int q = 0; q < 2; ++q) {
        int ee = e + q * 256;
        int P = ee & 255, half = ee >> 8;
        int by = P >> 6, pp = P & 63;
        int g = pp >> 5;
        int tcol = (pp & 31) + half * 32;
        int c = by * 128 + g * 64 + tcol;
        Wtp[((size_t)layer * 512 + c) * 256 + k] = __float2bfloat16(src[ee]);
    }
}

// ---------------------------------------------------------------------------
// 2) input projection -> U[b][d][l] fp32 and Ub[b][d][l] bf16
// ---------------------------------------------------------------------------
__global__ __launch_bounds__(256) void input_proj_kernel(
    const float* __restrict__ xp, const float* __restrict__ nf,
    const float* __restrict__ xf, const float* __restrict__ sa,
    const float* __restrict__ inW, const float* __restrict__ inb,
    const float* __restrict__ tb, float* __restrict__ U,
    __hip_bfloat16* __restrict__ Ub) {
    int b  = blockIdx.y;
    int l0 = blockIdx.x * 256;
    int tx = threadIdx.x;
    int l  = l0 + tx;

    __shared__ float feats[256][18];
    __shared__ float Ws[17][DM];
    __shared__ float sdot[DM];
    __shared__ float tbs[DM];
    __shared__ float sstat[SDIM];

    if (tx < SDIM) sstat[tx] = sa[b * SDIM + tx];
    for (int k = 0; k < 17; ++k) Ws[k][tx] = inW[k * DM + tx];
    tbs[tx] = tb[b * DM + tx];

    bool valid = (l < LT);
    if (valid) {
        const float* src = (l < L_) ? &xp[((size_t)b * L_ + l) * DMET]
                                    : &xf[((size_t)b * (H_ - 1) + (l - L_)) * DMET];
        #pragma unroll
        for (int k = 0; k < DMET; ++k) feats[tx][k] = src[k];
        feats[tx][16] = (l >= L_ - 1) ? nf[b * H_ + (l - (L_ - 1))] : 0.0f;
    }
    __syncthreads();

    float sd = 0.0f;
    for (int k = 0; k < SDIM; ++k)
        sd = fmaf(sstat[k], inW[(17 + k) * DM + tx], sd);
    sdot[tx] = sd;
    __syncthreads();

    if (!valid) return;
    bool cond = (l >= L_ - 1);
    size_t base  = ((size_t)b * DM) * LTP + l;
    size_t baseb = ((size_t)b * DM) * LTR + l;
    for (int d = 0; d < DM; ++d) {
        float acc = inb[d] + sdot[d] + (cond ? tbs[d] : 0.0f);
        #pragma unroll
        for (int k = 0; k < 17; ++k)
            acc = fmaf(feats[tx][k], Ws[k][d], acc);
        U[base + (size_t)d * LTP] = acc;
        Ub[baseb + (size_t)d * LTR] = __float2bfloat16(acc);
    }
}

// ---------------------------------------------------------------------------
// 2b) zero the l >= LT pad of Ub (poisoned each launch)
// ---------------------------------------------------------------------------
__global__ __launch_bounds__(128) void padzero_kernel(__hip_bfloat16* __restrict__ Ub) {
    int bd = blockIdx.x;
    int t = threadIdx.x;
    if (t < LTR - LT)
        Ub[(size_t)bd * LTR + LT + t] = __float2bfloat16(0.0f);
}

// ---------------------------------------------------------------------------
// 3a) per-layer per-channel matrix prep, fully parallel: w^p = exp(p*dt*A)
//     computed directly per element (matches reference Vandermonde exactly).
// ---------------------------------------------------------------------------
__global__ __launch_bounds__(256) void prep_kernel(
    const float* __restrict__ log_dt,
    const float* __restrict__ A_re, const float* __restrict__ A_im,
    const float* __restrict__ C_re, const float* __restrict__ C_im,
    const float* __restrict__ Dp,
    __hip_bfloat16* __restrict__ Abig, __hip_bfloat16* __restrict__ SA,
    int layer) {
    int d = blockIdx.x;
    int t = threadIdx.x;
    __shared__ float sAr[64], sAi[64], sCkr[64], sCki[64];
    __shared__ float kap[TCH];

    float dt = expf(log_dt[layer * DM + d]);
    float Dd = Dp[layer * DM + d];
    if (t < 64) {
        size_t ab = ((size_t)layer * DM + d) * DS + t;
        float Ar = A_re[ab], Ai = A_im[ab], Cr = C_re[ab], Ci = C_im[ab];
        float e = expf(dt * Ar);
        float wre = e * cosf(dt * Ai), wim = e * sinf(dt * Ai);
        float mr = wre - 1.0f, mi = wim;
        float den = 1.0f / (Ar * Ar + Ai * Ai);
        float qr = (mr * Ar + mi * Ai) * den, qi = (mi * Ar - mr * Ai) * den;
        sCkr[t] = Cr * qr - Ci * qi;
        sCki[t] = Cr * qi + Ci * qr;
        sAr[t] = dt * Ar;
        sAi[t] = dt * Ai;
    }
    __syncthreads();

    // kappa[delta] = 2 Re(sum_n Ck_n w^delta) ; kap[0] += D
    {
        int delta = t >> 1, half = t & 1;
        float fd = (float)delta;
        float p = 0.0f;
        #pragma unroll 8
        for (int n = half * 32; n < half * 32 + 32; ++n) {
            float er = expf(fd * sAr[n]);
            float ph = fd * sAi[n];
            p += er * (sCkr[n] * cosf(ph) - sCki[n] * sinf(ph));
        }
        p += __shfl_xor(p, 1);
        if (half == 0) kap[delta] = 2.0f * p + (delta == 0 ? Dd : 0.0f);
    }
    __syncthreads();

    __hip_bfloat16* Ad = Abig + (size_t)d * TCH * 256;
    for (int idx = t; idx < TCH * TCH; idx += 256) {
        int i = idx >> 7, m = idx & 127;
        Ad[(size_t)i * 256 + m] = __float2bfloat16(m <= i ? kap[i - m] : 0.0f);
    }
    // Vout[i][n] = Ck_n * w^{i+1}
    for (int idx = t; idx < TCH * 64; idx += 256) {
        int i = idx >> 6, n = idx & 63;
        float fp = (float)(i + 1);
        float er = expf(fp * sAr[n]);
        float ph = fp * sAi[n];
        float c = cosf(ph), s = sinf(ph);
        float vr = er * (sCkr[n] * c - sCki[n] * s);
        float vi = er * (sCkr[n] * s + sCki[n] * c);
        Ad[(size_t)i * 256 + 128 + n] = __float2bfloat16(2.0f * vr);
        Ad[(size_t)i * 256 + 192 + n] = __float2bfloat16(-2.0f * vi);
    }
    // Vin: SA[n][m] = Re(w^{127-m}), SA[64+n][m] = Im(w^{127-m})
    __hip_bfloat16* Sd = SA + (size_t)d * TCH * TCH;
    for (int idx = t; idx < 64 * TCH; idx += 256) {
        int n = idx >> 7, m = idx & 127;
        float fp = (float)(127 - m);
        float er = expf(fp * sAr[n]);
        float ph = fp * sAi[n];
        Sd[(size_t)n * 128 + m]        = __float2bfloat16(er * cosf(ph));
        Sd[(size_t)(64 + n) * 128 + m] = __float2bfloat16(er * sinf(ph));
    }
}

// ---------------------------------------------------------------------------
// 3b) S-GEMM: S[d][col][k 128] = Vin_d x u_chunk.  B staged in LDS once.
// ---------------------------------------------------------------------------
__global__ __launch_bounds__(256) void sgemm_kernel(
    const __hip_bfloat16* __restrict__ Ub, const __hip_bfloat16* __restrict__ SA,
    __hip_bfloat16* __restrict__ S) {
    int cb = blockIdx.x, d = blockIdx.y;
    int tid = threadIdx.x, wave = tid >> 6, lane = tid & 63;
    int lm = lane & 15, quad = lane >> 4;
    const __hip_bfloat16* SAd = SA + (size_t)d * TCH * TCH;

    __shared__ short Bs[8192];   // 4 sections x 64 cols x 32 shorts = 16 KB

    #pragma unroll
    for (int it = 0; it < 4; ++it) {
        int idx = it * 256 + tid;
        int kk = idx >> 8;
        int colloc = (idx >> 2) & 63;
        int part = idx & 3;
        int col = cb * 64 + colloc;
        int colc = col < COLS ? col : COLS - 1;
        int bh = (colc * 241) >> 12;
        int c = colc - bh * 17;
        const __hip_bfloat16* src =
            Ub + ((size_t)bh * DM + d) * LTR + (size_t)c * TCH + kk * 32 + part * 8;
        glds16(src, (char*)Bs + idx * 16);
    }
    asm volatile("s_waitcnt vmcnt(0)" ::: "memory");
    __syncthreads();

    floatx4 acc[2][4];
    floatx4 zf = {0.f, 0.f, 0.f, 0.f};
    #pragma unroll
    for (int mi = 0; mi < 2; ++mi)
        #pragma unroll
        for (int nt = 0; nt < 4; ++nt) acc[mi][nt] = zf;

    #pragma unroll
    for (int kk = 0; kk < 4; ++kk) {
        short8 a0 = *(const short8*)(SAd + (size_t)(wave * 32 + lm) * TCH + kk * 32 + quad * 8);
        short8 a1 = *(const short8*)(SAd + (size_t)(wave * 32 + 16 + lm) * TCH + kk * 32 + quad * 8);
        #pragma unroll
        for (int nt = 0; nt < 4; ++nt) {
            short8 bv = *(const short8*)(Bs + kk * 2048 + (nt * 16 + lm) * 32 + quad * 8);
            acc[0][nt] = __builtin_amdgcn_mfma_f32_16x16x32_bf16(a0, bv, acc[0][nt], 0, 0, 0);
            acc[1][nt] = __builtin_amdgcn_mfma_f32_16x16x32_bf16(a1, bv, acc[1][nt], 0, 0, 0);
        }
    }
    #pragma unroll
    for (int mi = 0; mi < 2; ++mi)
        #pragma unroll
        for (int nt = 0; nt < 4; ++nt) {
            int col = cb * 64 + nt * 16 + lm;
            if (col >= COLS) continue;
            int row = wave * 32 + mi * 16 + quad * 4;
            short4v o;
            o[0] = bfs(acc[mi][nt][0]); o[1] = bfs(acc[mi][nt][1]);
            o[2] = bfs(acc[mi][nt][2]); o[3] = bfs(acc[mi][nt][3]);
            *(short4v*)(S + ((size_t)d * COLS + col) * TCH + row) = o;
        }
}

// ---------------------------------------------------------------------------
// 3c) carry scan over chunks (in place)
// ---------------------------------------------------------------------------
__global__ __launch_bounds__(64) void carry_kernel(
    __hip_bfloat16* __restrict__ SX,
    const float* __restrict__ log_dt,
    const float* __restrict__ A_re, const float* __restrict__ A_im,
    int layer) {
    int d = blockIdx.x, b = blockIdx.y;
    int n = threadIdx.x;
    float dt = expf(log_dt[layer * DM + d]);
    size_t ab = ((size_t)layer * DM + d) * DS + n;
    float Ar = A_re[ab], Ai = A_im[ab];
    float e = expf(dt * Ar);
    float wre = e * cosf(dt * Ai), wim = e * sinf(dt * Ai);
    #pragma unroll
    for (int t = 0; t < 7; ++t) {
        float r = wre * wre - wim * wim;
        wim = 2.0f * wre * wim; wre = r;
    }
    float xr = 0.0f, xi = 0.0f;
    for (int c = 0; c < NC; ++c) {
        size_t addr = ((size_t)d * COLS + b * NC + c) * TCH;
        float sre = __bfloat162float(SX[addr + n]);
        float sim = __bfloat162float(SX[addr + 64 + n]);
        SX[addr + n]      = __float2bfloat16(xr);
        SX[addr + 64 + n] = __float2bfloat16(xi);
        float nr = wre * xr - wim * xi + sre;
        xi = wre * xi + wim * xr + sim;
        xr = nr;
    }
}

// ---------------------------------------------------------------------------
// 3d) main chunk GEMM: y = [Toep | Vout] x [u ; x], gelu -> Ybt[b][d][l].
// ---------------------------------------------------------------------------
__global__ __launch_bounds__(256) void mainscan_kernel(
    const __hip_bfloat16* __restrict__ Ub, const __hip_bfloat16* __restrict__ X,
    const __hip_bfloat16* __restrict__ Abig, __hip_bfloat16* __restrict__ Ybt) {
    int cb = blockIdx.x, d = blockIdx.y;
    int tid = threadIdx.x, wave = tid >> 6, lane = tid & 63;
    int lm = lane & 15, quad = lane >> 4;
    const __hip_bfloat16* Ad = Abig + (size_t)d * TCH * 256;

    __shared__ short Bs[16384];  // 8 sections x 64 cols x 32 shorts = 32 KB

    #pragma unroll
    for (int it = 0; it < 8; ++it) {
        int idx = it * 256 + tid;
        int kk = idx >> 8;
        int colloc = (idx >> 2) & 63;
        int part = idx & 3;
        int col = cb * 64 + colloc;
        int colc = col < COLS ? col : COLS - 1;
        int bh = (colc * 241) >> 12;
        int c = colc - bh * 17;
        const __hip_bfloat16* src;
        if (kk < 4)
            src = Ub + ((size_t)bh * DM + d) * LTR + (size_t)c * TCH + kk * 32 + part * 8;
        else
            src = X + ((size_t)d * COLS + colc) * TCH + (kk - 4) * 32 + part * 8;
        glds16(src, (char*)Bs + idx * 16);
    }
    asm volatile("s_waitcnt vmcnt(0)" ::: "memory");
    __syncthreads();

    floatx4 acc[2][4];
    floatx4 zf = {0.f, 0.f, 0.f, 0.f};
    #pragma unroll
    for (int mi = 0; mi < 2; ++mi)
        #pragma unroll
        for (int nt = 0; nt < 4; ++nt) acc[mi][nt] = zf;

    #pragma unroll
    for (int kk = 0; kk < 8; ++kk) {
        short8 a0 = *(const short8*)(Ad + (size_t)(wave * 32 + lm) * 256 + kk * 32 + quad * 8);
        short8 a1 = *(const short8*)(Ad + (size_t)(wave * 32 + 16 + lm) * 256 + kk * 32 + quad * 8);
        #pragma unroll
        for (int nt = 0; nt < 4; ++nt) {
            short8 bv = *(const short8*)(Bs + kk * 2048 + (nt * 16 + lm) * 32 + quad * 8);
            acc[0][nt] = __builtin_amdgcn_mfma_f32_16x16x32_bf16(a0, bv, acc[0][nt], 0, 0, 0);
            acc[1][nt] = __builtin_amdgcn_mfma_f32_16x16x32_bf16(a1, bv, acc[1][nt], 0, 0, 0);
        }
    }

    #pragma unroll
    for (int mi = 0; mi < 2; ++mi)
        #pragma unroll
        for (int nt = 0; nt < 4; ++nt) {
            int col = cb * 64 + nt * 16 + lm;
            if (col >= COLS) continue;
            int bh = (col * 241) >> 12;
            int c = col - bh * 17;
            int row0 = wave * 32 + mi * 16 + quad * 4;
            int l0 = c * TCH + row0;
            float g0 = gelu_tanh(acc[mi][nt][0]);
            float g1 = gelu_tanh(acc[mi][nt][1]);
            float g2 = gelu_tanh(acc[mi][nt][2]);
            float g3 = gelu_tanh(acc[mi][nt][3]);
            __hip_bfloat16* dst = Ybt + ((size_t)bh * DM + d) * LTR + l0;
            if (l0 + 3 < LT) {
                short4v o;
                o[0] = bfs(g0); o[1] = bfs(g1); o[2] = bfs(g2); o[3] = bfs(g3);
                *(short4v*)dst = o;
            } else {
                if (l0 + 0 < LT) dst[0] = __float2bfloat16(g0);
                if (l0 + 1 < LT) dst[1] = __float2bfloat16(g1);
                if (l0 + 2 < LT) dst[2] = __float2bfloat16(g2);
                if (l0 + 3 < LT) dst[3] = __float2bfloat16(g3);
            }
        }
}

// ---------------------------------------------------------------------------
// 3e) transpose Ybt[b][d][l] -> Yb[b][l][d]
// ---------------------------------------------------------------------------
__global__ __launch_bounds__(256) void transpose_kernel(
    const __hip_bfloat16* __restrict__ Ybt, __hip_bfloat16* __restrict__ Yb) {
    int lt = blockIdx.x, dti = blockIdx.y, b = blockIdx.z;
    int t = threadIdx.x;
    __shared__ short tileT[64 * 66];   // [l][d], stride 66
    int l0 = lt * 64, d0 = dti * 64;
    #pragma unroll
    for (int r = 0; r < 2; ++r) {
        int idx = r * 256 + t;
        int dd = idx >> 3, lseg = idx & 7;
        short8 v = *(const short8*)(Ybt + ((size_t)b * DM + d0 + dd) * LTR + l0 + lseg * 8);
        #pragma unroll
        for (int i = 0; i < 8; ++i)
            tileT[(lseg * 8 + i) * 66 + dd] = v[i];
    }
    __syncthreads();
    #pragma unroll
    for (int r = 0; r < 2; ++r) {
        int idx = r * 256 + t;
        int ll = idx >> 3, dseg = idx & 7;
        short8 v;
        #pragma unroll
        for (int i = 0; i < 8; ++i)
            v[i] = tileT[ll * 66 + dseg * 8 + i];
        *(short8*)(Yb + ((size_t)b * LTR + l0 + ll) * DM + d0 + dseg * 8) = v;
    }
}

// ---------------------------------------------------------------------------
// 4) LDS-staged MFMA GEMM + GLU + residual + BN stats.  BK=64 (4 K-steps).
//    Chunk swizzle: c = (q + r) & 7  ->  frag ds_read_b128 2-way only.
// ---------------------------------------------------------------------------
__global__ __launch_bounds__(256) void gemm_glu_mfma_kernel(
    const __hip_bfloat16* __restrict__ Yb, float* __restrict__ U,
    const __hip_bfloat16* __restrict__ Wtp, const float* __restrict__ out_b,
    float* __restrict__ stats, int layer) {
    int bx = blockIdx.x, by = blockIdx.y, b = blockIdx.z;
    int tid = threadIdx.x;
    int wave = tid >> 6, lane = tid & 63;
    int lm = lane & 15, quad = lane >> 4;
    int l0 = bx * 128;

    __shared__ short lds[16384];          // A: [0,8192) shorts, B: [8192,16384)
    short* Asb = lds;
    short* Bsb = lds + 8192;

    const __hip_bfloat16* Yb_b = Yb + (size_t)b * LTR * DM;
    const __hip_bfloat16* Wl = Wtp + (size_t)layer * 512 * 256 + (size_t)by * 128 * 256;

    floatx4 acc[4][4];
    floatx4 zf = {0.f, 0.f, 0.f, 0.f};
    #pragma unroll
    for (int mi = 0; mi < 4; ++mi)
        #pragma unroll
        for (int ni = 0; ni < 4; ++ni) acc[mi][ni] = zf;

    // staging: idx = i*256+tid -> row = idx>>3, c = idx&7, q = (c - row) & 7
    int rowS[4], qS[4];
    #pragma unroll
    for (int i = 0; i < 4; ++i) {
        int idx = i * 256 + tid;
        rowS[i] = idx >> 3;
        qS[i] = ((idx & 7) - rowS[i]) & 7;
    }
    // frag offsets (shorts): r*64 + ((q + r) & 7)*8, q = kh*4 + quad
    int aoff[2][4], boff[2][4];
    #pragma unroll
    for (int kh = 0; kh < 2; ++kh) {
        #pragma unroll
        for (int mi = 0; mi < 4; ++mi) {
            int r = (wave >> 1) * 64 + mi * 16 + lm;
            aoff[kh][mi] = r * 64 + ((kh * 4 + quad + r) & 7) * 8;
        }
        #pragma unroll
        for (int ni = 0; ni < 4; ++ni) {
            int r = (wave & 1) * 64 + ni * 16 + lm;
            boff[kh][ni] = r * 64 + ((kh * 4 + quad + r) & 7) * 8;
        }
    }

    for (int ks = 0; ks < 4; ++ks) {
        int k0 = ks * 64;
        __syncthreads();
        #pragma unroll
        for (int i = 0; i < 4; ++i) {
            const __hip_bfloat16* ga = Yb_b + (size_t)(l0 + rowS[i]) * DM + k0 + qS[i] * 8;
            glds16(ga, (char*)Asb + i * 4096 + wave * 1024 + (lane & 63) * 16);
            const __hip_bfloat16* gb = Wl + (size_t)rowS[i] * 256 + k0 + qS[i] * 8;
            glds16(gb, (char*)Bsb + i * 4096 + wave * 1024 + (lane & 63) * 16);
        }
        asm volatile("s_waitcnt vmcnt(0)" ::: "memory");
        __syncthreads();

        #pragma unroll
        for (int kh = 0; kh < 2; ++kh) {
            short8 af[4], bf4[4];
            #pragma unroll
            for (int mi = 0; mi < 4; ++mi) af[mi] = *(const short8*)(Asb + aoff[kh][mi]);
            #pragma unroll
            for (int ni = 0; ni < 4; ++ni) bf4[ni] = *(const short8*)(Bsb + boff[kh][ni]);
            #pragma unroll
            for (int mi = 0; mi < 4; ++mi)
                #pragma unroll
                for (int ni = 0; ni < 4; ++ni)
                    acc[mi][ni] = __builtin_amdgcn_mfma_f32_16x16x32_bf16(
                        af[mi], bf4[ni], acc[mi][ni], 0, 0, 0);
        }
    }

    const float* bl = out_b + layer * 512;
    int Pbase = by * 64 + (wave & 1) * 32;
    int lw = l0 + (wave >> 1) * 64;
    #pragma unroll
    for (int ni = 0; ni < 2; ++ni) {
        int P = Pbase + ni * 16 + lm;
        float bz1 = bl[P], bz2 = bl[256 + P];
        float* urow = U + ((size_t)b * DM + P) * LTP;
        float sp = 0.f, sq = 0.f;
        #pragma unroll
        for (int mi = 0; mi < 4; ++mi) {
            int l0q = lw + mi * 16 + quad * 4;
            if (l0q >= LT) continue;
            floatx4 z1 = acc[mi][ni];
            floatx4 z2 = acc[mi][ni + 2];
            if (l0q + 4 <= LT) {
                float4 uv = *(const float4*)(urow + l0q);
                float h0 = uv.x + (z1[0] + bz1) * sigmoidf_(z2[0] + bz2);
                float h1 = uv.y + (z1[1] + bz1) * sigmoidf_(z2[1] + bz2);
                float h2 = uv.z + (z1[2] + bz1) * sigmoidf_(z2[2] + bz2);
                float h3 = uv.w + (z1[3] + bz1) * sigmoidf_(z2[3] + bz2);
                *(float4*)(urow + l0q) = make_float4(h0, h1, h2, h3);
                sp += (h0 + h1) + (h2 + h3);
                sq += (h0 * h0 + h1 * h1) + (h2 * h2 + h3 * h3);
            } else {
                #pragma unroll
                for (int r = 0; r < 4; ++r) {
                    int l = l0q + r;
                    if (l < LT) {
                        float uvv = urow[l];
                        float hh = uvv + (z1[r] + bz1) * sigmoidf_(z2[r] + bz2);
                        urow[l] = hh;
                        sp += hh; sq += hh * hh;
                    }
                }
            }
        }
        sp += __shfl_xor(sp, 16); sp += __shfl_xor(sp, 32);
        sq += __shfl_xor(sq, 16); sq += __shfl_xor(sq, 32);
        if (quad == 0) {
            atomicAdd(&stats[P], sp);
            atomicAdd(&stats[DM + P], sq);
        }
    }
}

// ---------------------------------------------------------------------------
// 5) BatchNorm normalize (in-place on U) + write Ub bf16 for next layer
// ---------------------------------------------------------------------------
__global__ __launch_bounds__(256) void bn_kernel(
    float* __restrict__ U, __hip_bfloat16* __restrict__ Ub,
    const float* __restrict__ stats,
    const float* __restrict__ gamma, const float* __restrict__ beta, int layer) {
    int l = blockIdx.x * 256 + threadIdx.x;
    int d = blockIdx.y, b = blockIdx.z;
    if (l >= LT) return;
    float s = stats[d], q = stats[DM + d];
    float mean = s * (1.0f / NTOT);
    float var  = q * (1.0f / NTOT) - mean * mean;
    float sc = rsqrtf(var + 1e-5f) * gamma[layer * DM + d];
    float sh = beta[layer * DM + d] - mean * sc;
    size_t idx = ((size_t)b * DM + d) * LTP + l;
    float v = fmaf(U[idx], sc, sh);
    U[idx] = v;
    Ub[((size_t)b * DM + d) * LTR + l] = __float2bfloat16(v);
}

// ---------------------------------------------------------------------------
// 6) head
// ---------------------------------------------------------------------------
__global__ __launch_bounds__(128) void head_kernel(
    const float* __restrict__ U,
    const float* __restrict__ W1, const float* __restrict__ b1,
    const float* __restrict__ W2, const float* __restrict__ b2,
    float* __restrict__ out) {
    int hh = blockIdx.x;
    int b  = blockIdx.y;
    int j  = threadIdx.x;
    int l  = (L_ - 1) + hh;
    const float* urow = U + ((size_t)b * DM) * LTP + l;
    float a = b1[j];
    for (int k = 0; k < DM; ++k)
        a = fmaf(urow[(size_t)k * LTP], W1[k * 128 + j], a);
    float hs = a * sigmoidf_(a);
    float v = hs * W2[j];
    v += __shfl_xor(v, 1);
    v += __shfl_xor(v, 2);
    v += __shfl_xor(v, 4);
    v += __shfl_xor(v, 8);
    v += __shfl_xor(v, 16);
    v += __shfl_xor(v, 32);
    __shared__ float partial[2];
    if ((j & 63) == 0) partial[j >> 6] = v;
    __syncthreads();
    if (j == 0) out[b * H_ + hh] = partial[0] + partial[1] + b2[0];
}

// ---------------------------------------------------------------------------
extern "C" void kernel_launch(void* const* d_in, const int* in_sizes, int n_in,
                              void* d_out, int out_size, void* d_ws, size_t ws_size,
                              hipStream_t stream) {
    (void)in_sizes; (void)n_in; (void)out_size; (void)ws_size;
    const float* x_past      = (const float*)d_in[0];
    const float* noisy       = (const float*)d_in[1];
    const float* t_in        = (const float*)d_in[2];
    const float* x_future    = (const float*)d_in[3];
    const float* static_attr = (const float*)d_in[4];
    const float* freqs       = (const float*)d_in[5];
    const float* phases      = (const float*)d_in[6];
    const float* in_W        = (const float*)d_in[7];
    const float* in_b        = (const float*)d_in[8];
    const float* tm_W1       = (const float*)d_in[9];
    const float* tm_b1       = (const float*)d_in[10];
    const float* tm_W2       = (const float*)d_in[11];
    const float* tm_b2       = (const float*)d_in[12];
    const float* log_dt      = (const float*)d_in[13];
    const float* A_re        = (const float*)d_in[14];
    const float* A_im        = (const float*)d_in[15];
    const float* C_re        = (const float*)d_in[16];
    const float* C_im        = (const float*)d_in[17];
    const float* Dp          = (const float*)d_in[18];
    const float* out_W       = (const float*)d_in[19];
    const float* out_b       = (const float*)d_in[20];
    const float* bn_gamma    = (const float*)d_in[21];
    const float* bn_beta     = (const float*)d_in[22];
    const float* head_W1     = (const float*)d_in[23];
    const float* head_b1     = (const float*)d_in[24];
    const float* head_W2     = (const float*)d_in[25];
    const float* head_b2     = (const float*)d_in[26];

    char* ws = (char*)d_ws;
    const size_t U_OFF  = 1u << 20;
    const size_t U_BYT  = (size_t)B_ * DM * LTP * 4;
    const size_t UB_OFF = U_OFF + U_BYT;
    const size_t UB_BYT = (size_t)B_ * DM * LTR * 2;
    const size_t R1_OFF = UB_OFF + UB_BYT;
    const size_t RB     = (size_t)256 * COLS * TCH * 2;
    const size_t R2_OFF = R1_OFF + RB;
    const size_t AB_OFF = R2_OFF + RB;
    const size_t AB_BYT = (size_t)256 * TCH * 256 * 2;
    const size_t SA_OFF = AB_OFF + AB_BYT;
    const size_t SA_BYT = (size_t)256 * TCH * TCH * 2;
    const size_t WT_OFF = SA_OFF + SA_BYT;

    float*          tb    = (float*)(ws);
    float*          stats = (float*)(ws + (64 << 10));
    float*          U     = (float*)(ws + U_OFF);
    __hip_bfloat16* Ub    = (__hip_bfloat16*)(ws + UB_OFF);
    __hip_bfloat16* R1    = (__hip_bfloat16*)(ws + R1_OFF);  // S/X, later Yb
    __hip_bfloat16* Ybt   = (__hip_bfloat16*)(ws + R2_OFF);
    __hip_bfloat16* Abig  = (__hip_bfloat16*)(ws + AB_OFF);
    __hip_bfloat16* SA    = (__hip_bfloat16*)(ws + SA_OFF);
    __hip_bfloat16* Wtp   = (__hip_bfloat16*)(ws + WT_OFF);

    time_mlp_kernel<<<dim3(B_), 256, 0, stream>>>(
        t_in, freqs, phases, tm_W1, tm_b1, tm_W2, tm_b2, tb);

    wt_prep_kernel<<<dim3(NL * 256), 256, 0, stream>>>(out_W, Wtp);

    input_proj_kernel<<<dim3((LT + 255) / 256, B_), 256, 0, stream>>>(
        x_past, noisy, x_future, static_attr, in_W, in_b, tb, U, Ub);

    padzero_kernel<<<dim3(B_ * DM), 128, 0, stream>>>(Ub);

    for (int layer = 0; layer < NL; ++layer) {
        prep_kernel<<<dim3(256), 256, 0, stream>>>(
            log_dt, A_re, A_im, C_re, C_im, Dp, Abig, SA, layer);
        sgemm_kernel<<<dim3(9, 256), 256, 0, stream>>>(Ub, SA, R1);
        carry_kernel<<<dim3(256, B_), 64, 0, stream>>>(
            R1, log_dt, A_re, A_im, layer);
        mainscan_kernel<<<dim3(9, 256), 256, 0, stream>>>(Ub, R1, Abig, Ybt);
        transpose_kernel<<<dim3(LTR / 64, DM / 64, B_), 256, 0, stream>>>(Ybt, R1);
        hipMemsetAsync(stats, 0, 2 * DM * sizeof(float), stream);
        gemm_glu_mfma_kernel<<<dim3(17, 4, B_), 256, 0, stream>>>(
            R1, U, Wtp, out_b, stats, layer);
        bn_kernel<<<dim3((LT + 255) / 256, DM, B_), 256, 0, stream>>>(
            U, Ub, stats, bn_gamma, bn_beta, layer);
    }

    head_kernel<<<dim3(H_, B_), 128, 0, stream>>>(
        U, head_W1, head_b1, head_W2, head_b2, (float*)d_out);
}

// Round 9
// 1026.791 us; speedup vs baseline: 3.9426x; 1.0544x over previous
//
#include <hip/hip_runtime.h>
#include <hip/hip_bf16.h>
#include <math.h>

#define B_   32
#define L_   2048
#define H_   8
#define DMET 16
#define SDIM 27
#define DM   256
#define NL   4
#define DS   64
#define TE   256
#define LT   2055          // L + H - 1
#define LTP  2056          // padded stride for U (fp32, [b][d][l])
#define LTR  2176          // 17*128: padded l for Ub/Ybt/Yb
#define TCH  128           // chunk length
#define NC   17            // chunks per sequence
#define COLS 544           // B_ * NC
#define NTOT (B_ * LT)

typedef __attribute__((ext_vector_type(8))) short short8;
typedef __attribute__((ext_vector_type(4))) short short4v;
typedef __attribute__((ext_vector_type(4))) float floatx4;

__device__ __forceinline__ float sigmoidf_(float x) {
    return 1.0f / (1.0f + expf(-x));
}

__device__ __forceinline__ float gelu_tanh(float x) {
    const float c0 = 0.7978845608028654f; // sqrt(2/pi)
    float x3 = x * x * x;
    float t = tanhf(c0 * (x + 0.044715f * x3));
    return 0.5f * x * (1.0f + t);
}

__device__ __forceinline__ short bfs(float x) {
    __hip_bfloat16 h = __float2bfloat16(x);
    return *(short*)&h;
}

__device__ __forceinline__ void glds16(const void* g, void* l) {
    __builtin_amdgcn_global_load_lds(
        (const __attribute__((address_space(1))) unsigned*)g,
        (__attribute__((address_space(3))) unsigned*)l, 16, 0, 0);
}

// ---------------------------------------------------------------------------
// 1) time MLP
// ---------------------------------------------------------------------------
__global__ __launch_bounds__(256) void time_mlp_kernel(
    const float* __restrict__ t, const float* __restrict__ freqs,
    const float* __restrict__ phases,
    const float* __restrict__ W1, const float* __restrict__ b1,
    const float* __restrict__ W2, const float* __restrict__ b2,
    float* __restrict__ tb) {
    int b = blockIdx.x;
    int tid = threadIdx.x;
    __shared__ float f[TE];
    __shared__ float hid[2 * TE];
    float tv = t[b];
    f[tid] = cosf(fmaf(tv, freqs[tid], phases[tid])) * 1.4142135623730951f;
    __syncthreads();
    float a0 = b1[tid], a1 = b1[tid + TE];
    for (int k = 0; k < TE; ++k) {
        float fk = f[k];
        a0 = fmaf(fk, W1[k * 2 * TE + tid], a0);
        a1 = fmaf(fk, W1[k * 2 * TE + tid + TE], a1);
    }
    hid[tid]      = a0 * sigmoidf_(a0);
    hid[tid + TE] = a1 * sigmoidf_(a1);
    __syncthreads();
    float acc = b2[tid];
    for (int j = 0; j < 2 * TE; ++j)
        acc = fmaf(hid[j], W2[j * DM + tid], acc);
    tb[b * DM + tid] = acc;
}

// ---------------------------------------------------------------------------
// 1b) out_W [NL][256][512] fp32 -> Wtp bf16 [NL][512 permuted cols][256 k]
// ---------------------------------------------------------------------------
__global__ __launch_bounds__(256) void wt_prep_kernel(
    const float* __restrict__ out_W, __hip_bfloat16* __restrict__ Wtp) {
    int bid = blockIdx.x;
    int layer = bid >> 8, k = bid & 255;
    int e = threadIdx.x;
    const float* src = out_W + ((size_t)layer * 256 + k) * 512;
    #pragma unroll
    for (int q = 0; q < 2; ++q) {
        int ee = e + q * 256;
        int P = ee & 255, half = ee >> 8;
        int by = P >> 6, pp = P & 63;
        int g = pp >> 5;
        int tcol = (pp & 31) + half * 32;
        int c = by * 128 + g * 64 + tcol;
        Wtp[((size_t)layer * 512 + c) * 256 + k] = __float2bfloat16(src[ee]);
    }
}

// ---------------------------------------------------------------------------
// 1c) init scsh to identity (layer-0 "normalization")
// ---------------------------------------------------------------------------
__global__ __launch_bounds__(256) void initscsh_kernel(float* __restrict__ scsh) {
    int d = threadIdx.x;
    scsh[d] = 1.0f;
    scsh[DM + d] = 0.0f;
}

// ---------------------------------------------------------------------------
// 2) input projection -> U[b][d][l] fp32 and Ub[b][d][l] bf16
// ---------------------------------------------------------------------------
__global__ __launch_bounds__(256) void input_proj_kernel(
    const float* __restrict__ xp, const float* __restrict__ nf,
    const float* __restrict__ xf, const float* __restrict__ sa,
    const float* __restrict__ inW, const float* __restrict__ inb,
    const float* __restrict__ tb, float* __restrict__ U,
    __hip_bfloat16* __restrict__ Ub) {
    int b  = blockIdx.y;
    int l0 = blockIdx.x * 256;
    int tx = threadIdx.x;
    int l  = l0 + tx;

    __shared__ float feats[256][18];
    __shared__ float Ws[17][DM];
    __shared__ float sdot[DM];
    __shared__ float tbs[DM];
    __shared__ float sstat[SDIM];

    if (tx < SDIM) sstat[tx] = sa[b * SDIM + tx];
    for (int k = 0; k < 17; ++k) Ws[k][tx] = inW[k * DM + tx];
    tbs[tx] = tb[b * DM + tx];

    bool valid = (l < LT);
    if (valid) {
        const float* src = (l < L_) ? &xp[((size_t)b * L_ + l) * DMET]
                                    : &xf[((size_t)b * (H_ - 1) + (l - L_)) * DMET];
        #pragma unroll
        for (int k = 0; k < DMET; ++k) feats[tx][k] = src[k];
        feats[tx][16] = (l >= L_ - 1) ? nf[b * H_ + (l - (L_ - 1))] : 0.0f;
    }
    __syncthreads();

    float sd = 0.0f;
    for (int k = 0; k < SDIM; ++k)
        sd = fmaf(sstat[k], inW[(17 + k) * DM + tx], sd);
    sdot[tx] = sd;
    __syncthreads();

    if (!valid) return;
    bool cond = (l >= L_ - 1);
    size_t base  = ((size_t)b * DM) * LTP + l;
    size_t baseb = ((size_t)b * DM) * LTR + l;
    for (int d = 0; d < DM; ++d) {
        float acc = inb[d] + sdot[d] + (cond ? tbs[d] : 0.0f);
        #pragma unroll
        for (int k = 0; k < 17; ++k)
            acc = fmaf(feats[tx][k], Ws[k][d], acc);
        U[base + (size_t)d * LTP] = acc;
        Ub[baseb + (size_t)d * LTR] = __float2bfloat16(acc);
    }
}

// ---------------------------------------------------------------------------
// 2b) zero the l >= LT pad of Ub (poisoned each launch)
// ---------------------------------------------------------------------------
__global__ __launch_bounds__(128) void padzero_kernel(__hip_bfloat16* __restrict__ Ub) {
    int bd = blockIdx.x;
    int t = threadIdx.x;
    if (t < LTR - LT)
        Ub[(size_t)bd * LTR + LT + t] = __float2bfloat16(0.0f);
}

// ---------------------------------------------------------------------------
// 3a) per-layer per-channel matrix prep with BN folding:
//     Toep & Vin scaled by sc_d; correction vectors Rsh (sgemm) & T1sh
//     (mainscan) carry the sh_d * (matrix row-sum) terms.  Vout unscaled.
// ---------------------------------------------------------------------------
__global__ __launch_bounds__(256) void prep_kernel(
    const float* __restrict__ log_dt,
    const float* __restrict__ A_re, const float* __restrict__ A_im,
    const float* __restrict__ C_re, const float* __restrict__ C_im,
    const float* __restrict__ Dp, const float* __restrict__ scsh,
    __hip_bfloat16* __restrict__ Abig, __hip_bfloat16* __restrict__ SA,
    float* __restrict__ Rsh, float* __restrict__ T1sh, int layer) {
    int d = blockIdx.x;
    int t = threadIdx.x;
    __shared__ float sAr[64], sAi[64], sCkr[64], sCki[64];
    __shared__ float kap[TCH];
    __shared__ float csum[TCH];

    float sc = scsh[d], sh = scsh[DM + d];
    float dt = expf(log_dt[layer * DM + d]);
    float Dd = Dp[layer * DM + d];
    if (t < 64) {
        size_t ab = ((size_t)layer * DM + d) * DS + t;
        float Ar = A_re[ab], Ai = A_im[ab], Cr = C_re[ab], Ci = C_im[ab];
        float ar = dt * Ar, ai = dt * Ai;
        float e = expf(ar);
        float wre = e * cosf(ai), wim = e * sinf(ai);
        float mr = wre - 1.0f, mi = wim;
        float den = 1.0f / (Ar * Ar + Ai * Ai);
        float qr = (mr * Ar + mi * Ai) * den, qi = (mi * Ar - mr * Ai) * den;
        sCkr[t] = Cr * qr - Ci * qi;
        sCki[t] = Cr * qi + Ci * qr;
        sAr[t] = ar;
        sAi[t] = ai;
        // gsum = sum_{p=0}^{127} w^p = (w^128 - 1)/(w - 1), stable forms
        float s2 = sinf(0.5f * ai);
        float dr = fmaf(expm1f(ar), cosf(ai), -2.0f * s2 * s2);
        float di = e * sinf(ai);
        float a128 = 128.0f * ar, b128 = 128.0f * ai;
        float s2b = sinf(0.5f * b128);
        float nr = fmaf(expm1f(a128), cosf(b128), -2.0f * s2b * s2b);
        float ni = expf(a128) * sinf(b128);
        float dd2 = 1.0f / (dr * dr + di * di);
        float gr = (nr * dr + ni * di) * dd2;
        float gi = (ni * dr - nr * di) * dd2;
        Rsh[(size_t)d * 128 + t]      = sh * gr;
        Rsh[(size_t)d * 128 + 64 + t] = sh * gi;
    }
    __syncthreads();

    // kappa[delta] = 2 Re(sum_n Ck_n w^delta) ; kap[0] += D
    {
        int delta = t >> 1, half = t & 1;
        float fd = (float)delta;
        float p = 0.0f;
        #pragma unroll 8
        for (int n = half * 32; n < half * 32 + 32; ++n) {
            float er = expf(fd * sAr[n]);
            float ph = fd * sAi[n];
            p += er * (sCkr[n] * cosf(ph) - sCki[n] * sinf(ph));
        }
        p += __shfl_xor(p, 1);
        if (half == 0) kap[delta] = 2.0f * p + (delta == 0 ? Dd : 0.0f);
    }
    __syncthreads();

    // cumsum(kap) -> T1sh (Hillis-Steele, 128 lanes, full-block barriers)
    if (t < 128) csum[t] = kap[t];
    __syncthreads();
    for (int off = 1; off < 128; off <<= 1) {
        float v = 0.0f;
        if (t >= off && t < 128) v = csum[t - off];
        __syncthreads();
        if (t < 128) csum[t] += v;
        __syncthreads();
    }
    if (t < 128) T1sh[(size_t)d * 128 + t] = sh * csum[t];

    __hip_bfloat16* Ad = Abig + (size_t)d * TCH * 256;
    for (int idx = t; idx < TCH * TCH; idx += 256) {
        int i = idx >> 7, m = idx & 127;
        Ad[(size_t)i * 256 + m] = __float2bfloat16(m <= i ? sc * kap[i - m] : 0.0f);
    }
    // Vout[i][n] = Ck_n * w^{i+1}  (unscaled - states are true states)
    for (int idx = t; idx < TCH * 64; idx += 256) {
        int i = idx >> 6, n = idx & 63;
        float fp = (float)(i + 1);
        float er = expf(fp * sAr[n]);
        float ph = fp * sAi[n];
        float c = cosf(ph), s = sinf(ph);
        float vr = er * (sCkr[n] * c - sCki[n] * s);
        float vi = er * (sCkr[n] * s + sCki[n] * c);
        Ad[(size_t)i * 256 + 128 + n] = __float2bfloat16(2.0f * vr);
        Ad[(size_t)i * 256 + 192 + n] = __float2bfloat16(-2.0f * vi);
    }
    // Vin scaled by sc: SA[n][m] = sc*Re(w^{127-m}), SA[64+n][m] = sc*Im(...)
    __hip_bfloat16* Sd = SA + (size_t)d * TCH * TCH;
    for (int idx = t; idx < 64 * TCH; idx += 256) {
        int n = idx >> 7, m = idx & 127;
        float fp = (float)(127 - m);
        float er = sc * expf(fp * sAr[n]);
        float ph = fp * sAi[n];
        Sd[(size_t)n * 128 + m]        = __float2bfloat16(er * cosf(ph));
        Sd[(size_t)(64 + n) * 128 + m] = __float2bfloat16(er * sinf(ph));
    }
}

// ---------------------------------------------------------------------------
// 3b) S-GEMM: S[d][col][k 128] = (sc*Vin_d) x u' + Rsh  (= true state sum)
// ---------------------------------------------------------------------------
__global__ __launch_bounds__(256) void sgemm_kernel(
    const __hip_bfloat16* __restrict__ Ub, const __hip_bfloat16* __restrict__ SA,
    const float* __restrict__ Rsh, __hip_bfloat16* __restrict__ S) {
    int cb = blockIdx.x, d = blockIdx.y;
    int tid = threadIdx.x, wave = tid >> 6, lane = tid & 63;
    int lm = lane & 15, quad = lane >> 4;
    const __hip_bfloat16* SAd = SA + (size_t)d * TCH * TCH;

    __shared__ short Bs[8192];   // 4 sections x 64 cols x 32 shorts = 16 KB

    #pragma unroll
    for (int it = 0; it < 4; ++it) {
        int idx = it * 256 + tid;
        int kk = idx >> 8;
        int colloc = (idx >> 2) & 63;
        int part = idx & 3;
        int col = cb * 64 + colloc;
        int colc = col < COLS ? col : COLS - 1;
        int bh = (colc * 241) >> 12;
        int c = colc - bh * 17;
        const __hip_bfloat16* src =
            Ub + ((size_t)bh * DM + d) * LTR + (size_t)c * TCH + kk * 32 + part * 8;
        glds16(src, (char*)Bs + idx * 16);
    }
    asm volatile("s_waitcnt vmcnt(0)" ::: "memory");
    __syncthreads();

    floatx4 acc[2][4];
    floatx4 zf = {0.f, 0.f, 0.f, 0.f};
    #pragma unroll
    for (int mi = 0; mi < 2; ++mi)
        #pragma unroll
        for (int nt = 0; nt < 4; ++nt) acc[mi][nt] = zf;

    #pragma unroll
    for (int kk = 0; kk < 4; ++kk) {
        short8 a0 = *(const short8*)(SAd + (size_t)(wave * 32 + lm) * TCH + kk * 32 + quad * 8);
        short8 a1 = *(const short8*)(SAd + (size_t)(wave * 32 + 16 + lm) * TCH + kk * 32 + quad * 8);
        #pragma unroll
        for (int nt = 0; nt < 4; ++nt) {
            short8 bv = *(const short8*)(Bs + kk * 2048 + (nt * 16 + lm) * 32 + quad * 8);
            acc[0][nt] = __builtin_amdgcn_mfma_f32_16x16x32_bf16(a0, bv, acc[0][nt], 0, 0, 0);
            acc[1][nt] = __builtin_amdgcn_mfma_f32_16x16x32_bf16(a1, bv, acc[1][nt], 0, 0, 0);
        }
    }
    #pragma unroll
    for (int mi = 0; mi < 2; ++mi) {
        int row = wave * 32 + mi * 16 + quad * 4;
        float4 rs = *(const float4*)(Rsh + (size_t)d * 128 + row);
        #pragma unroll
        for (int nt = 0; nt < 4; ++nt) {
            int col = cb * 64 + nt * 16 + lm;
            if (col >= COLS) continue;
            short4v o;
            o[0] = bfs(acc[mi][nt][0] + rs.x); o[1] = bfs(acc[mi][nt][1] + rs.y);
            o[2] = bfs(acc[mi][nt][2] + rs.z); o[3] = bfs(acc[mi][nt][3] + rs.w);
            *(short4v*)(S + ((size_t)d * COLS + col) * TCH + row) = o;
        }
    }
}

// ---------------------------------------------------------------------------
// 3c) carry scan over chunks (in place)
// ---------------------------------------------------------------------------
__global__ __launch_bounds__(64) void carry_kernel(
    __hip_bfloat16* __restrict__ SX,
    const float* __restrict__ log_dt,
    const float* __restrict__ A_re, const float* __restrict__ A_im,
    int layer) {
    int d = blockIdx.x, b = blockIdx.y;
    int n = threadIdx.x;
    float dt = expf(log_dt[layer * DM + d]);
    size_t ab = ((size_t)layer * DM + d) * DS + n;
    float Ar = A_re[ab], Ai = A_im[ab];
    float e = expf(dt * Ar);
    float wre = e * cosf(dt * Ai), wim = e * sinf(dt * Ai);
    #pragma unroll
    for (int t = 0; t < 7; ++t) {
        float r = wre * wre - wim * wim;
        wim = 2.0f * wre * wim; wre = r;
    }
    float xr = 0.0f, xi = 0.0f;
    for (int c = 0; c < NC; ++c) {
        size_t addr = ((size_t)d * COLS + b * NC + c) * TCH;
        float sre = __bfloat162float(SX[addr + n]);
        float sim = __bfloat162float(SX[addr + 64 + n]);
        SX[addr + n]      = __float2bfloat16(xr);
        SX[addr + 64 + n] = __float2bfloat16(xi);
        float nr = wre * xr - wim * xi + sre;
        xi = wre * xi + wim * xr + sim;
        xr = nr;
    }
}

// ---------------------------------------------------------------------------
// 3d) main chunk GEMM: y = [sc*Toep | Vout] x [u' ; x] + T1sh, gelu -> Ybt
// ---------------------------------------------------------------------------
__global__ __launch_bounds__(256) void mainscan_kernel(
    const __hip_bfloat16* __restrict__ Ub, const __hip_bfloat16* __restrict__ X,
    const __hip_bfloat16* __restrict__ Abig, const float* __restrict__ T1sh,
    __hip_bfloat16* __restrict__ Ybt) {
    int cb = blockIdx.x, d = blockIdx.y;
    int tid = threadIdx.x, wave = tid >> 6, lane = tid & 63;
    int lm = lane & 15, quad = lane >> 4;
    const __hip_bfloat16* Ad = Abig + (size_t)d * TCH * 256;

    __shared__ short Bs[16384];  // 8 sections x 64 cols x 32 shorts = 32 KB

    #pragma unroll
    for (int it = 0; it < 8; ++it) {
        int idx = it * 256 + tid;
        int kk = idx >> 8;
        int colloc = (idx >> 2) & 63;
        int part = idx & 3;
        int col = cb * 64 + colloc;
        int colc = col < COLS ? col : COLS - 1;
        int bh = (colc * 241) >> 12;
        int c = colc - bh * 17;
        const __hip_bfloat16* src;
        if (kk < 4)
            src = Ub + ((size_t)bh * DM + d) * LTR + (size_t)c * TCH + kk * 32 + part * 8;
        else
            src = X + ((size_t)d * COLS + colc) * TCH + (kk - 4) * 32 + part * 8;
        glds16(src, (char*)Bs + idx * 16);
    }
    asm volatile("s_waitcnt vmcnt(0)" ::: "memory");
    __syncthreads();

    floatx4 acc[2][4];
    floatx4 zf = {0.f, 0.f, 0.f, 0.f};
    #pragma unroll
    for (int mi = 0; mi < 2; ++mi)
        #pragma unroll
        for (int nt = 0; nt < 4; ++nt) acc[mi][nt] = zf;

    #pragma unroll
    for (int kk = 0; kk < 8; ++kk) {
        short8 a0 = *(const short8*)(Ad + (size_t)(wave * 32 + lm) * 256 + kk * 32 + quad * 8);
        short8 a1 = *(const short8*)(Ad + (size_t)(wave * 32 + 16 + lm) * 256 + kk * 32 + quad * 8);
        #pragma unroll
        for (int nt = 0; nt < 4; ++nt) {
            short8 bv = *(const short8*)(Bs + kk * 2048 + (nt * 16 + lm) * 32 + quad * 8);
            acc[0][nt] = __builtin_amdgcn_mfma_f32_16x16x32_bf16(a0, bv, acc[0][nt], 0, 0, 0);
            acc[1][nt] = __builtin_amdgcn_mfma_f32_16x16x32_bf16(a1, bv, acc[1][nt], 0, 0, 0);
        }
    }

    #pragma unroll
    for (int mi = 0; mi < 2; ++mi) {
        int row0 = wave * 32 + mi * 16 + quad * 4;
        float4 t1 = *(const float4*)(T1sh + (size_t)d * 128 + row0);
        #pragma unroll
        for (int nt = 0; nt < 4; ++nt) {
            int col = cb * 64 + nt * 16 + lm;
            if (col >= COLS) continue;
            int bh = (col * 241) >> 12;
            int c = col - bh * 17;
            int l0 = c * TCH + row0;
            float g0 = gelu_tanh(acc[mi][nt][0] + t1.x);
            float g1 = gelu_tanh(acc[mi][nt][1] + t1.y);
            float g2 = gelu_tanh(acc[mi][nt][2] + t1.z);
            float g3 = gelu_tanh(acc[mi][nt][3] + t1.w);
            __hip_bfloat16* dst = Ybt + ((size_t)bh * DM + d) * LTR + l0;
            if (l0 + 3 < LT) {
                short4v o;
                o[0] = bfs(g0); o[1] = bfs(g1); o[2] = bfs(g2); o[3] = bfs(g3);
                *(short4v*)dst = o;
            } else {
                if (l0 + 0 < LT) dst[0] = __float2bfloat16(g0);
                if (l0 + 1 < LT) dst[1] = __float2bfloat16(g1);
                if (l0 + 2 < LT) dst[2] = __float2bfloat16(g2);
                if (l0 + 3 < LT) dst[3] = __float2bfloat16(g3);
            }
        }
    }
}

// ---------------------------------------------------------------------------
// 3e) transpose Ybt[b][d][l] -> Yb[b][l][d]
// ---------------------------------------------------------------------------
__global__ __launch_bounds__(256) void transpose_kernel(
    const __hip_bfloat16* __restrict__ Ybt, __hip_bfloat16* __restrict__ Yb) {
    int lt = blockIdx.x, dti = blockIdx.y, b = blockIdx.z;
    int t = threadIdx.x;
    __shared__ short tileT[64 * 66];   // [l][d], stride 66
    int l0 = lt * 64, d0 = dti * 64;
    #pragma unroll
    for (int r = 0; r < 2; ++r) {
        int idx = r * 256 + t;
        int dd = idx >> 3, lseg = idx & 7;
        short8 v = *(const short8*)(Ybt + ((size_t)b * DM + d0 + dd) * LTR + l0 + lseg * 8);
        #pragma unroll
        for (int i = 0; i < 8; ++i)
            tileT[(lseg * 8 + i) * 66 + dd] = v[i];
    }
    __syncthreads();
    #pragma unroll
    for (int r = 0; r < 2; ++r) {
        int idx = r * 256 + t;
        int ll = idx >> 3, dseg = idx & 7;
        short8 v;
        #pragma unroll
        for (int i = 0; i < 8; ++i)
            v[i] = tileT[ll * 66 + dseg * 8 + i];
        *(short8*)(Yb + ((size_t)b * LTR + l0 + ll) * DM + d0 + dseg * 8) = v;
    }
}

// ---------------------------------------------------------------------------
// 4) LDS-staged MFMA GEMM + GLU + residual (normalize-on-read) + BN stats +
//    next-layer Ub' bf16 write.  BK=64.
// ---------------------------------------------------------------------------
__global__ __launch_bounds__(256) void gemm_glu_mfma_kernel(
    const __hip_bfloat16* __restrict__ Yb, float* __restrict__ U,
    __hip_bfloat16* __restrict__ Ub,
    const __hip_bfloat16* __restrict__ Wtp, const float* __restrict__ out_b,
    const float* __restrict__ scsh, float* __restrict__ stats, int layer) {
    int bx = blockIdx.x, by = blockIdx.y, b = blockIdx.z;
    int tid = threadIdx.x;
    int wave = tid >> 6, lane = tid & 63;
    int lm = lane & 15, quad = lane >> 4;
    int l0 = bx * 128;

    __shared__ short lds[16384];          // A: [0,8192) shorts, B: [8192,16384)
    short* Asb = lds;
    short* Bsb = lds + 8192;

    const __hip_bfloat16* Yb_b = Yb + (size_t)b * LTR * DM;
    const __hip_bfloat16* Wl = Wtp + (size_t)layer * 512 * 256 + (size_t)by * 128 * 256;

    floatx4 acc[4][4];
    floatx4 zf = {0.f, 0.f, 0.f, 0.f};
    #pragma unroll
    for (int mi = 0; mi < 4; ++mi)
        #pragma unroll
        for (int ni = 0; ni < 4; ++ni) acc[mi][ni] = zf;

    int rowS[4], qS[4];
    #pragma unroll
    for (int i = 0; i < 4; ++i) {
        int idx = i * 256 + tid;
        rowS[i] = idx >> 3;
        qS[i] = ((idx & 7) - rowS[i]) & 7;
    }
    int aoff[2][4], boff[2][4];
    #pragma unroll
    for (int kh = 0; kh < 2; ++kh) {
        #pragma unroll
        for (int mi = 0; mi < 4; ++mi) {
            int r = (wave >> 1) * 64 + mi * 16 + lm;
            aoff[kh][mi] = r * 64 + ((kh * 4 + quad + r) & 7) * 8;
        }
        #pragma unroll
        for (int ni = 0; ni < 4; ++ni) {
            int r = (wave & 1) * 64 + ni * 16 + lm;
            boff[kh][ni] = r * 64 + ((kh * 4 + quad + r) & 7) * 8;
        }
    }

    for (int ks = 0; ks < 4; ++ks) {
        int k0 = ks * 64;
        __syncthreads();
        #pragma unroll
        for (int i = 0; i < 4; ++i) {
            const __hip_bfloat16* ga = Yb_b + (size_t)(l0 + rowS[i]) * DM + k0 + qS[i] * 8;
            glds16(ga, (char*)Asb + i * 4096 + wave * 1024 + (lane & 63) * 16);
            const __hip_bfloat16* gb = Wl + (size_t)rowS[i] * 256 + k0 + qS[i] * 8;
            glds16(gb, (char*)Bsb + i * 4096 + wave * 1024 + (lane & 63) * 16);
        }
        asm volatile("s_waitcnt vmcnt(0)" ::: "memory");
        __syncthreads();

        #pragma unroll
        for (int kh = 0; kh < 2; ++kh) {
            short8 af[4], bf4[4];
            #pragma unroll
            for (int mi = 0; mi < 4; ++mi) af[mi] = *(const short8*)(Asb + aoff[kh][mi]);
            #pragma unroll
            for (int ni = 0; ni < 4; ++ni) bf4[ni] = *(const short8*)(Bsb + boff[kh][ni]);
            #pragma unroll
            for (int mi = 0; mi < 4; ++mi)
                #pragma unroll
                for (int ni = 0; ni < 4; ++ni)
                    acc[mi][ni] = __builtin_amdgcn_mfma_f32_16x16x32_bf16(
                        af[mi], bf4[ni], acc[mi][ni], 0, 0, 0);
        }
    }

    const float* bl = out_b + layer * 512;
    int Pbase = by * 64 + (wave & 1) * 32;
    int lw = l0 + (wave >> 1) * 64;
    #pragma unroll
    for (int ni = 0; ni < 2; ++ni) {
        int P = Pbase + ni * 16 + lm;
        float bz1 = bl[P], bz2 = bl[256 + P];
        float scP = scsh[P], shP = scsh[DM + P];
        float* urow = U + ((size_t)b * DM + P) * LTP;
        __hip_bfloat16* ubrow = Ub + ((size_t)b * DM + P) * LTR;
        float sp = 0.f, sq = 0.f;
        #pragma unroll
        for (int mi = 0; mi < 4; ++mi) {
            int l0q = lw + mi * 16 + quad * 4;
            if (l0q >= LT) continue;
            floatx4 z1 = acc[mi][ni];
            floatx4 z2 = acc[mi][ni + 2];
            if (l0q + 4 <= LT) {
                float4 uv = *(const float4*)(urow + l0q);
                float h0 = fmaf(scP, uv.x, shP) + (z1[0] + bz1) * sigmoidf_(z2[0] + bz2);
                float h1 = fmaf(scP, uv.y, shP) + (z1[1] + bz1) * sigmoidf_(z2[1] + bz2);
                float h2 = fmaf(scP, uv.z, shP) + (z1[2] + bz1) * sigmoidf_(z2[2] + bz2);
                float h3 = fmaf(scP, uv.w, shP) + (z1[3] + bz1) * sigmoidf_(z2[3] + bz2);
                *(float4*)(urow + l0q) = make_float4(h0, h1, h2, h3);
                short4v ov;
                ov[0] = bfs(h0); ov[1] = bfs(h1); ov[2] = bfs(h2); ov[3] = bfs(h3);
                *(short4v*)(ubrow + l0q) = ov;
                sp += (h0 + h1) + (h2 + h3);
                sq += (h0 * h0 + h1 * h1) + (h2 * h2 + h3 * h3);
            } else {
                #pragma unroll
                for (int r = 0; r < 4; ++r) {
                    int l = l0q + r;
                    if (l < LT) {
                        float uvv = urow[l];
                        float hh = fmaf(scP, uvv, shP) + (z1[r] + bz1) * sigmoidf_(z2[r] + bz2);
                        urow[l] = hh;
                        ubrow[l] = __float2bfloat16(hh);
                        sp += hh; sq += hh * hh;
                    }
                }
            }
        }
        sp += __shfl_xor(sp, 16); sp += __shfl_xor(sp, 32);
        sq += __shfl_xor(sq, 16); sq += __shfl_xor(sq, 32);
        if (quad == 0) {
            atomicAdd(&stats[P], sp);
            atomicAdd(&stats[DM + P], sq);
        }
    }
}

// ---------------------------------------------------------------------------
// 5) stats -> (sc, sh) for the next layer's consumers
// ---------------------------------------------------------------------------
__global__ __launch_bounds__(256) void statsfin_kernel(
    const float* __restrict__ stats,
    const float* __restrict__ gamma, const float* __restrict__ beta,
    float* __restrict__ scsh, int layer) {
    int d = threadIdx.x;
    float s = stats[d], q = stats[DM + d];
    float mean = s * (1.0f / NTOT);
    float var  = q * (1.0f / NTOT) - mean * mean;
    float sc = rsqrtf(var + 1e-5f) * gamma[layer * DM + d];
    scsh[d] = sc;
    scsh[DM + d] = beta[layer * DM + d] - mean * sc;
}

// ---------------------------------------------------------------------------
// 6) head (applies final normalization on read)
// ---------------------------------------------------------------------------
__global__ __launch_bounds__(128) void head_kernel(
    const float* __restrict__ U, const float* __restrict__ scsh,
    const float* __restrict__ W1, const float* __restrict__ b1,
    const float* __restrict__ W2, const float* __restrict__ b2,
    float* __restrict__ out) {
    int hh = blockIdx.x;
    int b  = blockIdx.y;
    int j  = threadIdx.x;
    int l  = (L_ - 1) + hh;
    const float* urow = U + ((size_t)b * DM) * LTP + l;
    float a = b1[j];
    for (int k = 0; k < DM; ++k) {
        float hn = fmaf(scsh[k], urow[(size_t)k * LTP], scsh[DM + k]);
        a = fmaf(hn, W1[k * 128 + j], a);
    }
    float hs = a * sigmoidf_(a);
    float v = hs * W2[j];
    v += __shfl_xor(v, 1);
    v += __shfl_xor(v, 2);
    v += __shfl_xor(v, 4);
    v += __shfl_xor(v, 8);
    v += __shfl_xor(v, 16);
    v += __shfl_xor(v, 32);
    __shared__ float partial[2];
    if ((j & 63) == 0) partial[j >> 6] = v;
    __syncthreads();
    if (j == 0) out[b * H_ + hh] = partial[0] + partial[1] + b2[0];
}

// ---------------------------------------------------------------------------
extern "C" void kernel_launch(void* const* d_in, const int* in_sizes, int n_in,
                              void* d_out, int out_size, void* d_ws, size_t ws_size,
                              hipStream_t stream) {
    (void)in_sizes; (void)n_in; (void)out_size; (void)ws_size;
    const float* x_past      = (const float*)d_in[0];
    const float* noisy       = (const float*)d_in[1];
    const float* t_in        = (const float*)d_in[2];
    const float* x_future    = (const float*)d_in[3];
    const float* static_attr = (const float*)d_in[4];
    const float* freqs       = (const float*)d_in[5];
    const float* phases      = (const float*)d_in[6];
    const float* in_W        = (const float*)d_in[7];
    const float* in_b        = (const float*)d_in[8];
    const float* tm_W1       = (const float*)d_in[9];
    const float* tm_b1       = (const float*)d_in[10];
    const float* tm_W2       = (const float*)d_in[11];
    const float* tm_b2       = (const float*)d_in[12];
    const float* log_dt      = (const float*)d_in[13];
    const float* A_re        = (const float*)d_in[14];
    const float* A_im        = (const float*)d_in[15];
    const float* C_re        = (const float*)d_in[16];
    const float* C_im        = (const float*)d_in[17];
    const float* Dp          = (const float*)d_in[18];
    const float* out_W       = (const float*)d_in[19];
    const float* out_b       = (const float*)d_in[20];
    const float* bn_gamma    = (const float*)d_in[21];
    const float* bn_beta     = (const float*)d_in[22];
    const float* head_W1     = (const float*)d_in[23];
    const float* head_b1     = (const float*)d_in[24];
    const float* head_W2     = (const float*)d_in[25];
    const float* head_b2     = (const float*)d_in[26];

    char* ws = (char*)d_ws;
    const size_t U_OFF  = 1u << 20;
    const size_t U_BYT  = (size_t)B_ * DM * LTP * 4;
    const size_t UB_OFF = U_OFF + U_BYT;
    const size_t UB_BYT = (size_t)B_ * DM * LTR * 2;
    const size_t R1_OFF = UB_OFF + UB_BYT;
    const size_t RB     = (size_t)256 * COLS * TCH * 2;
    const size_t R2_OFF = R1_OFF + RB;
    const size_t AB_OFF = R2_OFF + RB;
    const size_t AB_BYT = (size_t)256 * TCH * 256 * 2;
    const size_t SA_OFF = AB_OFF + AB_BYT;
    const size_t SA_BYT = (size_t)256 * TCH * TCH * 2;
    const size_t WT_OFF = SA_OFF + SA_BYT;

    float*          tb    = (float*)(ws);
    float*          stats = (float*)(ws + (64 << 10));
    float*          scsh  = (float*)(ws + (96 << 10));
    float*          Rsh   = (float*)(ws + (128 << 10));   // 128 KB
    float*          T1sh  = (float*)(ws + (256 << 10));   // 128 KB
    float*          U     = (float*)(ws + U_OFF);
    __hip_bfloat16* Ub    = (__hip_bfloat16*)(ws + UB_OFF);
    __hip_bfloat16* R1    = (__hip_bfloat16*)(ws + R1_OFF);  // S/X, later Yb
    __hip_bfloat16* Ybt   = (__hip_bfloat16*)(ws + R2_OFF);
    __hip_bfloat16* Abig  = (__hip_bfloat16*)(ws + AB_OFF);
    __hip_bfloat16* SA    = (__hip_bfloat16*)(ws + SA_OFF);
    __hip_bfloat16* Wtp   = (__hip_bfloat16*)(ws + WT_OFF);

    time_mlp_kernel<<<dim3(B_), 256, 0, stream>>>(
        t_in, freqs, phases, tm_W1, tm_b1, tm_W2, tm_b2, tb);

    wt_prep_kernel<<<dim3(NL * 256), 256, 0, stream>>>(out_W, Wtp);

    initscsh_kernel<<<dim3(1), 256, 0, stream>>>(scsh);

    input_proj_kernel<<<dim3((LT + 255) / 256, B_), 256, 0, stream>>>(
        x_past, noisy, x_future, static_attr, in_W, in_b, tb, U, Ub);

    padzero_kernel<<<dim3(B_ * DM), 128, 0, stream>>>(Ub);

    for (int layer = 0; layer < NL; ++layer) {
        prep_kernel<<<dim3(256), 256, 0, stream>>>(
            log_dt, A_re, A_im, C_re, C_im, Dp, scsh, Abig, SA, Rsh, T1sh, layer);
        sgemm_kernel<<<dim3(9, 256), 256, 0, stream>>>(Ub, SA, Rsh, R1);
        carry_kernel<<<dim3(256, B_), 64, 0, stream>>>(
            R1, log_dt, A_re, A_im, layer);
        mainscan_kernel<<<dim3(9, 256), 256, 0, stream>>>(Ub, R1, Abig, T1sh, Ybt);
        transpose_kernel<<<dim3(LTR / 64, DM / 64, B_), 256, 0, stream>>>(Ybt, R1);
        hipMemsetAsync(stats, 0, 2 * DM * sizeof(float), stream);
        gemm_glu_mfma_kernel<<<dim3(17, 4, B_), 256, 0, stream>>>(
            R1, U, Ub, Wtp, out_b, scsh, stats, layer);
        statsfin_kernel<<<dim3(1), 256, 0, stream>>>(
            stats, bn_gamma, bn_beta, scsh, layer);
    }

    head_kernel<<<dim3(H_, B_), 128, 0, stream>>>(
        U, scsh, head_W1, head_b1, head_W2, head_b2, (float*)d_out);
}

// Round 10
// 944.411 us; speedup vs baseline: 4.2865x; 1.0872x over previous
//
#include <hip/hip_runtime.h>
#include <hip/hip_bf16.h>
#include <math.h>

#define B_   32
#define L_   2048
#define H_   8
#define DMET 16
#define SDIM 27
#define DM   256
#define NL   4
#define DS   64
#define TE   256
#define LT   2055          // L + H - 1
#define LTR  2176          // 17*128: padded l for Ub/Ybt/Yb
#define TCH  128           // chunk length
#define NC   17            // chunks per sequence
#define COLS 544           // B_ * NC
#define NTOT (B_ * LT)

typedef __attribute__((ext_vector_type(8))) short short8;
typedef __attribute__((ext_vector_type(4))) short short4v;
typedef __attribute__((ext_vector_type(4))) float floatx4;

__device__ __forceinline__ float sigmoidf_(float x) {
    return 1.0f / (1.0f + expf(-x));
}

__device__ __forceinline__ float gelu_tanh(float x) {
    const float c0 = 0.7978845608028654f; // sqrt(2/pi)
    float x3 = x * x * x;
    float t = tanhf(c0 * (x + 0.044715f * x3));
    return 0.5f * x * (1.0f + t);
}

__device__ __forceinline__ short bfs(float x) {
    __hip_bfloat16 h = __float2bfloat16(x);
    return *(short*)&h;
}

__device__ __forceinline__ float sbf(short s) {
    unsigned u = ((unsigned)(unsigned short)s) << 16;
    return __uint_as_float(u);
}

__device__ __forceinline__ void glds16(const void* g, void* l) {
    __builtin_amdgcn_global_load_lds(
        (const __attribute__((address_space(1))) unsigned*)g,
        (__attribute__((address_space(3))) unsigned*)l, 16, 0, 0);
}

// ---------------------------------------------------------------------------
// 1) time MLP
// ---------------------------------------------------------------------------
__global__ __launch_bounds__(256) void time_mlp_kernel(
    const float* __restrict__ t, const float* __restrict__ freqs,
    const float* __restrict__ phases,
    const float* __restrict__ W1, const float* __restrict__ b1,
    const float* __restrict__ W2, const float* __restrict__ b2,
    float* __restrict__ tb) {
    int b = blockIdx.x;
    int tid = threadIdx.x;
    __shared__ float f[TE];
    __shared__ float hid[2 * TE];
    float tv = t[b];
    f[tid] = cosf(fmaf(tv, freqs[tid], phases[tid])) * 1.4142135623730951f;
    __syncthreads();
    float a0 = b1[tid], a1 = b1[tid + TE];
    for (int k = 0; k < TE; ++k) {
        float fk = f[k];
        a0 = fmaf(fk, W1[k * 2 * TE + tid], a0);
        a1 = fmaf(fk, W1[k * 2 * TE + tid + TE], a1);
    }
    hid[tid]      = a0 * sigmoidf_(a0);
    hid[tid + TE] = a1 * sigmoidf_(a1);
    __syncthreads();
    float acc = b2[tid];
    for (int j = 0; j < 2 * TE; ++j)
        acc = fmaf(hid[j], W2[j * DM + tid], acc);
    tb[b * DM + tid] = acc;
}

// ---------------------------------------------------------------------------
// 1b) out_W [NL][256][512] fp32 -> Wtp bf16 [NL][512 permuted cols][256 k]
// ---------------------------------------------------------------------------
__global__ __launch_bounds__(256) void wt_prep_kernel(
    const float* __restrict__ out_W, __hip_bfloat16* __restrict__ Wtp) {
    int bid = blockIdx.x;
    int layer = bid >> 8, k = bid & 255;
    int e = threadIdx.x;
    const float* src = out_W + ((size_t)layer * 256 + k) * 512;
    #pragma unroll
    for (int q = 0; q < 2; ++q) {
        int ee = e + q * 256;
        int P = ee & 255, half = ee >> 8;
        int by = P >> 6, pp = P & 63;
        int g = pp >> 5;
        int tcol = (pp & 31) + half * 32;
        int c = by * 128 + g * 64 + tcol;
        Wtp[((size_t)layer * 512 + c) * 256 + k] = __float2bfloat16(src[ee]);
    }
}

// ---------------------------------------------------------------------------
// 2) input projection -> Ub[b][d][l] bf16 (residual stream lives here).
//    Also zeroes the l in [LT, LTR) pad.
// ---------------------------------------------------------------------------
__global__ __launch_bounds__(256) void input_proj_kernel(
    const float* __restrict__ xp, const float* __restrict__ nf,
    const float* __restrict__ xf, const float* __restrict__ sa,
    const float* __restrict__ inW, const float* __restrict__ inb,
    const float* __restrict__ tb, __hip_bfloat16* __restrict__ Ub) {
    int b  = blockIdx.y;
    int l0 = blockIdx.x * 256;
    int tx = threadIdx.x;
    int l  = l0 + tx;

    __shared__ float feats[256][18];
    __shared__ float Ws[17][DM];
    __shared__ float sdot[DM];
    __shared__ float tbs[DM];
    __shared__ float sstat[SDIM];

    if (tx < SDIM) sstat[tx] = sa[b * SDIM + tx];
    for (int k = 0; k < 17; ++k) Ws[k][tx] = inW[k * DM + tx];
    tbs[tx] = tb[b * DM + tx];

    bool valid = (l < LT);
    if (valid) {
        const float* src = (l < L_) ? &xp[((size_t)b * L_ + l) * DMET]
                                    : &xf[((size_t)b * (H_ - 1) + (l - L_)) * DMET];
        #pragma unroll
        for (int k = 0; k < DMET; ++k) feats[tx][k] = src[k];
        feats[tx][16] = (l >= L_ - 1) ? nf[b * H_ + (l - (L_ - 1))] : 0.0f;
    }
    __syncthreads();

    float sd = 0.0f;
    for (int k = 0; k < SDIM; ++k)
        sd = fmaf(sstat[k], inW[(17 + k) * DM + tx], sd);
    sdot[tx] = sd;
    __syncthreads();

    if (l >= LTR) return;
    size_t baseb = ((size_t)b * DM) * LTR + l;
    if (!valid) {   // pad region: zero all d
        __hip_bfloat16 z = __float2bfloat16(0.0f);
        for (int d = 0; d < DM; ++d) Ub[baseb + (size_t)d * LTR] = z;
        return;
    }
    bool cond = (l >= L_ - 1);
    for (int d = 0; d < DM; ++d) {
        float acc = inb[d] + sdot[d] + (cond ? tbs[d] : 0.0f);
        #pragma unroll
        for (int k = 0; k < 17; ++k)
            acc = fmaf(feats[tx][k], Ws[k][d], acc);
        Ub[baseb + (size_t)d * LTR] = __float2bfloat16(acc);
    }
}

// ---------------------------------------------------------------------------
// 3a) per-layer per-channel matrix prep with BN folding.  Also finalizes
//     (sc, sh) from the previous layer's stats and zeroes stats for reuse.
// ---------------------------------------------------------------------------
__global__ __launch_bounds__(256) void prep_kernel(
    const float* __restrict__ log_dt,
    const float* __restrict__ A_re, const float* __restrict__ A_im,
    const float* __restrict__ C_re, const float* __restrict__ C_im,
    const float* __restrict__ Dp,
    const float* __restrict__ gamma, const float* __restrict__ beta,
    float* __restrict__ stats, float* __restrict__ scsh,
    __hip_bfloat16* __restrict__ Abig, __hip_bfloat16* __restrict__ SA,
    float* __restrict__ Rsh, float* __restrict__ T1sh, int layer) {
    int d = blockIdx.x;
    int t = threadIdx.x;
    __shared__ float sAr[64], sAi[64], sCkr[64], sCki[64];
    __shared__ float kap[TCH];
    __shared__ float csum[TCH];
    __shared__ float s_sc, s_sh;

    if (t == 0) {
        float sc, sh;
        if (layer == 0) { sc = 1.0f; sh = 0.0f; }
        else {
            float s = stats[d], q = stats[DM + d];
            float mean = s * (1.0f / NTOT);
            float var  = q * (1.0f / NTOT) - mean * mean;
            sc = rsqrtf(var + 1e-5f) * gamma[(layer - 1) * DM + d];
            sh = beta[(layer - 1) * DM + d] - mean * sc;
        }
        s_sc = sc; s_sh = sh;
        scsh[d] = sc; scsh[DM + d] = sh;
        stats[d] = 0.0f; stats[DM + d] = 0.0f;   // ready for this layer's gemm
    }
    __syncthreads();
    float sc = s_sc, sh = s_sh;

    float dt = expf(log_dt[layer * DM + d]);
    float Dd = Dp[layer * DM + d];
    if (t < 64) {
        size_t ab = ((size_t)layer * DM + d) * DS + t;
        float Ar = A_re[ab], Ai = A_im[ab], Cr = C_re[ab], Ci = C_im[ab];
        float ar = dt * Ar, ai = dt * Ai;
        float e = expf(ar);
        float wre = e * cosf(ai), wim = e * sinf(ai);
        float mr = wre - 1.0f, mi = wim;
        float den = 1.0f / (Ar * Ar + Ai * Ai);
        float qr = (mr * Ar + mi * Ai) * den, qi = (mi * Ar - mr * Ai) * den;
        sCkr[t] = Cr * qr - Ci * qi;
        sCki[t] = Cr * qi + Ci * qr;
        sAr[t] = ar;
        sAi[t] = ai;
        // gsum = sum_{p=0}^{127} w^p = (w^128 - 1)/(w - 1), stable forms
        float s2 = sinf(0.5f * ai);
        float dr = fmaf(expm1f(ar), cosf(ai), -2.0f * s2 * s2);
        float di = e * sinf(ai);
        float a128 = 128.0f * ar, b128 = 128.0f * ai;
        float s2b = sinf(0.5f * b128);
        float nr = fmaf(expm1f(a128), cosf(b128), -2.0f * s2b * s2b);
        float ni = expf(a128) * sinf(b128);
        float dd2 = 1.0f / (dr * dr + di * di);
        float gr = (nr * dr + ni * di) * dd2;
        float gi = (ni * dr - nr * di) * dd2;
        Rsh[(size_t)d * 128 + t]      = sh * gr;
        Rsh[(size_t)d * 128 + 64 + t] = sh * gi;
    }
    __syncthreads();

    // kappa[delta] = 2 Re(sum_n Ck_n w^delta) ; kap[0] += D
    {
        int delta = t >> 1, half = t & 1;
        float fd = (float)delta;
        float p = 0.0f;
        #pragma unroll 8
        for (int n = half * 32; n < half * 32 + 32; ++n) {
            float er = expf(fd * sAr[n]);
            float ph = fd * sAi[n];
            p += er * (sCkr[n] * cosf(ph) - sCki[n] * sinf(ph));
        }
        p += __shfl_xor(p, 1);
        if (half == 0) kap[delta] = 2.0f * p + (delta == 0 ? Dd : 0.0f);
    }
    __syncthreads();

    // cumsum(kap) -> T1sh
    if (t < 128) csum[t] = kap[t];
    __syncthreads();
    for (int off = 1; off < 128; off <<= 1) {
        float v = 0.0f;
        if (t >= off && t < 128) v = csum[t - off];
        __syncthreads();
        if (t < 128) csum[t] += v;
        __syncthreads();
    }
    if (t < 128) T1sh[(size_t)d * 128 + t] = sh * csum[t];

    __hip_bfloat16* Ad = Abig + (size_t)d * TCH * 256;
    for (int idx = t; idx < TCH * TCH; idx += 256) {
        int i = idx >> 7, m = idx & 127;
        Ad[(size_t)i * 256 + m] = __float2bfloat16(m <= i ? sc * kap[i - m] : 0.0f);
    }
    // Vout[i][n] = Ck_n * w^{i+1}
    for (int idx = t; idx < TCH * 64; idx += 256) {
        int i = idx >> 6, n = idx & 63;
        float fp = (float)(i + 1);
        float er = expf(fp * sAr[n]);
        float ph = fp * sAi[n];
        float c = cosf(ph), s = sinf(ph);
        float vr = er * (sCkr[n] * c - sCki[n] * s);
        float vi = er * (sCkr[n] * s + sCki[n] * c);
        Ad[(size_t)i * 256 + 128 + n] = __float2bfloat16(2.0f * vr);
        Ad[(size_t)i * 256 + 192 + n] = __float2bfloat16(-2.0f * vi);
    }
    // Vin scaled by sc
    __hip_bfloat16* Sd = SA + (size_t)d * TCH * TCH;
    for (int idx = t; idx < 64 * TCH; idx += 256) {
        int n = idx >> 7, m = idx & 127;
        float fp = (float)(127 - m);
        float er = sc * expf(fp * sAr[n]);
        float ph = fp * sAi[n];
        Sd[(size_t)n * 128 + m]        = __float2bfloat16(er * cosf(ph));
        Sd[(size_t)(64 + n) * 128 + m] = __float2bfloat16(er * sinf(ph));
    }
}

// ---------------------------------------------------------------------------
// 3b) S-GEMM: S[d][col][k 128] = (sc*Vin_d) x u' + Rsh
// ---------------------------------------------------------------------------
__global__ __launch_bounds__(256) void sgemm_kernel(
    const __hip_bfloat16* __restrict__ Ub, const __hip_bfloat16* __restrict__ SA,
    const float* __restrict__ Rsh, __hip_bfloat16* __restrict__ S) {
    int cb = blockIdx.x, d = blockIdx.y;
    int tid = threadIdx.x, wave = tid >> 6, lane = tid & 63;
    int lm = lane & 15, quad = lane >> 4;
    const __hip_bfloat16* SAd = SA + (size_t)d * TCH * TCH;

    __shared__ short Bs[8192];

    #pragma unroll
    for (int it = 0; it < 4; ++it) {
        int idx = it * 256 + tid;
        int kk = idx >> 8;
        int colloc = (idx >> 2) & 63;
        int part = idx & 3;
        int col = cb * 64 + colloc;
        int colc = col < COLS ? col : COLS - 1;
        int bh = (colc * 241) >> 12;
        int c = colc - bh * 17;
        const __hip_bfloat16* src =
            Ub + ((size_t)bh * DM + d) * LTR + (size_t)c * TCH + kk * 32 + part * 8;
        glds16(src, (char*)Bs + idx * 16);
    }
    asm volatile("s_waitcnt vmcnt(0)" ::: "memory");
    __syncthreads();

    floatx4 acc[2][4];
    floatx4 zf = {0.f, 0.f, 0.f, 0.f};
    #pragma unroll
    for (int mi = 0; mi < 2; ++mi)
        #pragma unroll
        for (int nt = 0; nt < 4; ++nt) acc[mi][nt] = zf;

    #pragma unroll
    for (int kk = 0; kk < 4; ++kk) {
        short8 a0 = *(const short8*)(SAd + (size_t)(wave * 32 + lm) * TCH + kk * 32 + quad * 8);
        short8 a1 = *(const short8*)(SAd + (size_t)(wave * 32 + 16 + lm) * TCH + kk * 32 + quad * 8);
        #pragma unroll
        for (int nt = 0; nt < 4; ++nt) {
            short8 bv = *(const short8*)(Bs + kk * 2048 + (nt * 16 + lm) * 32 + quad * 8);
            acc[0][nt] = __builtin_amdgcn_mfma_f32_16x16x32_bf16(a0, bv, acc[0][nt], 0, 0, 0);
            acc[1][nt] = __builtin_amdgcn_mfma_f32_16x16x32_bf16(a1, bv, acc[1][nt], 0, 0, 0);
        }
    }
    #pragma unroll
    for (int mi = 0; mi < 2; ++mi) {
        int row = wave * 32 + mi * 16 + quad * 4;
        float4 rs = *(const float4*)(Rsh + (size_t)d * 128 + row);
        #pragma unroll
        for (int nt = 0; nt < 4; ++nt) {
            int col = cb * 64 + nt * 16 + lm;
            if (col >= COLS) continue;
            short4v o;
            o[0] = bfs(acc[mi][nt][0] + rs.x); o[1] = bfs(acc[mi][nt][1] + rs.y);
            o[2] = bfs(acc[mi][nt][2] + rs.z); o[3] = bfs(acc[mi][nt][3] + rs.w);
            *(short4v*)(S + ((size_t)d * COLS + col) * TCH + row) = o;
        }
    }
}

// ---------------------------------------------------------------------------
// 3c) carry scan over chunks (in place)
// ---------------------------------------------------------------------------
__global__ __launch_bounds__(64) void carry_kernel(
    __hip_bfloat16* __restrict__ SX,
    const float* __restrict__ log_dt,
    const float* __restrict__ A_re, const float* __restrict__ A_im,
    int layer) {
    int d = blockIdx.x, b = blockIdx.y;
    int n = threadIdx.x;
    float dt = expf(log_dt[layer * DM + d]);
    size_t ab = ((size_t)layer * DM + d) * DS + n;
    float Ar = A_re[ab], Ai = A_im[ab];
    float e = expf(dt * Ar);
    float wre = e * cosf(dt * Ai), wim = e * sinf(dt * Ai);
    #pragma unroll
    for (int t = 0; t < 7; ++t) {
        float r = wre * wre - wim * wim;
        wim = 2.0f * wre * wim; wre = r;
    }
    float xr = 0.0f, xi = 0.0f;
    for (int c = 0; c < NC; ++c) {
        size_t addr = ((size_t)d * COLS + b * NC + c) * TCH;
        float sre = __bfloat162float(SX[addr + n]);
        float sim = __bfloat162float(SX[addr + 64 + n]);
        SX[addr + n]      = __float2bfloat16(xr);
        SX[addr + 64 + n] = __float2bfloat16(xi);
        float nr = wre * xr - wim * xi + sre;
        xi = wre * xi + wim * xr + sim;
        xr = nr;
    }
}

// ---------------------------------------------------------------------------
// 3d) main chunk GEMM: y = [sc*Toep | Vout] x [u' ; x] + T1sh, gelu -> Ybt
// ---------------------------------------------------------------------------
__global__ __launch_bounds__(256) void mainscan_kernel(
    const __hip_bfloat16* __restrict__ Ub, const __hip_bfloat16* __restrict__ X,
    const __hip_bfloat16* __restrict__ Abig, const float* __restrict__ T1sh,
    __hip_bfloat16* __restrict__ Ybt) {
    int cb = blockIdx.x, d = blockIdx.y;
    int tid = threadIdx.x, wave = tid >> 6, lane = tid & 63;
    int lm = lane & 15, quad = lane >> 4;
    const __hip_bfloat16* Ad = Abig + (size_t)d * TCH * 256;

    __shared__ short Bs[16384];

    #pragma unroll
    for (int it = 0; it < 8; ++it) {
        int idx = it * 256 + tid;
        int kk = idx >> 8;
        int colloc = (idx >> 2) & 63;
        int part = idx & 3;
        int col = cb * 64 + colloc;
        int colc = col < COLS ? col : COLS - 1;
        int bh = (colc * 241) >> 12;
        int c = colc - bh * 17;
        const __hip_bfloat16* src;
        if (kk < 4)
            src = Ub + ((size_t)bh * DM + d) * LTR + (size_t)c * TCH + kk * 32 + part * 8;
        else
            src = X + ((size_t)d * COLS + colc) * TCH + (kk - 4) * 32 + part * 8;
        glds16(src, (char*)Bs + idx * 16);
    }
    asm volatile("s_waitcnt vmcnt(0)" ::: "memory");
    __syncthreads();

    floatx4 acc[2][4];
    floatx4 zf = {0.f, 0.f, 0.f, 0.f};
    #pragma unroll
    for (int mi = 0; mi < 2; ++mi)
        #pragma unroll
        for (int nt = 0; nt < 4; ++nt) acc[mi][nt] = zf;

    #pragma unroll
    for (int kk = 0; kk < 8; ++kk) {
        short8 a0 = *(const short8*)(Ad + (size_t)(wave * 32 + lm) * 256 + kk * 32 + quad * 8);
        short8 a1 = *(const short8*)(Ad + (size_t)(wave * 32 + 16 + lm) * 256 + kk * 32 + quad * 8);
        #pragma unroll
        for (int nt = 0; nt < 4; ++nt) {
            short8 bv = *(const short8*)(Bs + kk * 2048 + (nt * 16 + lm) * 32 + quad * 8);
            acc[0][nt] = __builtin_amdgcn_mfma_f32_16x16x32_bf16(a0, bv, acc[0][nt], 0, 0, 0);
            acc[1][nt] = __builtin_amdgcn_mfma_f32_16x16x32_bf16(a1, bv, acc[1][nt], 0, 0, 0);
        }
    }

    #pragma unroll
    for (int mi = 0; mi < 2; ++mi) {
        int row0 = wave * 32 + mi * 16 + quad * 4;
        float4 t1 = *(const float4*)(T1sh + (size_t)d * 128 + row0);
        #pragma unroll
        for (int nt = 0; nt < 4; ++nt) {
            int col = cb * 64 + nt * 16 + lm;
            if (col >= COLS) continue;
            int bh = (col * 241) >> 12;
            int c = col - bh * 17;
            int l0 = c * TCH + row0;
            float g0 = gelu_tanh(acc[mi][nt][0] + t1.x);
            float g1 = gelu_tanh(acc[mi][nt][1] + t1.y);
            float g2 = gelu_tanh(acc[mi][nt][2] + t1.z);
            float g3 = gelu_tanh(acc[mi][nt][3] + t1.w);
            __hip_bfloat16* dst = Ybt + ((size_t)bh * DM + d) * LTR + l0;
            if (l0 + 3 < LT) {
                short4v o;
                o[0] = bfs(g0); o[1] = bfs(g1); o[2] = bfs(g2); o[3] = bfs(g3);
                *(short4v*)dst = o;
            } else {
                if (l0 + 0 < LT) dst[0] = __float2bfloat16(g0);
                if (l0 + 1 < LT) dst[1] = __float2bfloat16(g1);
                if (l0 + 2 < LT) dst[2] = __float2bfloat16(g2);
                if (l0 + 3 < LT) dst[3] = __float2bfloat16(g3);
            }
        }
    }
}

// ---------------------------------------------------------------------------
// 3e) transpose Ybt[b][d][l] -> Yb[b][l][d]
// ---------------------------------------------------------------------------
__global__ __launch_bounds__(256) void transpose_kernel(
    const __hip_bfloat16* __restrict__ Ybt, __hip_bfloat16* __restrict__ Yb) {
    int lt = blockIdx.x, dti = blockIdx.y, b = blockIdx.z;
    int t = threadIdx.x;
    __shared__ short tileT[64 * 66];   // [l][d], stride 66
    int l0 = lt * 64, d0 = dti * 64;
    #pragma unroll
    for (int r = 0; r < 2; ++r) {
        int idx = r * 256 + t;
        int dd = idx >> 3, lseg = idx & 7;
        short8 v = *(const short8*)(Ybt + ((size_t)b * DM + d0 + dd) * LTR + l0 + lseg * 8);
        #pragma unroll
        for (int i = 0; i < 8; ++i)
            tileT[(lseg * 8 + i) * 66 + dd] = v[i];
    }
    __syncthreads();
    #pragma unroll
    for (int r = 0; r < 2; ++r) {
        int idx = r * 256 + t;
        int ll = idx >> 3, dseg = idx & 7;
        short8 v;
        #pragma unroll
        for (int i = 0; i < 8; ++i)
            v[i] = tileT[ll * 66 + dseg * 8 + i];
        *(short8*)(Yb + ((size_t)b * LTR + l0 + ll) * DM + d0 + dseg * 8) = v;
    }
}

// ---------------------------------------------------------------------------
// 4) LDS-staged MFMA GEMM + GLU + residual (bf16 Ub, normalize-on-read,
//    in-place) + BN stats.  BK=64.
// ---------------------------------------------------------------------------
__global__ __launch_bounds__(256) void gemm_glu_mfma_kernel(
    const __hip_bfloat16* __restrict__ Yb, __hip_bfloat16* __restrict__ Ub,
    const __hip_bfloat16* __restrict__ Wtp, const float* __restrict__ out_b,
    const float* __restrict__ scsh, float* __restrict__ stats, int layer) {
    int bx = blockIdx.x, by = blockIdx.y, b = blockIdx.z;
    int tid = threadIdx.x;
    int wave = tid >> 6, lane = tid & 63;
    int lm = lane & 15, quad = lane >> 4;
    int l0 = bx * 128;

    __shared__ short lds[16384];
    short* Asb = lds;
    short* Bsb = lds + 8192;

    const __hip_bfloat16* Yb_b = Yb + (size_t)b * LTR * DM;
    const __hip_bfloat16* Wl = Wtp + (size_t)layer * 512 * 256 + (size_t)by * 128 * 256;

    floatx4 acc[4][4];
    floatx4 zf = {0.f, 0.f, 0.f, 0.f};
    #pragma unroll
    for (int mi = 0; mi < 4; ++mi)
        #pragma unroll
        for (int ni = 0; ni < 4; ++ni) acc[mi][ni] = zf;

    int rowS[4], qS[4];
    #pragma unroll
    for (int i = 0; i < 4; ++i) {
        int idx = i * 256 + tid;
        rowS[i] = idx >> 3;
        qS[i] = ((idx & 7) - rowS[i]) & 7;
    }
    int aoff[2][4], boff[2][4];
    #pragma unroll
    for (int kh = 0; kh < 2; ++kh) {
        #pragma unroll
        for (int mi = 0; mi < 4; ++mi) {
            int r = (wave >> 1) * 64 + mi * 16 + lm;
            aoff[kh][mi] = r * 64 + ((kh * 4 + quad + r) & 7) * 8;
        }
        #pragma unroll
        for (int ni = 0; ni < 4; ++ni) {
            int r = (wave & 1) * 64 + ni * 16 + lm;
            boff[kh][ni] = r * 64 + ((kh * 4 + quad + r) & 7) * 8;
        }
    }

    for (int ks = 0; ks < 4; ++ks) {
        int k0 = ks * 64;
        __syncthreads();
        #pragma unroll
        for (int i = 0; i < 4; ++i) {
            const __hip_bfloat16* ga = Yb_b + (size_t)(l0 + rowS[i]) * DM + k0 + qS[i] * 8;
            glds16(ga, (char*)Asb + i * 4096 + wave * 1024 + (lane & 63) * 16);
            const __hip_bfloat16* gb = Wl + (size_t)rowS[i] * 256 + k0 + qS[i] * 8;
            glds16(gb, (char*)Bsb + i * 4096 + wave * 1024 + (lane & 63) * 16);
        }
        asm volatile("s_waitcnt vmcnt(0)" ::: "memory");
        __syncthreads();

        #pragma unroll
        for (int kh = 0; kh < 2; ++kh) {
            short8 af[4], bf4[4];
            #pragma unroll
            for (int mi = 0; mi < 4; ++mi) af[mi] = *(const short8*)(Asb + aoff[kh][mi]);
            #pragma unroll
            for (int ni = 0; ni < 4; ++ni) bf4[ni] = *(const short8*)(Bsb + boff[kh][ni]);
            #pragma unroll
            for (int mi = 0; mi < 4; ++mi)
                #pragma unroll
                for (int ni = 0; ni < 4; ++ni)
                    acc[mi][ni] = __builtin_amdgcn_mfma_f32_16x16x32_bf16(
                        af[mi], bf4[ni], acc[mi][ni], 0, 0, 0);
        }
    }

    const float* bl = out_b + layer * 512;
    int Pbase = by * 64 + (wave & 1) * 32;
    int lw = l0 + (wave >> 1) * 64;
    #pragma unroll
    for (int ni = 0; ni < 2; ++ni) {
        int P = Pbase + ni * 16 + lm;
        float bz1 = bl[P], bz2 = bl[256 + P];
        float scP = scsh[P], shP = scsh[DM + P];
        __hip_bfloat16* ubrow = Ub + ((size_t)b * DM + P) * LTR;
        float sp = 0.f, sq = 0.f;
        #pragma unroll
        for (int mi = 0; mi < 4; ++mi) {
            int l0q = lw + mi * 16 + quad * 4;
            if (l0q >= LT) continue;
            floatx4 z1 = acc[mi][ni];
            floatx4 z2 = acc[mi][ni + 2];
            if (l0q + 4 <= LT) {
                short4v uv = *(const short4v*)(ubrow + l0q);
                float h0 = fmaf(scP, sbf(uv[0]), shP) + (z1[0] + bz1) * sigmoidf_(z2[0] + bz2);
                float h1 = fmaf(scP, sbf(uv[1]), shP) + (z1[1] + bz1) * sigmoidf_(z2[1] + bz2);
                float h2 = fmaf(scP, sbf(uv[2]), shP) + (z1[2] + bz1) * sigmoidf_(z2[2] + bz2);
                float h3 = fmaf(scP, sbf(uv[3]), shP) + (z1[3] + bz1) * sigmoidf_(z2[3] + bz2);
                short4v ov;
                ov[0] = bfs(h0); ov[1] = bfs(h1); ov[2] = bfs(h2); ov[3] = bfs(h3);
                *(short4v*)(ubrow + l0q) = ov;
                sp += (h0 + h1) + (h2 + h3);
                sq += (h0 * h0 + h1 * h1) + (h2 * h2 + h3 * h3);
            } else {
                #pragma unroll
                for (int r = 0; r < 4; ++r) {
                    int l = l0q + r;
                    if (l < LT) {
                        float uvv = __bfloat162float(ubrow[l]);
                        float hh = fmaf(scP, uvv, shP) + (z1[r] + bz1) * sigmoidf_(z2[r] + bz2);
                        ubrow[l] = __float2bfloat16(hh);
                        sp += hh; sq += hh * hh;
                    }
                }
            }
        }
        sp += __shfl_xor(sp, 16); sp += __shfl_xor(sp, 32);
        sq += __shfl_xor(sq, 16); sq += __shfl_xor(sq, 32);
        if (quad == 0) {
            atomicAdd(&stats[P], sp);
            atomicAdd(&stats[DM + P], sq);
        }
    }
}

// ---------------------------------------------------------------------------
// 5) final stats -> (sc, sh) for head
// ---------------------------------------------------------------------------
__global__ __launch_bounds__(256) void statsfin_kernel(
    const float* __restrict__ stats,
    const float* __restrict__ gamma, const float* __restrict__ beta,
    float* __restrict__ scsh, int layer) {
    int d = threadIdx.x;
    float s = stats[d], q = stats[DM + d];
    float mean = s * (1.0f / NTOT);
    float var  = q * (1.0f / NTOT) - mean * mean;
    float sc = rsqrtf(var + 1e-5f) * gamma[layer * DM + d];
    scsh[d] = sc;
    scsh[DM + d] = beta[layer * DM + d] - mean * sc;
}

// ---------------------------------------------------------------------------
// 6) head (applies final normalization on read, from bf16 Ub)
// ---------------------------------------------------------------------------
__global__ __launch_bounds__(128) void head_kernel(
    const __hip_bfloat16* __restrict__ Ub, const float* __restrict__ scsh,
    const float* __restrict__ W1, const float* __restrict__ b1,
    const float* __restrict__ W2, const float* __restrict__ b2,
    float* __restrict__ out) {
    int hh = blockIdx.x;
    int b  = blockIdx.y;
    int j  = threadIdx.x;
    int l  = (L_ - 1) + hh;
    const __hip_bfloat16* urow = Ub + ((size_t)b * DM) * LTR + l;
    float a = b1[j];
    for (int k = 0; k < DM; ++k) {
        float hn = fmaf(scsh[k], __bfloat162float(urow[(size_t)k * LTR]), scsh[DM + k]);
        a = fmaf(hn, W1[k * 128 + j], a);
    }
    float hs = a * sigmoidf_(a);
    float v = hs * W2[j];
    v += __shfl_xor(v, 1);
    v += __shfl_xor(v, 2);
    v += __shfl_xor(v, 4);
    v += __shfl_xor(v, 8);
    v += __shfl_xor(v, 16);
    v += __shfl_xor(v, 32);
    __shared__ float partial[2];
    if ((j & 63) == 0) partial[j >> 6] = v;
    __syncthreads();
    if (j == 0) out[b * H_ + hh] = partial[0] + partial[1] + b2[0];
}

// ---------------------------------------------------------------------------
extern "C" void kernel_launch(void* const* d_in, const int* in_sizes, int n_in,
                              void* d_out, int out_size, void* d_ws, size_t ws_size,
                              hipStream_t stream) {
    (void)in_sizes; (void)n_in; (void)out_size; (void)ws_size;
    const float* x_past      = (const float*)d_in[0];
    const float* noisy       = (const float*)d_in[1];
    const float* t_in        = (const float*)d_in[2];
    const float* x_future    = (const float*)d_in[3];
    const float* static_attr = (const float*)d_in[4];
    const float* freqs       = (const float*)d_in[5];
    const float* phases      = (const float*)d_in[6];
    const float* in_W        = (const float*)d_in[7];
    const float* in_b        = (const float*)d_in[8];
    const float* tm_W1       = (const float*)d_in[9];
    const float* tm_b1       = (const float*)d_in[10];
    const float* tm_W2       = (const float*)d_in[11];
    const float* tm_b2       = (const float*)d_in[12];
    const float* log_dt      = (const float*)d_in[13];
    const float* A_re        = (const float*)d_in[14];
    const float* A_im        = (const float*)d_in[15];
    const float* C_re        = (const float*)d_in[16];
    const float* C_im        = (const float*)d_in[17];
    const float* Dp          = (const float*)d_in[18];
    const float* out_W       = (const float*)d_in[19];
    const float* out_b       = (const float*)d_in[20];
    const float* bn_gamma    = (const float*)d_in[21];
    const float* bn_beta     = (const float*)d_in[22];
    const float* head_W1     = (const float*)d_in[23];
    const float* head_b1     = (const float*)d_in[24];
    const float* head_W2     = (const float*)d_in[25];
    const float* head_b2     = (const float*)d_in[26];

    char* ws = (char*)d_ws;
    const size_t UB_OFF = 1u << 20;
    const size_t UB_BYT = (size_t)B_ * DM * LTR * 2;
    const size_t R1_OFF = UB_OFF + UB_BYT;
    const size_t RB     = (size_t)256 * COLS * TCH * 2;
    const size_t R2_OFF = R1_OFF + RB;
    const size_t AB_OFF = R2_OFF + RB;
    const size_t AB_BYT = (size_t)256 * TCH * 256 * 2;
    const size_t SA_OFF = AB_OFF + AB_BYT;
    const size_t SA_BYT = (size_t)256 * TCH * TCH * 2;
    const size_t WT_OFF = SA_OFF + SA_BYT;

    float*          tb    = (float*)(ws);
    float*          stats = (float*)(ws + (64 << 10));
    float*          scsh  = (float*)(ws + (96 << 10));
    float*          Rsh   = (float*)(ws + (128 << 10));
    float*          T1sh  = (float*)(ws + (256 << 10));
    __hip_bfloat16* Ub    = (__hip_bfloat16*)(ws + UB_OFF);
    __hip_bfloat16* R1    = (__hip_bfloat16*)(ws + R1_OFF);  // S/X, later Yb
    __hip_bfloat16* Ybt   = (__hip_bfloat16*)(ws + R2_OFF);
    __hip_bfloat16* Abig  = (__hip_bfloat16*)(ws + AB_OFF);
    __hip_bfloat16* SA    = (__hip_bfloat16*)(ws + SA_OFF);
    __hip_bfloat16* Wtp   = (__hip_bfloat16*)(ws + WT_OFF);

    time_mlp_kernel<<<dim3(B_), 256, 0, stream>>>(
        t_in, freqs, phases, tm_W1, tm_b1, tm_W2, tm_b2, tb);

    wt_prep_kernel<<<dim3(NL * 256), 256, 0, stream>>>(out_W, Wtp);

    input_proj_kernel<<<dim3(9, B_), 256, 0, stream>>>(
        x_past, noisy, x_future, static_attr, in_W, in_b, tb, Ub);

    for (int layer = 0; layer < NL; ++layer) {
        prep_kernel<<<dim3(256), 256, 0, stream>>>(
            log_dt, A_re, A_im, C_re, C_im, Dp, bn_gamma, bn_beta,
            stats, scsh, Abig, SA, Rsh, T1sh, layer);
        sgemm_kernel<<<dim3(9, 256), 256, 0, stream>>>(Ub, SA, Rsh, R1);
        carry_kernel<<<dim3(256, B_), 64, 0, stream>>>(
            R1, log_dt, A_re, A_im, layer);
        mainscan_kernel<<<dim3(9, 256), 256, 0, stream>>>(Ub, R1, Abig, T1sh, Ybt);
        transpose_kernel<<<dim3(LTR / 64, DM / 64, B_), 256, 0, stream>>>(Ybt, R1);
        gemm_glu_mfma_kernel<<<dim3(17, 4, B_), 256, 0, stream>>>(
            R1, Ub, Wtp, out_b, scsh, stats, layer);
    }

    statsfin_kernel<<<dim3(1), 256, 0, stream>>>(
        stats, bn_gamma, bn_beta, scsh, NL - 1);

    head_kernel<<<dim3(H_, B_), 128, 0, stream>>>(
        Ub, scsh, head_W1, head_b1, head_W2, head_b2, (float*)d_out);
}

// Round 11
// 923.350 us; speedup vs baseline: 4.3843x; 1.0228x over previous
//
#include <hip/hip_runtime.h>
#include <hip/hip_bf16.h>
#include <math.h>

#define B_   32
#define L_   2048
#define H_   8
#define DMET 16
#define SDIM 27
#define DM   256
#define NL   4
#define DS   64
#define TE   256
#define LT   2055          // L + H - 1
#define LTR  2176          // 17*128: padded l for Ub/Ybt/Yb
#define TCH  128           // chunk length
#define NC   17            // chunks per sequence
#define COLS 544           // B_ * NC
#define NTOT (B_ * LT)

typedef __attribute__((ext_vector_type(8))) short short8;
typedef __attribute__((ext_vector_type(4))) short short4v;
typedef __attribute__((ext_vector_type(4))) float floatx4;

__device__ __forceinline__ float sigmoidf_(float x) {
    return 1.0f / (1.0f + expf(-x));
}

__device__ __forceinline__ float gelu_tanh(float x) {
    const float c0 = 0.7978845608028654f; // sqrt(2/pi)
    float x3 = x * x * x;
    float t = tanhf(c0 * (x + 0.044715f * x3));
    return 0.5f * x * (1.0f + t);
}

__device__ __forceinline__ short bfs(float x) {
    __hip_bfloat16 h = __float2bfloat16(x);
    return *(short*)&h;
}

__device__ __forceinline__ float sbf(short s) {
    unsigned u = ((unsigned)(unsigned short)s) << 16;
    return __uint_as_float(u);
}

__device__ __forceinline__ void glds16(const void* g, void* l) {
    __builtin_amdgcn_global_load_lds(
        (const __attribute__((address_space(1))) unsigned*)g,
        (__attribute__((address_space(3))) unsigned*)l, 16, 0, 0);
}

// ---------------------------------------------------------------------------
// 1) time MLP
// ---------------------------------------------------------------------------
__global__ __launch_bounds__(256) void time_mlp_kernel(
    const float* __restrict__ t, const float* __restrict__ freqs,
    const float* __restrict__ phases,
    const float* __restrict__ W1, const float* __restrict__ b1,
    const float* __restrict__ W2, const float* __restrict__ b2,
    float* __restrict__ tb) {
    int b = blockIdx.x;
    int tid = threadIdx.x;
    __shared__ float f[TE];
    __shared__ float hid[2 * TE];
    float tv = t[b];
    f[tid] = cosf(fmaf(tv, freqs[tid], phases[tid])) * 1.4142135623730951f;
    __syncthreads();
    float a0 = b1[tid], a1 = b1[tid + TE];
    for (int k = 0; k < TE; ++k) {
        float fk = f[k];
        a0 = fmaf(fk, W1[k * 2 * TE + tid], a0);
        a1 = fmaf(fk, W1[k * 2 * TE + tid + TE], a1);
    }
    hid[tid]      = a0 * sigmoidf_(a0);
    hid[tid + TE] = a1 * sigmoidf_(a1);
    __syncthreads();
    float acc = b2[tid];
    for (int j = 0; j < 2 * TE; ++j)
        acc = fmaf(hid[j], W2[j * DM + tid], acc);
    tb[b * DM + tid] = acc;
}

// ---------------------------------------------------------------------------
// 1b) out_W [NL][256][512] fp32 -> Wtp bf16 [NL][512 permuted cols][256 k]
// ---------------------------------------------------------------------------
__global__ __launch_bounds__(256) void wt_prep_kernel(
    const float* __restrict__ out_W, __hip_bfloat16* __restrict__ Wtp) {
    int bid = blockIdx.x;
    int layer = bid >> 8, k = bid & 255;
    int e = threadIdx.x;
    const float* src = out_W + ((size_t)layer * 256 + k) * 512;
    #pragma unroll
    for (int q = 0; q < 2; ++q) {
        int ee = e + q * 256;
        int P = ee & 255, half = ee >> 8;
        int by = P >> 6, pp = P & 63;
        int g = pp >> 5;
        int tcol = (pp & 31) + half * 32;
        int c = by * 128 + g * 64 + tcol;
        Wtp[((size_t)layer * 512 + c) * 256 + k] = __float2bfloat16(src[ee]);
    }
}

// ---------------------------------------------------------------------------
// 2) input projection -> Ub[b][d][l] bf16, zeroes pad
// ---------------------------------------------------------------------------
__global__ __launch_bounds__(256) void input_proj_kernel(
    const float* __restrict__ xp, const float* __restrict__ nf,
    const float* __restrict__ xf, const float* __restrict__ sa,
    const float* __restrict__ inW, const float* __restrict__ inb,
    const float* __restrict__ tb, __hip_bfloat16* __restrict__ Ub) {
    int b  = blockIdx.y;
    int l0 = blockIdx.x * 256;
    int tx = threadIdx.x;
    int l  = l0 + tx;

    __shared__ float feats[256][18];
    __shared__ float Ws[17][DM];
    __shared__ float sdot[DM];
    __shared__ float tbs[DM];
    __shared__ float sstat[SDIM];

    if (tx < SDIM) sstat[tx] = sa[b * SDIM + tx];
    for (int k = 0; k < 17; ++k) Ws[k][tx] = inW[k * DM + tx];
    tbs[tx] = tb[b * DM + tx];

    bool valid = (l < LT);
    if (valid) {
        const float* src = (l < L_) ? &xp[((size_t)b * L_ + l) * DMET]
                                    : &xf[((size_t)b * (H_ - 1) + (l - L_)) * DMET];
        #pragma unroll
        for (int k = 0; k < DMET; ++k) feats[tx][k] = src[k];
        feats[tx][16] = (l >= L_ - 1) ? nf[b * H_ + (l - (L_ - 1))] : 0.0f;
    }
    __syncthreads();

    float sd = 0.0f;
    for (int k = 0; k < SDIM; ++k)
        sd = fmaf(sstat[k], inW[(17 + k) * DM + tx], sd);
    sdot[tx] = sd;
    __syncthreads();

    if (l >= LTR) return;
    size_t baseb = ((size_t)b * DM) * LTR + l;
    if (!valid) {
        __hip_bfloat16 z = __float2bfloat16(0.0f);
        for (int d = 0; d < DM; ++d) Ub[baseb + (size_t)d * LTR] = z;
        return;
    }
    bool cond = (l >= L_ - 1);
    for (int d = 0; d < DM; ++d) {
        float acc = inb[d] + sdot[d] + (cond ? tbs[d] : 0.0f);
        #pragma unroll
        for (int k = 0; k < 17; ++k)
            acc = fmaf(feats[tx][k], Ws[k][d], acc);
        Ub[baseb + (size_t)d * LTR] = __float2bfloat16(acc);
    }
}

// ---------------------------------------------------------------------------
// 3a) per-layer per-channel matrix prep with BN folding + stats finalize
// ---------------------------------------------------------------------------
__global__ __launch_bounds__(256) void prep_kernel(
    const float* __restrict__ log_dt,
    const float* __restrict__ A_re, const float* __restrict__ A_im,
    const float* __restrict__ C_re, const float* __restrict__ C_im,
    const float* __restrict__ Dp,
    const float* __restrict__ gamma, const float* __restrict__ beta,
    float* __restrict__ stats, float* __restrict__ scsh,
    __hip_bfloat16* __restrict__ Abig, __hip_bfloat16* __restrict__ SA,
    float* __restrict__ Rsh, float* __restrict__ T1sh, int layer) {
    int d = blockIdx.x;
    int t = threadIdx.x;
    __shared__ float sAr[64], sAi[64], sCkr[64], sCki[64];
    __shared__ float kap[TCH];
    __shared__ float csum[TCH];
    __shared__ float s_sc, s_sh;

    if (t == 0) {
        float sc, sh;
        if (layer == 0) { sc = 1.0f; sh = 0.0f; }
        else {
            float s = stats[d], q = stats[DM + d];
            float mean = s * (1.0f / NTOT);
            float var  = q * (1.0f / NTOT) - mean * mean;
            sc = rsqrtf(var + 1e-5f) * gamma[(layer - 1) * DM + d];
            sh = beta[(layer - 1) * DM + d] - mean * sc;
        }
        s_sc = sc; s_sh = sh;
        scsh[d] = sc; scsh[DM + d] = sh;
        stats[d] = 0.0f; stats[DM + d] = 0.0f;
    }
    __syncthreads();
    float sc = s_sc, sh = s_sh;

    float dt = expf(log_dt[layer * DM + d]);
    float Dd = Dp[layer * DM + d];
    if (t < 64) {
        size_t ab = ((size_t)layer * DM + d) * DS + t;
        float Ar = A_re[ab], Ai = A_im[ab], Cr = C_re[ab], Ci = C_im[ab];
        float ar = dt * Ar, ai = dt * Ai;
        float e = expf(ar);
        float wre = e * cosf(ai), wim = e * sinf(ai);
        float mr = wre - 1.0f, mi = wim;
        float den = 1.0f / (Ar * Ar + Ai * Ai);
        float qr = (mr * Ar + mi * Ai) * den, qi = (mi * Ar - mr * Ai) * den;
        sCkr[t] = Cr * qr - Ci * qi;
        sCki[t] = Cr * qi + Ci * qr;
        sAr[t] = ar;
        sAi[t] = ai;
        float s2 = sinf(0.5f * ai);
        float dr = fmaf(expm1f(ar), cosf(ai), -2.0f * s2 * s2);
        float di = e * sinf(ai);
        float a128 = 128.0f * ar, b128 = 128.0f * ai;
        float s2b = sinf(0.5f * b128);
        float nr = fmaf(expm1f(a128), cosf(b128), -2.0f * s2b * s2b);
        float ni = expf(a128) * sinf(b128);
        float dd2 = 1.0f / (dr * dr + di * di);
        float gr = (nr * dr + ni * di) * dd2;
        float gi = (ni * dr - nr * di) * dd2;
        Rsh[(size_t)d * 128 + t]      = sh * gr;
        Rsh[(size_t)d * 128 + 64 + t] = sh * gi;
    }
    __syncthreads();

    {
        int delta = t >> 1, half = t & 1;
        float fd = (float)delta;
        float p = 0.0f;
        #pragma unroll 8
        for (int n = half * 32; n < half * 32 + 32; ++n) {
            float er = expf(fd * sAr[n]);
            float ph = fd * sAi[n];
            p += er * (sCkr[n] * cosf(ph) - sCki[n] * sinf(ph));
        }
        p += __shfl_xor(p, 1);
        if (half == 0) kap[delta] = 2.0f * p + (delta == 0 ? Dd : 0.0f);
    }
    __syncthreads();

    if (t < 128) csum[t] = kap[t];
    __syncthreads();
    for (int off = 1; off < 128; off <<= 1) {
        float v = 0.0f;
        if (t >= off && t < 128) v = csum[t - off];
        __syncthreads();
        if (t < 128) csum[t] += v;
        __syncthreads();
    }
    if (t < 128) T1sh[(size_t)d * 128 + t] = sh * csum[t];

    __hip_bfloat16* Ad = Abig + (size_t)d * TCH * 256;
    for (int idx = t; idx < TCH * TCH; idx += 256) {
        int i = idx >> 7, m = idx & 127;
        Ad[(size_t)i * 256 + m] = __float2bfloat16(m <= i ? sc * kap[i - m] : 0.0f);
    }
    for (int idx = t; idx < TCH * 64; idx += 256) {
        int i = idx >> 6, n = idx & 63;
        float fp = (float)(i + 1);
        float er = expf(fp * sAr[n]);
        float ph = fp * sAi[n];
        float c = cosf(ph), s = sinf(ph);
        float vr = er * (sCkr[n] * c - sCki[n] * s);
        float vi = er * (sCkr[n] * s + sCki[n] * c);
        Ad[(size_t)i * 256 + 128 + n] = __float2bfloat16(2.0f * vr);
        Ad[(size_t)i * 256 + 192 + n] = __float2bfloat16(-2.0f * vi);
    }
    __hip_bfloat16* Sd = SA + (size_t)d * TCH * TCH;
    for (int idx = t; idx < 64 * TCH; idx += 256) {
        int n = idx >> 7, m = idx & 127;
        float fp = (float)(127 - m);
        float er = sc * expf(fp * sAr[n]);
        float ph = fp * sAi[n];
        Sd[(size_t)n * 128 + m]        = __float2bfloat16(er * cosf(ph));
        Sd[(size_t)(64 + n) * 128 + m] = __float2bfloat16(er * sinf(ph));
    }
}

// ---------------------------------------------------------------------------
// 3b) S-GEMM.  XCD-swizzled grid; conflict-free B layout [kk][nt][lane]x8.
// ---------------------------------------------------------------------------
__global__ __launch_bounds__(256) void sgemm_kernel(
    const __hip_bfloat16* __restrict__ Ub, const __hip_bfloat16* __restrict__ SA,
    const float* __restrict__ Rsh, __hip_bfloat16* __restrict__ S) {
    int id = blockIdx.x;               // 2304 blocks
    int xcd = id & 7, j = id >> 3;     // j in [0,288)
    int d = xcd * 32 + ((j * 7282) >> 16);   // j/9
    int cb = j - ((j * 7282) >> 16) * 9;
    int tid = threadIdx.x, wave = tid >> 6, lane = tid & 63;
    int lm = lane & 15, quad = lane >> 4;
    const __hip_bfloat16* SAd = SA + (size_t)d * TCH * TCH;

    __shared__ short Bs[8192];

    // staging: idx -> kk=idx>>8, nt=(idx>>6)&3, q=(idx>>4)&3, c=idx&15
    #pragma unroll
    for (int it = 0; it < 4; ++it) {
        int idx = it * 256 + tid;
        int kk = idx >> 8;
        int nt = (idx >> 6) & 3;
        int q  = (idx >> 4) & 3;
        int cc = idx & 15;
        int col = cb * 64 + nt * 16 + cc;
        int colc = col < COLS ? col : COLS - 1;
        int bh = (colc * 241) >> 12;
        int c = colc - bh * 17;
        const __hip_bfloat16* src =
            Ub + ((size_t)bh * DM + d) * LTR + (size_t)c * TCH + kk * 32 + q * 8;
        glds16(src, (char*)Bs + idx * 16);
    }
    asm volatile("s_waitcnt vmcnt(0)" ::: "memory");
    __syncthreads();

    floatx4 acc[2][4];
    floatx4 zf = {0.f, 0.f, 0.f, 0.f};
    #pragma unroll
    for (int mi = 0; mi < 2; ++mi)
        #pragma unroll
        for (int nt = 0; nt < 4; ++nt) acc[mi][nt] = zf;

    #pragma unroll
    for (int kk = 0; kk < 4; ++kk) {
        short8 a0 = *(const short8*)(SAd + (size_t)(wave * 32 + lm) * TCH + kk * 32 + quad * 8);
        short8 a1 = *(const short8*)(SAd + (size_t)(wave * 32 + 16 + lm) * TCH + kk * 32 + quad * 8);
        #pragma unroll
        for (int nt = 0; nt < 4; ++nt) {
            short8 bv = *(const short8*)(Bs + kk * 2048 + nt * 512 + lane * 8);
            acc[0][nt] = __builtin_amdgcn_mfma_f32_16x16x32_bf16(a0, bv, acc[0][nt], 0, 0, 0);
            acc[1][nt] = __builtin_amdgcn_mfma_f32_16x16x32_bf16(a1, bv, acc[1][nt], 0, 0, 0);
        }
    }
    #pragma unroll
    for (int mi = 0; mi < 2; ++mi) {
        int row = wave * 32 + mi * 16 + quad * 4;
        float4 rs = *(const float4*)(Rsh + (size_t)d * 128 + row);
        #pragma unroll
        for (int nt = 0; nt < 4; ++nt) {
            int col = cb * 64 + nt * 16 + lm;
            if (col >= COLS) continue;
            short4v o;
            o[0] = bfs(acc[mi][nt][0] + rs.x); o[1] = bfs(acc[mi][nt][1] + rs.y);
            o[2] = bfs(acc[mi][nt][2] + rs.z); o[3] = bfs(acc[mi][nt][3] + rs.w);
            *(short4v*)(S + ((size_t)d * COLS + col) * TCH + row) = o;
        }
    }
}

// ---------------------------------------------------------------------------
// 3c) carry scan over chunks (in place)
// ---------------------------------------------------------------------------
__global__ __launch_bounds__(64) void carry_kernel(
    __hip_bfloat16* __restrict__ SX,
    const float* __restrict__ log_dt,
    const float* __restrict__ A_re, const float* __restrict__ A_im,
    int layer) {
    int d = blockIdx.x, b = blockIdx.y;
    int n = threadIdx.x;
    float dt = expf(log_dt[layer * DM + d]);
    size_t ab = ((size_t)layer * DM + d) * DS + n;
    float Ar = A_re[ab], Ai = A_im[ab];
    float e = expf(dt * Ar);
    float wre = e * cosf(dt * Ai), wim = e * sinf(dt * Ai);
    #pragma unroll
    for (int t = 0; t < 7; ++t) {
        float r = wre * wre - wim * wim;
        wim = 2.0f * wre * wim; wre = r;
    }
    float xr = 0.0f, xi = 0.0f;
    for (int c = 0; c < NC; ++c) {
        size_t addr = ((size_t)d * COLS + b * NC + c) * TCH;
        float sre = __bfloat162float(SX[addr + n]);
        float sim = __bfloat162float(SX[addr + 64 + n]);
        SX[addr + n]      = __float2bfloat16(xr);
        SX[addr + 64 + n] = __float2bfloat16(xi);
        float nr = wre * xr - wim * xi + sre;
        xi = wre * xi + wim * xr + sim;
        xr = nr;
    }
}

// ---------------------------------------------------------------------------
// 3d) main chunk GEMM.  XCD-swizzled grid; conflict-free B layout.
// ---------------------------------------------------------------------------
__global__ __launch_bounds__(256) void mainscan_kernel(
    const __hip_bfloat16* __restrict__ Ub, const __hip_bfloat16* __restrict__ X,
    const __hip_bfloat16* __restrict__ Abig, const float* __restrict__ T1sh,
    __hip_bfloat16* __restrict__ Ybt) {
    int id = blockIdx.x;               // 2304 blocks
    int xcd = id & 7, j = id >> 3;
    int d = xcd * 32 + ((j * 7282) >> 16);
    int cb = j - ((j * 7282) >> 16) * 9;
    int tid = threadIdx.x, wave = tid >> 6, lane = tid & 63;
    int lm = lane & 15, quad = lane >> 4;
    const __hip_bfloat16* Ad = Abig + (size_t)d * TCH * 256;

    __shared__ short Bs[16384];

    #pragma unroll
    for (int it = 0; it < 8; ++it) {
        int idx = it * 256 + tid;
        int kk = idx >> 8;
        int nt = (idx >> 6) & 3;
        int q  = (idx >> 4) & 3;
        int cc = idx & 15;
        int col = cb * 64 + nt * 16 + cc;
        int colc = col < COLS ? col : COLS - 1;
        int bh = (colc * 241) >> 12;
        int c = colc - bh * 17;
        const __hip_bfloat16* src;
        if (kk < 4)
            src = Ub + ((size_t)bh * DM + d) * LTR + (size_t)c * TCH + kk * 32 + q * 8;
        else
            src = X + ((size_t)d * COLS + colc) * TCH + (kk - 4) * 32 + q * 8;
        glds16(src, (char*)Bs + idx * 16);
    }
    asm volatile("s_waitcnt vmcnt(0)" ::: "memory");
    __syncthreads();

    floatx4 acc[2][4];
    floatx4 zf = {0.f, 0.f, 0.f, 0.f};
    #pragma unroll
    for (int mi = 0; mi < 2; ++mi)
        #pragma unroll
        for (int nt = 0; nt < 4; ++nt) acc[mi][nt] = zf;

    #pragma unroll
    for (int kk = 0; kk < 8; ++kk) {
        short8 a0 = *(const short8*)(Ad + (size_t)(wave * 32 + lm) * 256 + kk * 32 + quad * 8);
        short8 a1 = *(const short8*)(Ad + (size_t)(wave * 32 + 16 + lm) * 256 + kk * 32 + quad * 8);
        #pragma unroll
        for (int nt = 0; nt < 4; ++nt) {
            short8 bv = *(const short8*)(Bs + kk * 2048 + nt * 512 + lane * 8);
            acc[0][nt] = __builtin_amdgcn_mfma_f32_16x16x32_bf16(a0, bv, acc[0][nt], 0, 0, 0);
            acc[1][nt] = __builtin_amdgcn_mfma_f32_16x16x32_bf16(a1, bv, acc[1][nt], 0, 0, 0);
        }
    }

    #pragma unroll
    for (int mi = 0; mi < 2; ++mi) {
        int row0 = wave * 32 + mi * 16 + quad * 4;
        float4 t1 = *(const float4*)(T1sh + (size_t)d * 128 + row0);
        #pragma unroll
        for (int nt = 0; nt < 4; ++nt) {
            int col = cb * 64 + nt * 16 + lm;
            if (col >= COLS) continue;
            int bh = (col * 241) >> 12;
            int c = col - bh * 17;
            int l0 = c * TCH + row0;
            float g0 = gelu_tanh(acc[mi][nt][0] + t1.x);
            float g1 = gelu_tanh(acc[mi][nt][1] + t1.y);
            float g2 = gelu_tanh(acc[mi][nt][2] + t1.z);
            float g3 = gelu_tanh(acc[mi][nt][3] + t1.w);
            __hip_bfloat16* dst = Ybt + ((size_t)bh * DM + d) * LTR + l0;
            if (l0 + 3 < LT) {
                short4v o;
                o[0] = bfs(g0); o[1] = bfs(g1); o[2] = bfs(g2); o[3] = bfs(g3);
                *(short4v*)dst = o;
            } else {
                if (l0 + 0 < LT) dst[0] = __float2bfloat16(g0);
                if (l0 + 1 < LT) dst[1] = __float2bfloat16(g1);
                if (l0 + 2 < LT) dst[2] = __float2bfloat16(g2);
                if (l0 + 3 < LT) dst[3] = __float2bfloat16(g3);
            }
        }
    }
}

// ---------------------------------------------------------------------------
// 3e) transpose Ybt[b][d][l] -> Yb[b][l][d]
// ---------------------------------------------------------------------------
__global__ __launch_bounds__(256) void transpose_kernel(
    const __hip_bfloat16* __restrict__ Ybt, __hip_bfloat16* __restrict__ Yb) {
    int lt = blockIdx.x, dti = blockIdx.y, b = blockIdx.z;
    int t = threadIdx.x;
    __shared__ short tileT[64 * 66];
    int l0 = lt * 64, d0 = dti * 64;
    #pragma unroll
    for (int r = 0; r < 2; ++r) {
        int idx = r * 256 + t;
        int dd = idx >> 3, lseg = idx & 7;
        short8 v = *(const short8*)(Ybt + ((size_t)b * DM + d0 + dd) * LTR + l0 + lseg * 8);
        #pragma unroll
        for (int i = 0; i < 8; ++i)
            tileT[(lseg * 8 + i) * 66 + dd] = v[i];
    }
    __syncthreads();
    #pragma unroll
    for (int r = 0; r < 2; ++r) {
        int idx = r * 256 + t;
        int ll = idx >> 3, dseg = idx & 7;
        short8 v;
        #pragma unroll
        for (int i = 0; i < 8; ++i)
            v[i] = tileT[ll * 66 + dseg * 8 + i];
        *(short8*)(Yb + ((size_t)b * LTR + l0 + ll) * DM + d0 + dseg * 8) = v;
    }
}

// ---------------------------------------------------------------------------
// 4) LDS-staged MFMA GEMM + GLU + residual + BN stats.  XCD-swizzled grid.
// ---------------------------------------------------------------------------
__global__ __launch_bounds__(256) void gemm_glu_mfma_kernel(
    const __hip_bfloat16* __restrict__ Yb, __hip_bfloat16* __restrict__ Ub,
    const __hip_bfloat16* __restrict__ Wtp, const float* __restrict__ out_b,
    const float* __restrict__ scsh, float* __restrict__ stats, int layer) {
    int id = blockIdx.x;               // 2176 blocks
    int r8 = id & 7, j = id >> 3;      // j in [0,272)
    int by = r8 >> 1;
    int sub = (r8 & 1) * 272 + j;      // [0,544)
    int bq = (sub * 3856) >> 16;       // sub/17
    int bx = sub - bq * 17;
    int b = bq;
    int tid = threadIdx.x;
    int wave = tid >> 6, lane = tid & 63;
    int lm = lane & 15, quad = lane >> 4;
    int l0 = bx * 128;

    __shared__ short lds[16384];
    short* Asb = lds;
    short* Bsb = lds + 8192;

    const __hip_bfloat16* Yb_b = Yb + (size_t)b * LTR * DM;
    const __hip_bfloat16* Wl = Wtp + (size_t)layer * 512 * 256 + (size_t)by * 128 * 256;

    floatx4 acc[4][4];
    floatx4 zf = {0.f, 0.f, 0.f, 0.f};
    #pragma unroll
    for (int mi = 0; mi < 4; ++mi)
        #pragma unroll
        for (int ni = 0; ni < 4; ++ni) acc[mi][ni] = zf;

    int rowS[4], qS[4];
    #pragma unroll
    for (int i = 0; i < 4; ++i) {
        int idx = i * 256 + tid;
        rowS[i] = idx >> 3;
        qS[i] = ((idx & 7) - rowS[i]) & 7;
    }
    int aoff[2][4], boff[2][4];
    #pragma unroll
    for (int kh = 0; kh < 2; ++kh) {
        #pragma unroll
        for (int mi = 0; mi < 4; ++mi) {
            int r = (wave >> 1) * 64 + mi * 16 + lm;
            aoff[kh][mi] = r * 64 + ((kh * 4 + quad + r) & 7) * 8;
        }
        #pragma unroll
        for (int ni = 0; ni < 4; ++ni) {
            int r = (wave & 1) * 64 + ni * 16 + lm;
            boff[kh][ni] = r * 64 + ((kh * 4 + quad + r) & 7) * 8;
        }
    }

    for (int ks = 0; ks < 4; ++ks) {
        int k0 = ks * 64;
        __syncthreads();
        #pragma unroll
        for (int i = 0; i < 4; ++i) {
            const __hip_bfloat16* ga = Yb_b + (size_t)(l0 + rowS[i]) * DM + k0 + qS[i] * 8;
            glds16(ga, (char*)Asb + i * 4096 + wave * 1024 + (lane & 63) * 16);
            const __hip_bfloat16* gb = Wl + (size_t)rowS[i] * 256 + k0 + qS[i] * 8;
            glds16(gb, (char*)Bsb + i * 4096 + wave * 1024 + (lane & 63) * 16);
        }
        asm volatile("s_waitcnt vmcnt(0)" ::: "memory");
        __syncthreads();

        #pragma unroll
        for (int kh = 0; kh < 2; ++kh) {
            short8 af[4], bf4[4];
            #pragma unroll
            for (int mi = 0; mi < 4; ++mi) af[mi] = *(const short8*)(Asb + aoff[kh][mi]);
            #pragma unroll
            for (int ni = 0; ni < 4; ++ni) bf4[ni] = *(const short8*)(Bsb + boff[kh][ni]);
            #pragma unroll
            for (int mi = 0; mi < 4; ++mi)
                #pragma unroll
                for (int ni = 0; ni < 4; ++ni)
                    acc[mi][ni] = __builtin_amdgcn_mfma_f32_16x16x32_bf16(
                        af[mi], bf4[ni], acc[mi][ni], 0, 0, 0);
        }
    }

    const float* bl = out_b + layer * 512;
    int Pbase = by * 64 + (wave & 1) * 32;
    int lw = l0 + (wave >> 1) * 64;
    #pragma unroll
    for (int ni = 0; ni < 2; ++ni) {
        int P = Pbase + ni * 16 + lm;
        float bz1 = bl[P], bz2 = bl[256 + P];
        float scP = scsh[P], shP = scsh[DM + P];
        __hip_bfloat16* ubrow = Ub + ((size_t)b * DM + P) * LTR;
        float sp = 0.f, sq = 0.f;
        #pragma unroll
        for (int mi = 0; mi < 4; ++mi) {
            int l0q = lw + mi * 16 + quad * 4;
            if (l0q >= LT) continue;
            floatx4 z1 = acc[mi][ni];
            floatx4 z2 = acc[mi][ni + 2];
            if (l0q + 4 <= LT) {
                short4v uv = *(const short4v*)(ubrow + l0q);
                float h0 = fmaf(scP, sbf(uv[0]), shP) + (z1[0] + bz1) * sigmoidf_(z2[0] + bz2);
                float h1 = fmaf(scP, sbf(uv[1]), shP) + (z1[1] + bz1) * sigmoidf_(z2[1] + bz2);
                float h2 = fmaf(scP, sbf(uv[2]), shP) + (z1[2] + bz1) * sigmoidf_(z2[2] + bz2);
                float h3 = fmaf(scP, sbf(uv[3]), shP) + (z1[3] + bz1) * sigmoidf_(z2[3] + bz2);
                short4v ov;
                ov[0] = bfs(h0); ov[1] = bfs(h1); ov[2] = bfs(h2); ov[3] = bfs(h3);
                *(short4v*)(ubrow + l0q) = ov;
                sp += (h0 + h1) + (h2 + h3);
                sq += (h0 * h0 + h1 * h1) + (h2 * h2 + h3 * h3);
            } else {
                #pragma unroll
                for (int r = 0; r < 4; ++r) {
                    int l = l0q + r;
                    if (l < LT) {
                        float uvv = __bfloat162float(ubrow[l]);
                        float hh = fmaf(scP, uvv, shP) + (z1[r] + bz1) * sigmoidf_(z2[r] + bz2);
                        ubrow[l] = __float2bfloat16(hh);
                        sp += hh; sq += hh * hh;
                    }
                }
            }
        }
        sp += __shfl_xor(sp, 16); sp += __shfl_xor(sp, 32);
        sq += __shfl_xor(sq, 16); sq += __shfl_xor(sq, 32);
        if (quad == 0) {
            atomicAdd(&stats[P], sp);
            atomicAdd(&stats[DM + P], sq);
        }
    }
}

// ---------------------------------------------------------------------------
// 5) final stats -> (sc, sh) for head
// ---------------------------------------------------------------------------
__global__ __launch_bounds__(256) void statsfin_kernel(
    const float* __restrict__ stats,
    const float* __restrict__ gamma, const float* __restrict__ beta,
    float* __restrict__ scsh, int layer) {
    int d = threadIdx.x;
    float s = stats[d], q = stats[DM + d];
    float mean = s * (1.0f / NTOT);
    float var  = q * (1.0f / NTOT) - mean * mean;
    float sc = rsqrtf(var + 1e-5f) * gamma[layer * DM + d];
    scsh[d] = sc;
    scsh[DM + d] = beta[layer * DM + d] - mean * sc;
}

// ---------------------------------------------------------------------------
// 6) head
// ---------------------------------------------------------------------------
__global__ __launch_bounds__(128) void head_kernel(
    const __hip_bfloat16* __restrict__ Ub, const float* __restrict__ scsh,
    const float* __restrict__ W1, const float* __restrict__ b1,
    const float* __restrict__ W2, const float* __restrict__ b2,
    float* __restrict__ out) {
    int hh = blockIdx.x;
    int b  = blockIdx.y;
    int j  = threadIdx.x;
    int l  = (L_ - 1) + hh;
    const __hip_bfloat16* urow = Ub + ((size_t)b * DM) * LTR + l;
    float a = b1[j];
    for (int k = 0; k < DM; ++k) {
        float hn = fmaf(scsh[k], __bfloat162float(urow[(size_t)k * LTR]), scsh[DM + k]);
        a = fmaf(hn, W1[k * 128 + j], a);
    }
    float hs = a * sigmoidf_(a);
    float v = hs * W2[j];
    v += __shfl_xor(v, 1);
    v += __shfl_xor(v, 2);
    v += __shfl_xor(v, 4);
    v += __shfl_xor(v, 8);
    v += __shfl_xor(v, 16);
    v += __shfl_xor(v, 32);
    __shared__ float partial[2];
    if ((j & 63) == 0) partial[j >> 6] = v;
    __syncthreads();
    if (j == 0) out[b * H_ + hh] = partial[0] + partial[1] + b2[0];
}

// ---------------------------------------------------------------------------
extern "C" void kernel_launch(void* const* d_in, const int* in_sizes, int n_in,
                              void* d_out, int out_size, void* d_ws, size_t ws_size,
                              hipStream_t stream) {
    (void)in_sizes; (void)n_in; (void)out_size; (void)ws_size;
    const float* x_past      = (const float*)d_in[0];
    const float* noisy       = (const float*)d_in[1];
    const float* t_in        = (const float*)d_in[2];
    const float* x_future    = (const float*)d_in[3];
    const float* static_attr = (const float*)d_in[4];
    const float* freqs       = (const float*)d_in[5];
    const float* phases      = (const float*)d_in[6];
    const float* in_W        = (const float*)d_in[7];
    const float* in_b        = (const float*)d_in[8];
    const float* tm_W1       = (const float*)d_in[9];
    const float* tm_b1       = (const float*)d_in[10];
    const float* tm_W2       = (const float*)d_in[11];
    const float* tm_b2       = (const float*)d_in[12];
    const float* log_dt      = (const float*)d_in[13];
    const float* A_re        = (const float*)d_in[14];
    const float* A_im        = (const float*)d_in[15];
    const float* C_re        = (const float*)d_in[16];
    const float* C_im        = (const float*)d_in[17];
    const float* Dp          = (const float*)d_in[18];
    const float* out_W       = (const float*)d_in[19];
    const float* out_b       = (const float*)d_in[20];
    const float* bn_gamma    = (const float*)d_in[21];
    const float* bn_beta     = (const float*)d_in[22];
    const float* head_W1     = (const float*)d_in[23];
    const float* head_b1     = (const float*)d_in[24];
    const float* head_W2     = (const float*)d_in[25];
    const float* head_b2     = (const float*)d_in[26];

    char* ws = (char*)d_ws;
    const size_t UB_OFF = 1u << 20;
    const size_t UB_BYT = (size_t)B_ * DM * LTR * 2;
    const size_t R1_OFF = UB_OFF + UB_BYT;
    const size_t RB     = (size_t)256 * COLS * TCH * 2;
    const size_t R2_OFF = R1_OFF + RB;
    const size_t AB_OFF = R2_OFF + RB;
    const size_t AB_BYT = (size_t)256 * TCH * 256 * 2;
    const size_t SA_OFF = AB_OFF + AB_BYT;
    const size_t SA_BYT = (size_t)256 * TCH * TCH * 2;
    const size_t WT_OFF = SA_OFF + SA_BYT;

    float*          tb    = (float*)(ws);
    float*          stats = (float*)(ws + (64 << 10));
    float*          scsh  = (float*)(ws + (96 << 10));
    float*          Rsh   = (float*)(ws + (128 << 10));
    float*          T1sh  = (float*)(ws + (256 << 10));
    __hip_bfloat16* Ub    = (__hip_bfloat16*)(ws + UB_OFF);
    __hip_bfloat16* R1    = (__hip_bfloat16*)(ws + R1_OFF);
    __hip_bfloat16* Ybt   = (__hip_bfloat16*)(ws + R2_OFF);
    __hip_bfloat16* Abig  = (__hip_bfloat16*)(ws + AB_OFF);
    __hip_bfloat16* SA    = (__hip_bfloat16*)(ws + SA_OFF);
    __hip_bfloat16* Wtp   = (__hip_bfloat16*)(ws + WT_OFF);

    time_mlp_kernel<<<dim3(B_), 256, 0, stream>>>(
        t_in, freqs, phases, tm_W1, tm_b1, tm_W2, tm_b2, tb);

    wt_prep_kernel<<<dim3(NL * 256), 256, 0, stream>>>(out_W, Wtp);

    input_proj_kernel<<<dim3(9, B_), 256, 0, stream>>>(
        x_past, noisy, x_future, static_attr, in_W, in_b, tb, Ub);

    for (int layer = 0; layer < NL; ++layer) {
        prep_kernel<<<dim3(256), 256, 0, stream>>>(
            log_dt, A_re, A_im, C_re, C_im, Dp, bn_gamma, bn_beta,
            stats, scsh, Abig, SA, Rsh, T1sh, layer);
        sgemm_kernel<<<dim3(2304), 256, 0, stream>>>(Ub, SA, Rsh, R1);
        carry_kernel<<<dim3(256, B_), 64, 0, stream>>>(
            R1, log_dt, A_re, A_im, layer);
        mainscan_kernel<<<dim3(2304), 256, 0, stream>>>(Ub, R1, Abig, T1sh, Ybt);
        transpose_kernel<<<dim3(LTR / 64, DM / 64, B_), 256, 0, stream>>>(Ybt, R1);
        gemm_glu_mfma_kernel<<<dim3(2176), 256, 0, stream>>>(
            R1, Ub, Wtp, out_b, scsh, stats, layer);
    }

    statsfin_kernel<<<dim3(1), 256, 0, stream>>>(
        stats, bn_gamma, bn_beta, scsh, NL - 1);

    head_kernel<<<dim3(H_, B_), 128, 0, stream>>>(
        Ub, scsh, head_W1, head_b1, head_W2, head_b2, (float*)d_out);
}